// Round 1
// baseline (1412.710 us; speedup 1.0000x reference)
//
#include <hip/hip_runtime.h>
#include <hip/hip_bf16.h>
#include <math.h>

#define NITEMS 100000
#define NUSERS 16384
#define HLEN   48
#define GCN    128
#define ATTN_D 128
#define HID    256
#define TOW    256

// ---------------------------------------------------------------------------
// K1: h = relu([item_feat, gcn_item] @ Wi1 + bi1)   (16 items/block)
// ---------------------------------------------------------------------------
__global__ __launch_bounds__(256) void k_item_h(
    const float* __restrict__ item_feat,
    const float* __restrict__ gcn_item,
    const float* __restrict__ Wi1,
    const float* __restrict__ bi1,
    float* __restrict__ h_out,          // [chunk_items][HID], local to chunk
    int item0)
{
  const int j  = threadIdx.x;
  const int i0 = item0 + blockIdx.x * 16;
  const size_t l0 = (size_t)blockIdx.x * 16;

  float acc[16];
  const float b = bi1[j];
  #pragma unroll
  for (int m = 0; m < 16; ++m) acc[m] = b;

  #pragma unroll
  for (int t = 0; t < 2; ++t) {
    const float w = Wi1[t * HID + j];
    #pragma unroll
    for (int m = 0; m < 16; ++m)
      acc[m] = fmaf(item_feat[(size_t)(i0 + m) * 2 + t], w, acc[m]);
  }
  #pragma unroll 4
  for (int t = 0; t < GCN; ++t) {
    const float w = Wi1[(2 + t) * HID + j];
    #pragma unroll
    for (int m = 0; m < 16; ++m)
      acc[m] = fmaf(gcn_item[(size_t)(i0 + m) * GCN + t], w, acc[m]);
  }
  #pragma unroll
  for (int m = 0; m < 16; ++m)
    h_out[(l0 + m) * HID + j] = fmaxf(acc[m], 0.f);
}

// ---------------------------------------------------------------------------
// K2: item_emb = l2norm(h @ Wi2 + bi2)   (16 items/block)
// ---------------------------------------------------------------------------
__global__ __launch_bounds__(256) void k_item_emb(
    const float* __restrict__ h_in,     // [chunk_items][HID]
    const float* __restrict__ Wi2,
    const float* __restrict__ bi2,
    float* __restrict__ item_emb,       // [NITEMS][TOW]
    int item0)
{
  const int j  = threadIdx.x;
  const int i0 = item0 + blockIdx.x * 16;
  const size_t hbase = (size_t)blockIdx.x * 16 * HID;

  float acc[16];
  const float b = bi2[j];
  #pragma unroll
  for (int m = 0; m < 16; ++m) acc[m] = b;

  #pragma unroll 4
  for (int t = 0; t < HID; ++t) {
    const float w = Wi2[t * TOW + j];
    #pragma unroll
    for (int m = 0; m < 16; ++m)
      acc[m] = fmaf(h_in[hbase + (size_t)m * HID + t], w, acc[m]);
  }

  // per-item L2 norm, reduce over the 256 threads
  float s[16];
  #pragma unroll
  for (int m = 0; m < 16; ++m) s[m] = acc[m] * acc[m];
  #pragma unroll
  for (int off = 32; off; off >>= 1) {
    #pragma unroll
    for (int m = 0; m < 16; ++m) s[m] += __shfl_xor(s[m], off);
  }
  __shared__ float red[4][16];
  __shared__ float rn[16];
  const int wid = j >> 6, lane = j & 63;
  if (lane == 0) {
    #pragma unroll
    for (int m = 0; m < 16; ++m) red[wid][m] = s[m];
  }
  __syncthreads();
  if (j < 16) {
    float n = red[0][j] + red[1][j] + red[2][j] + red[3][j];
    rn[j] = 1.0f / fmaxf(sqrtf(n), 1e-12f);
  }
  __syncthreads();
  #pragma unroll
  for (int m = 0; m < 16; ++m)
    item_emb[(size_t)(i0 + m) * TOW + j] = acc[m] * rn[m];
}

// ---------------------------------------------------------------------------
// K3: K_item = item_emb @ Wk + bk    (16 items/block; 128 cols, m split 8/8)
// ---------------------------------------------------------------------------
__global__ __launch_bounds__(256) void k_item_k(
    const float* __restrict__ item_emb,
    const float* __restrict__ Wk,
    const float* __restrict__ bk,
    float* __restrict__ K_item)         // [NITEMS][ATTN_D]
{
  const int j  = threadIdx.x & 127;
  const int mb = (threadIdx.x >> 7) * 8;   // wave-uniform: 0 or 8
  const int i0 = blockIdx.x * 16;

  float acc[8];
  const float b = bk[j];
  #pragma unroll
  for (int mm = 0; mm < 8; ++mm) acc[mm] = b;

  #pragma unroll 4
  for (int t = 0; t < TOW; ++t) {
    const float w = Wk[t * ATTN_D + j];
    #pragma unroll
    for (int mm = 0; mm < 8; ++mm)
      acc[mm] = fmaf(item_emb[(size_t)(i0 + mb + mm) * TOW + t], w, acc[mm]);
  }
  #pragma unroll
  for (int mm = 0; mm < 8; ++mm)
    K_item[(size_t)(i0 + mb + mm) * ATTN_D + j] = acc[mm];
}

// ---------------------------------------------------------------------------
// K4: per-user attention -> hist   (1 user/block, 256 threads)
// ---------------------------------------------------------------------------
__global__ __launch_bounds__(256) void k_user_attn(
    const float* __restrict__ gcn_user,
    const int*   __restrict__ hist_idx,
    const int*   __restrict__ hist_len,
    const float* __restrict__ Wq,
    const float* __restrict__ bq,
    const float* __restrict__ item_emb,
    const float* __restrict__ K_item,
    float* __restrict__ hist_out)       // [NUSERS][TOW]
{
  const int u = blockIdx.x;
  const int j = threadIdx.x;
  __shared__ float q[ATTN_D];
  __shared__ int   idx[HLEN];
  __shared__ float sc[HLEN];
  __shared__ float attn[HLEN];

  if (j < HLEN) idx[j] = hist_idx[u * HLEN + j];

  if (j < ATTN_D) {
    float a = bq[j];
    #pragma unroll 4
    for (int t = 0; t < GCN; ++t)
      a = fmaf(gcn_user[(size_t)u * GCN + t], Wq[t * ATTN_D + j], a);
    q[j] = a;
  }
  __syncthreads();

  const int wid = j >> 6, lane = j & 63;
  const float ql = q[lane], qh = q[lane + 64];
  for (int h = wid; h < HLEN; h += 4) {
    const float* kr = &K_item[(size_t)idx[h] * ATTN_D];
    float a = ql * kr[lane] + qh * kr[lane + 64];
    #pragma unroll
    for (int off = 32; off; off >>= 1) a += __shfl_xor(a, off);
    if (lane == 0) sc[h] = a * 0.08838834764831845f;  // 1/sqrt(128)
  }
  __syncthreads();

  const int len = hist_len[u];
  float mx = -1e30f;
  for (int h = 0; h < HLEN; ++h) if (h <= len) mx = fmaxf(mx, sc[h]);
  float sum = 0.f;
  for (int h = 0; h < HLEN; ++h) if (h <= len) sum += expf(sc[h] - mx);
  if (j < HLEN) attn[j] = (j <= len) ? (expf(sc[j] - mx) / sum) : 0.f;
  __syncthreads();

  float hv = 0.f;
  for (int h = 0; h <= len; ++h)
    hv = fmaf(attn[h], item_emb[(size_t)idx[h] * TOW + j], hv);
  hist_out[(size_t)u * TOW + j] = hv;
}

// ---------------------------------------------------------------------------
// K5: hu = relu([gcn_user, hist] @ Wu1 + bu1)   (8 users/block)
// ---------------------------------------------------------------------------
__global__ __launch_bounds__(256) void k_user_hu(
    const float* __restrict__ gcn_user,
    const float* __restrict__ hist,
    const float* __restrict__ Wu1,
    const float* __restrict__ bu1,
    float* __restrict__ hu_out)         // [NUSERS][HID]
{
  const int j  = threadIdx.x;
  const int u0 = blockIdx.x * 8;

  float acc[8];
  const float b = bu1[j];
  #pragma unroll
  for (int uu = 0; uu < 8; ++uu) acc[uu] = b;

  #pragma unroll 4
  for (int t = 0; t < GCN; ++t) {
    const float w = Wu1[t * HID + j];
    #pragma unroll
    for (int uu = 0; uu < 8; ++uu)
      acc[uu] = fmaf(gcn_user[(size_t)(u0 + uu) * GCN + t], w, acc[uu]);
  }
  #pragma unroll 4
  for (int t = 0; t < TOW; ++t) {
    const float w = Wu1[(GCN + t) * HID + j];
    #pragma unroll
    for (int uu = 0; uu < 8; ++uu)
      acc[uu] = fmaf(hist[(size_t)(u0 + uu) * TOW + t], w, acc[uu]);
  }
  #pragma unroll
  for (int uu = 0; uu < 8; ++uu)
    hu_out[(size_t)(u0 + uu) * HID + j] = fmaxf(acc[uu], 0.f);
}

// ---------------------------------------------------------------------------
// K6: user_emb = l2norm(hu @ Wu2 + bu2)   (8 users/block)
// ---------------------------------------------------------------------------
__global__ __launch_bounds__(256) void k_user_out(
    const float* __restrict__ hu,
    const float* __restrict__ Wu2,
    const float* __restrict__ bu2,
    float* __restrict__ out)            // [NUSERS][TOW]
{
  const int j  = threadIdx.x;
  const int u0 = blockIdx.x * 8;

  float acc[8];
  const float b = bu2[j];
  #pragma unroll
  for (int uu = 0; uu < 8; ++uu) acc[uu] = b;

  #pragma unroll 4
  for (int t = 0; t < HID; ++t) {
    const float w = Wu2[t * TOW + j];
    #pragma unroll
    for (int uu = 0; uu < 8; ++uu)
      acc[uu] = fmaf(hu[(size_t)(u0 + uu) * HID + t], w, acc[uu]);
  }

  float s[8];
  #pragma unroll
  for (int uu = 0; uu < 8; ++uu) s[uu] = acc[uu] * acc[uu];
  #pragma unroll
  for (int off = 32; off; off >>= 1) {
    #pragma unroll
    for (int uu = 0; uu < 8; ++uu) s[uu] += __shfl_xor(s[uu], off);
  }
  __shared__ float red[4][8];
  __shared__ float rn[8];
  const int wid = j >> 6, lane = j & 63;
  if (lane == 0) {
    #pragma unroll
    for (int uu = 0; uu < 8; ++uu) red[wid][uu] = s[uu];
  }
  __syncthreads();
  if (j < 8)
    rn[j] = 1.0f / fmaxf(sqrtf(red[0][j] + red[1][j] + red[2][j] + red[3][j]), 1e-12f);
  __syncthreads();
  #pragma unroll
  for (int uu = 0; uu < 8; ++uu)
    out[(size_t)(u0 + uu) * TOW + j] = acc[uu] * rn[uu];
}

// ---------------------------------------------------------------------------
extern "C" void kernel_launch(void* const* d_in, const int* in_sizes, int n_in,
                              void* d_out, int out_size, void* d_ws, size_t ws_size,
                              hipStream_t stream) {
  const float* item_feat = (const float*)d_in[0];
  const float* gcn_item  = (const float*)d_in[1];
  const float* gcn_user  = (const float*)d_in[2];
  const int*   hist_idx  = (const int*)d_in[3];
  const int*   hist_len  = (const int*)d_in[4];
  const float* Wi1 = (const float*)d_in[5];
  const float* bi1 = (const float*)d_in[6];
  const float* Wi2 = (const float*)d_in[7];
  const float* bi2 = (const float*)d_in[8];
  const float* Wq  = (const float*)d_in[9];
  const float* bq  = (const float*)d_in[10];
  const float* Wk  = (const float*)d_in[11];
  const float* bk  = (const float*)d_in[12];
  const float* Wu1 = (const float*)d_in[13];
  const float* bu1 = (const float*)d_in[14];
  const float* Wu2 = (const float*)d_in[15];
  const float* bu2 = (const float*)d_in[16];

  float* ws = (float*)d_ws;
  // workspace layout (floats)
  float* item_emb = ws;                                  // 25,600,000
  float* K_item   = item_emb + (size_t)NITEMS * TOW;     // 12,800,000
  float* scratch  = K_item + (size_t)NITEMS * ATTN_D;    // max(6.55M, 8.39M)
  float* h_chunk  = scratch;                             // 25600*256 (per chunk)
  float* hist     = scratch;                             // 16384*256 (after chunks)
  float* hu       = scratch + (size_t)NUSERS * TOW;      // 16384*256

  // ---- item tower (chunked h scratch) ----
  const int CHUNK = 25600;   // multiple of 16
  for (int c0 = 0; c0 < NITEMS; c0 += CHUNK) {
    int n = NITEMS - c0; if (n > CHUNK) n = CHUNK;
    int blocks = n / 16;
    k_item_h<<<blocks, 256, 0, stream>>>(item_feat, gcn_item, Wi1, bi1, h_chunk, c0);
    k_item_emb<<<blocks, 256, 0, stream>>>(h_chunk, Wi2, bi2, item_emb, c0);
  }
  k_item_k<<<NITEMS / 16, 256, 0, stream>>>(item_emb, Wk, bk, K_item);

  // ---- user tower ----
  k_user_attn<<<NUSERS, 256, 0, stream>>>(gcn_user, hist_idx, hist_len,
                                          Wq, bq, item_emb, K_item, hist);
  k_user_hu<<<NUSERS / 8, 256, 0, stream>>>(gcn_user, hist, Wu1, bu1, hu);
  k_user_out<<<NUSERS / 8, 256, 0, stream>>>(hu, Wu2, bu2, (float*)d_out);
}

// Round 2
// 374.045 us; speedup vs baseline: 3.7768x; 3.7768x over previous
//
#include <hip/hip_runtime.h>
#include <hip/hip_bf16.h>
#include <math.h>

#define NITEMS 100000
#define NUSERS 16384
#define HLEN   48
#define GCN    128
#define ATTN_D 128
#define HID    256
#define TOW    256

typedef __attribute__((ext_vector_type(8))) short short8;
typedef __attribute__((ext_vector_type(4))) float f32x4;
typedef __hip_bfloat16 bf16;

// ---------------------------------------------------------------------------
// Prep: pack fp32 weight [Korig][N] -> bf16 fragment-ordered buffer
// layout: out[((ks*NT + ct)*64 + lane)*8 + i] = W[ks*32 + (lane>>4)*8 + i][ct*16 + (lane&15)]
// zero-padded for k >= Korig.
// ---------------------------------------------------------------------------
__global__ __launch_bounds__(256) void k_prep_w(const float* __restrict__ W,
                                                bf16* __restrict__ out,
                                                int Korig, int KS, int NT) {
  int tid = blockIdx.x * 256 + threadIdx.x;
  int total = KS * NT * 512;
  if (tid >= total) return;
  int i  = tid & 7;
  int l  = (tid >> 3) & 63;
  int ct = (tid >> 9) % NT;
  int ks = (tid >> 9) / NT;
  int k   = ks * 32 + ((l >> 4) << 3) + i;
  int col = ct * 16 + (l & 15);
  int N = NT * 16;
  float v = (k < Korig) ? W[(size_t)k * N + col] : 0.f;
  out[tid] = __float2bfloat16(v);
}

// Prep item input: A1p[row][k] (k<2: feat, k<130: gcn, else 0), padded K=160, bf16
__global__ __launch_bounds__(256) void k_prep_a1(const float* __restrict__ feat,
                                                 const float* __restrict__ gcn,
                                                 bf16* __restrict__ out) {
  size_t tid = (size_t)blockIdx.x * 256 + threadIdx.x;
  if (tid >= (size_t)NITEMS * 160) return;
  int k = (int)(tid % 160);
  size_t row = tid / 160;
  float v = (k < 2) ? feat[row * 2 + k] : ((k < 130) ? gcn[row * GCN + (k - 2)] : 0.f);
  out[tid] = __float2bfloat16(v);
}

// Prep user fused input cols 0..127 (gcn_user -> bf16, row stride 384)
__global__ __launch_bounds__(256) void k_prep_user(const float* __restrict__ gcn_user,
                                                   bf16* __restrict__ fused) {
  int tid = blockIdx.x * 256 + threadIdx.x;
  if (tid >= NUSERS * GCN) return;
  int k = tid & 127;
  int u = tid >> 7;
  fused[(size_t)u * (GCN + TOW) + k] = __float2bfloat16(gcn_user[tid]);
}

// ---------------------------------------------------------------------------
// Generic MFMA GEMM: C = epilogue(A @ W + b)
// A: [M][KS*32] bf16 (row stride = KS*32), Wf: fragment-packed bf16
// wave = 16 rows x NT*16 cols; block = 4 waves.
// MODE 0: relu -> bf16; 1: l2norm -> bf16; 2: plain -> bf16; 3: l2norm -> fp32
// ---------------------------------------------------------------------------
template<int KS, int NT, int MODE>
__global__ __launch_bounds__(256) void k_gemm(
    const bf16* __restrict__ A,
    const bf16* __restrict__ Wf,
    const float* __restrict__ bias,
    void* __restrict__ Cout,
    int Mtiles)
{
  const int l   = threadIdx.x & 63;
  const int wid = threadIdx.x >> 6;
  const int tile = blockIdx.x * 4 + wid;
  if (tile >= Mtiles) return;
  const int K = KS * 32;
  const int N = NT * 16;
  const int r = l & 15, g = l >> 4;

  f32x4 acc[NT];
  #pragma unroll
  for (int ct = 0; ct < NT; ++ct) acc[ct] = (f32x4){0.f, 0.f, 0.f, 0.f};

  const bf16* arow = A + (size_t)(tile * 16 + r) * K + g * 8;
  const bf16* wf   = Wf + (size_t)l * 8;

  for (int ks = 0; ks < KS; ++ks) {
    short8 a = *(const short8*)(arow + ks * 32);
    #pragma unroll
    for (int ct = 0; ct < NT; ++ct) {
      short8 b = *(const short8*)(wf + (size_t)(ks * NT + ct) * 512);
      acc[ct] = __builtin_amdgcn_mfma_f32_16x16x32_bf16(a, b, acc[ct], 0, 0, 0);
    }
  }

  // bias (per-column), col = ct*16 + r for this lane, same for all 4 rows
  #pragma unroll
  for (int ct = 0; ct < NT; ++ct) {
    const float bj = bias[ct * 16 + r];
    #pragma unroll
    for (int i = 0; i < 4; ++i) acc[ct][i] += bj;
  }

  if (MODE == 0 || MODE == 2) {
    bf16* C = (bf16*)Cout;
    #pragma unroll
    for (int ct = 0; ct < NT; ++ct)
      #pragma unroll
      for (int i = 0; i < 4; ++i) {
        float v = acc[ct][i];
        if (MODE == 0) v = fmaxf(v, 0.f);
        C[(size_t)(tile * 16 + g * 4 + i) * N + ct * 16 + r] = __float2bfloat16(v);
      }
  } else {
    // l2norm over the row (this wave owns the full row)
    float s[4] = {0.f, 0.f, 0.f, 0.f};
    #pragma unroll
    for (int ct = 0; ct < NT; ++ct)
      #pragma unroll
      for (int i = 0; i < 4; ++i) s[i] += acc[ct][i] * acc[ct][i];
    #pragma unroll
    for (int off = 1; off < 16; off <<= 1) {
      #pragma unroll
      for (int i = 0; i < 4; ++i) s[i] += __shfl_xor(s[i], off);
    }
    float rn[4];
    #pragma unroll
    for (int i = 0; i < 4; ++i) rn[i] = 1.f / fmaxf(sqrtf(s[i]), 1e-12f);

    if (MODE == 1) {
      bf16* C = (bf16*)Cout;
      #pragma unroll
      for (int ct = 0; ct < NT; ++ct)
        #pragma unroll
        for (int i = 0; i < 4; ++i)
          C[(size_t)(tile * 16 + g * 4 + i) * N + ct * 16 + r] =
              __float2bfloat16(acc[ct][i] * rn[i]);
    } else {
      float* C = (float*)Cout;
      #pragma unroll
      for (int ct = 0; ct < NT; ++ct)
        #pragma unroll
        for (int i = 0; i < 4; ++i)
          C[(size_t)(tile * 16 + g * 4 + i) * N + ct * 16 + r] = acc[ct][i] * rn[i];
    }
  }
}

// ---------------------------------------------------------------------------
// Attention: per-user (1 user/block). q fp32; K_item/item_emb bf16 gather.
// Writes hist (bf16) into fused[u][128..383].
// ---------------------------------------------------------------------------
__global__ __launch_bounds__(256) void k_user_attn(
    const float* __restrict__ gcn_user,
    const int*   __restrict__ hist_idx,
    const int*   __restrict__ hist_len,
    const float* __restrict__ Wq,
    const float* __restrict__ bq,
    const bf16*  __restrict__ item_emb,
    const bf16*  __restrict__ K_item,
    bf16* __restrict__ fused)
{
  const int u = blockIdx.x;
  const int j = threadIdx.x;
  __shared__ float q[ATTN_D];
  __shared__ int   idx[HLEN];
  __shared__ float sc[HLEN];
  __shared__ float attn[HLEN];

  if (j < HLEN) idx[j] = hist_idx[u * HLEN + j];

  if (j < ATTN_D) {
    float a = bq[j];
    #pragma unroll 4
    for (int t = 0; t < GCN; ++t)
      a = fmaf(gcn_user[(size_t)u * GCN + t], Wq[t * ATTN_D + j], a);
    q[j] = a;
  }
  __syncthreads();

  const int wid = j >> 6, lane = j & 63;
  const float ql = q[lane], qh = q[lane + 64];
  for (int h = wid; h < HLEN; h += 4) {
    const bf16* kr = &K_item[(size_t)idx[h] * ATTN_D];
    float a = ql * __bfloat162float(kr[lane]) + qh * __bfloat162float(kr[lane + 64]);
    #pragma unroll
    for (int off = 32; off; off >>= 1) a += __shfl_xor(a, off);
    if (lane == 0) sc[h] = a * 0.08838834764831845f;  // 1/sqrt(128)
  }
  __syncthreads();

  const int len = hist_len[u];
  float mx = -1e30f;
  for (int h = 0; h <= len; ++h) mx = fmaxf(mx, sc[h]);
  float sum = 0.f;
  for (int h = 0; h <= len; ++h) sum += expf(sc[h] - mx);
  if (j < HLEN) attn[j] = (j <= len) ? (expf(sc[j] - mx) / sum) : 0.f;
  __syncthreads();

  float hv = 0.f;
  for (int h = 0; h <= len; ++h)
    hv = fmaf(attn[h], __bfloat162float(item_emb[(size_t)idx[h] * TOW + j]), hv);
  fused[(size_t)u * (GCN + TOW) + GCN + j] = __float2bfloat16(hv);
}

// ---------------------------------------------------------------------------
extern "C" void kernel_launch(void* const* d_in, const int* in_sizes, int n_in,
                              void* d_out, int out_size, void* d_ws, size_t ws_size,
                              hipStream_t stream) {
  const float* item_feat = (const float*)d_in[0];
  const float* gcn_item  = (const float*)d_in[1];
  const float* gcn_user  = (const float*)d_in[2];
  const int*   hist_idx  = (const int*)d_in[3];
  const int*   hist_len  = (const int*)d_in[4];
  const float* Wi1 = (const float*)d_in[5];
  const float* bi1 = (const float*)d_in[6];
  const float* Wi2 = (const float*)d_in[7];
  const float* bi2 = (const float*)d_in[8];
  const float* Wq  = (const float*)d_in[9];
  const float* bq  = (const float*)d_in[10];
  const float* Wk  = (const float*)d_in[11];
  const float* bk  = (const float*)d_in[12];
  const float* Wu1 = (const float*)d_in[13];
  const float* bu1 = (const float*)d_in[14];
  const float* Wu2 = (const float*)d_in[15];
  const float* bu2 = (const float*)d_in[16];

  char* ws = (char*)d_ws;
  // packed weights (bf16)
  bf16* Wi1p = (bf16*)(ws + 0);          //  5*16*512 = 40960 el
  bf16* Wi2p = (bf16*)(ws + 81920);      //  8*16*512 = 65536 el
  bf16* Wkp  = (bf16*)(ws + 212992);     //  8* 8*512 = 32768 el
  bf16* Wu1p = (bf16*)(ws + 278528);     // 12*16*512 = 98304 el
  bf16* Wu2p = (bf16*)(ws + 475136);     //  8*16*512 = 65536 el
  bf16* A1p      = (bf16*)(ws + 606208);     // 100000*160
  bf16* h_buf    = (bf16*)(ws + 32606208);   // 100000*256
  bf16* item_emb = (bf16*)(ws + 83806208);   // 100000*256
  bf16* K_item   = (bf16*)(ws + 135006208);  // 100000*128
  bf16* fusedA   = (bf16*)(ws + 160606208);  // 16384*384
  bf16* hu_buf   = (bf16*)(ws + 173189120);  // 16384*256
  // end: 181577728 bytes

  // ---- weight packing ----
  k_prep_w<<<160, 256, 0, stream>>>(Wi1, Wi1p, 130, 5, 16);
  k_prep_w<<<256, 256, 0, stream>>>(Wi2, Wi2p, 256, 8, 16);
  k_prep_w<<<128, 256, 0, stream>>>(Wk,  Wkp,  256, 8, 8);
  k_prep_w<<<384, 256, 0, stream>>>(Wu1, Wu1p, 384, 12, 16);
  k_prep_w<<<256, 256, 0, stream>>>(Wu2, Wu2p, 256, 8, 16);
  k_prep_a1<<<(NITEMS * 160 + 255) / 256, 256, 0, stream>>>(item_feat, gcn_item, A1p);
  k_prep_user<<<(NUSERS * GCN + 255) / 256, 256, 0, stream>>>(gcn_user, fusedA);

  // ---- item tower (MFMA) ----
  const int itiles = NITEMS / 16;            // 6250
  const int iblk = (itiles + 3) / 4;         // 1563
  k_gemm<5, 16, 0><<<iblk, 256, 0, stream>>>(A1p, Wi1p, bi1, h_buf, itiles);
  k_gemm<8, 16, 1><<<iblk, 256, 0, stream>>>(h_buf, Wi2p, bi2, item_emb, itiles);
  k_gemm<8, 8, 2><<<iblk, 256, 0, stream>>>(item_emb, Wkp, bk, K_item, itiles);

  // ---- user tower ----
  k_user_attn<<<NUSERS, 256, 0, stream>>>(gcn_user, hist_idx, hist_len,
                                          Wq, bq, item_emb, K_item, fusedA);
  const int utiles = NUSERS / 16;            // 1024
  const int ublk = utiles / 4;               // 256
  k_gemm<12, 16, 0><<<ublk, 256, 0, stream>>>(fusedA, Wu1p, bu1, hu_buf, utiles);
  k_gemm<8, 16, 3><<<ublk, 256, 0, stream>>>(hu_buf, Wu2p, bu2, (float*)d_out, utiles);
}

// Round 3
// 322.315 us; speedup vs baseline: 4.3830x; 1.1605x over previous
//
#include <hip/hip_runtime.h>
#include <hip/hip_bf16.h>
#include <math.h>

#define NITEMS 100000
#define NUSERS 16384
#define HLEN   48
#define GCN    128
#define ATTN_D 128
#define HID    256
#define TOW    256

typedef __attribute__((ext_vector_type(8))) short short8;
typedef __attribute__((ext_vector_type(4))) float f32x4;
typedef __hip_bfloat16 bf16;

static __device__ __forceinline__ float bfu(unsigned short u) {
  unsigned int x = ((unsigned int)u) << 16;
  float f; __builtin_memcpy(&f, &x, 4); return f;
}

// ---------------------------------------------------------------------------
// Prep: pack fp32 weight [Korig][N] -> bf16 fragment-ordered buffer
// out[((ks*NT + ct)*64 + lane)*8 + i] = W[ks*32 + (lane>>4)*8 + i][ct*16 + (lane&15)]
// ---------------------------------------------------------------------------
__global__ __launch_bounds__(256) void k_prep_w(const float* __restrict__ W,
                                                bf16* __restrict__ out,
                                                int Korig, int KS, int NT) {
  int tid = blockIdx.x * 256 + threadIdx.x;
  int total = KS * NT * 512;
  if (tid >= total) return;
  int i  = tid & 7;
  int l  = (tid >> 3) & 63;
  int ct = (tid >> 9) % NT;
  int ks = (tid >> 9) / NT;
  int k   = ks * 32 + ((l >> 4) << 3) + i;
  int col = ct * 16 + (l & 15);
  int N = NT * 16;
  float v = (k < Korig) ? W[(size_t)k * N + col] : 0.f;
  out[tid] = __float2bfloat16(v);
}

__global__ __launch_bounds__(256) void k_prep_a1(const float* __restrict__ feat,
                                                 const float* __restrict__ gcn,
                                                 bf16* __restrict__ out) {
  size_t tid = (size_t)blockIdx.x * 256 + threadIdx.x;
  if (tid >= (size_t)NITEMS * 160) return;
  int k = (int)(tid % 160);
  size_t row = tid / 160;
  float v = (k < 2) ? feat[row * 2 + k] : ((k < 130) ? gcn[row * GCN + (k - 2)] : 0.f);
  out[tid] = __float2bfloat16(v);
}

__global__ __launch_bounds__(256) void k_prep_user(const float* __restrict__ gcn_user,
                                                   bf16* __restrict__ fused) {
  int tid = blockIdx.x * 256 + threadIdx.x;
  if (tid >= NUSERS * GCN) return;
  int k = tid & 127;
  int u = tid >> 7;
  fused[(size_t)u * (GCN + TOW) + k] = __float2bfloat16(gcn_user[tid]);
}

// ---------------------------------------------------------------------------
// Generic MFMA GEMM, MR row-frags (16 rows each) per wave, 4 waves/block.
// MODE 0: relu->bf16; 1: l2norm->bf16; 2: plain->bf16; 3: l2norm->fp32; 4: plain->fp32
// ---------------------------------------------------------------------------
template<int KS, int NT, int MODE, int MR>
__global__ __launch_bounds__(256) void k_gemm(
    const bf16* __restrict__ A,
    const bf16* __restrict__ Wf,
    const float* __restrict__ bias,
    void* __restrict__ Cout,
    int Mtiles, int Astride)
{
  const int l   = threadIdx.x & 63;
  const int wid = threadIdx.x >> 6;
  const int tile = blockIdx.x * 4 + wid;
  if (tile >= Mtiles) return;
  const int N = NT * 16;
  const int r = l & 15, g = l >> 4;

  f32x4 acc[MR][NT];
  #pragma unroll
  for (int mr = 0; mr < MR; ++mr)
    #pragma unroll
    for (int ct = 0; ct < NT; ++ct) acc[mr][ct] = (f32x4){0.f, 0.f, 0.f, 0.f};

  const bf16* arow[MR];
  #pragma unroll
  for (int mr = 0; mr < MR; ++mr)
    arow[mr] = A + (size_t)(tile * (16 * MR) + mr * 16 + r) * Astride + g * 8;
  const bf16* wf = Wf + (size_t)l * 8;

  for (int ks = 0; ks < KS; ++ks) {
    short8 a[MR];
    #pragma unroll
    for (int mr = 0; mr < MR; ++mr) a[mr] = *(const short8*)(arow[mr] + ks * 32);
    #pragma unroll
    for (int ct = 0; ct < NT; ++ct) {
      short8 b = *(const short8*)(wf + (size_t)(ks * NT + ct) * 512);
      #pragma unroll
      for (int mr = 0; mr < MR; ++mr)
        acc[mr][ct] = __builtin_amdgcn_mfma_f32_16x16x32_bf16(a[mr], b, acc[mr][ct], 0, 0, 0);
    }
  }

  #pragma unroll
  for (int mr = 0; mr < MR; ++mr) {
    #pragma unroll
    for (int ct = 0; ct < NT; ++ct) {
      const float bj = bias[ct * 16 + r];
      #pragma unroll
      for (int i = 0; i < 4; ++i) acc[mr][ct][i] += bj;
    }
  }

  if (MODE == 0 || MODE == 2 || MODE == 4) {
    #pragma unroll
    for (int mr = 0; mr < MR; ++mr)
      #pragma unroll
      for (int ct = 0; ct < NT; ++ct)
        #pragma unroll
        for (int i = 0; i < 4; ++i) {
          float v = acc[mr][ct][i];
          if (MODE == 0) v = fmaxf(v, 0.f);
          size_t off = (size_t)(tile * (16 * MR) + mr * 16 + g * 4 + i) * N + ct * 16 + r;
          if (MODE == 4) ((float*)Cout)[off] = v;
          else           ((bf16*)Cout)[off]  = __float2bfloat16(v);
        }
  } else {
    #pragma unroll
    for (int mr = 0; mr < MR; ++mr) {
      float s[4] = {0.f, 0.f, 0.f, 0.f};
      #pragma unroll
      for (int ct = 0; ct < NT; ++ct)
        #pragma unroll
        for (int i = 0; i < 4; ++i) s[i] += acc[mr][ct][i] * acc[mr][ct][i];
      #pragma unroll
      for (int off = 1; off < 16; off <<= 1) {
        #pragma unroll
        for (int i = 0; i < 4; ++i) s[i] += __shfl_xor(s[i], off);
      }
      float rn[4];
      #pragma unroll
      for (int i = 0; i < 4; ++i) rn[i] = 1.f / fmaxf(sqrtf(s[i]), 1e-12f);
      #pragma unroll
      for (int ct = 0; ct < NT; ++ct)
        #pragma unroll
        for (int i = 0; i < 4; ++i) {
          size_t off = (size_t)(tile * (16 * MR) + mr * 16 + g * 4 + i) * N + ct * 16 + r;
          float v = acc[mr][ct][i] * rn[i];
          if (MODE == 3) ((float*)Cout)[off] = v;
          else           ((bf16*)Cout)[off]  = __float2bfloat16(v);
        }
    }
  }
}

// ---------------------------------------------------------------------------
// Attention v2: 1 user/block, all loops static (HLEN=48), Q precomputed fp32.
// ---------------------------------------------------------------------------
__global__ __launch_bounds__(256) void k_user_attn(
    const float* __restrict__ Q,
    const int*   __restrict__ hist_idx,
    const int*   __restrict__ hist_len,
    const bf16*  __restrict__ item_emb,
    const bf16*  __restrict__ K_item,
    bf16* __restrict__ fused)
{
  const int u = blockIdx.x;
  const int j = threadIdx.x;
  const int wid = j >> 6, lane = j & 63;
  __shared__ int   idx[HLEN];
  __shared__ float sc[HLEN];
  __shared__ float attn[HLEN];

  if (j < HLEN) idx[j] = hist_idx[u * HLEN + j];
  __syncthreads();

  // ---- scores: wave wid handles h = wid*12 .. wid*12+11, all static ----
  const float q0 = Q[(size_t)u * ATTN_D + 2 * lane];
  const float q1 = Q[(size_t)u * ATTN_D + 2 * lane + 1];
  ushort2 kv[12];
  #pragma unroll
  for (int t = 0; t < 12; ++t) {
    const int h = wid * 12 + t;
    kv[t] = *(const ushort2*)(K_item + (size_t)idx[h] * ATTN_D + 2 * lane);
  }
  #pragma unroll
  for (int t = 0; t < 12; ++t) {
    float a = q0 * bfu(kv[t].x) + q1 * bfu(kv[t].y);
    #pragma unroll
    for (int off = 32; off; off >>= 1) a += __shfl_xor(a, off);
    if (lane == 0) sc[wid * 12 + t] = a * 0.08838834764831845f;  // 1/sqrt(128)
  }
  __syncthreads();

  // ---- softmax (wave 0, lane-parallel) ----
  if (wid == 0) {
    const int len = hist_len[u];
    const bool valid = (lane < HLEN) && (lane <= len);
    float x = valid ? sc[lane] : -1e30f;
    float m = x;
    #pragma unroll
    for (int off = 32; off; off >>= 1) m = fmaxf(m, __shfl_xor(m, off));
    float e = valid ? expf(x - m) : 0.f;
    float s = e;
    #pragma unroll
    for (int off = 32; off; off >>= 1) s += __shfl_xor(s, off);
    if (lane < HLEN) attn[lane] = e / s;
  }
  __syncthreads();

  // ---- PV: static 48 rows, 4 partial accumulators ----
  float hv0 = 0.f, hv1 = 0.f, hv2 = 0.f, hv3 = 0.f;
  #pragma unroll
  for (int h = 0; h < HLEN; h += 4) {
    hv0 = fmaf(attn[h + 0], __bfloat162float(item_emb[(size_t)idx[h + 0] * TOW + j]), hv0);
    hv1 = fmaf(attn[h + 1], __bfloat162float(item_emb[(size_t)idx[h + 1] * TOW + j]), hv1);
    hv2 = fmaf(attn[h + 2], __bfloat162float(item_emb[(size_t)idx[h + 2] * TOW + j]), hv2);
    hv3 = fmaf(attn[h + 3], __bfloat162float(item_emb[(size_t)idx[h + 3] * TOW + j]), hv3);
  }
  fused[(size_t)u * (GCN + TOW) + GCN + j] = __float2bfloat16((hv0 + hv1) + (hv2 + hv3));
}

// ---------------------------------------------------------------------------
extern "C" void kernel_launch(void* const* d_in, const int* in_sizes, int n_in,
                              void* d_out, int out_size, void* d_ws, size_t ws_size,
                              hipStream_t stream) {
  const float* item_feat = (const float*)d_in[0];
  const float* gcn_item  = (const float*)d_in[1];
  const float* gcn_user  = (const float*)d_in[2];
  const int*   hist_idx  = (const int*)d_in[3];
  const int*   hist_len  = (const int*)d_in[4];
  const float* Wi1 = (const float*)d_in[5];
  const float* bi1 = (const float*)d_in[6];
  const float* Wi2 = (const float*)d_in[7];
  const float* bi2 = (const float*)d_in[8];
  const float* Wq  = (const float*)d_in[9];
  const float* bq  = (const float*)d_in[10];
  const float* Wk  = (const float*)d_in[11];
  const float* bk  = (const float*)d_in[12];
  const float* Wu1 = (const float*)d_in[13];
  const float* bu1 = (const float*)d_in[14];
  const float* Wu2 = (const float*)d_in[15];
  const float* bu2 = (const float*)d_in[16];

  char* ws = (char*)d_ws;
  bf16* Wi1p = (bf16*)(ws + 0);          // 40960 el  (81920 B)
  bf16* Wi2p = (bf16*)(ws + 81920);      // 65536 el  (131072 B)
  bf16* Wkp  = (bf16*)(ws + 212992);     // 32768 el  (65536 B)
  bf16* Wu1p = (bf16*)(ws + 278528);     // 98304 el  (196608 B)
  bf16* Wu2p = (bf16*)(ws + 475136);     // 65536 el  (131072 B)
  bf16* Wqp  = (bf16*)(ws + 606208);     // 16384 el  (32768 B)
  // A1p region reused for Q after the item tower consumes A1p
  bf16*  A1p  = (bf16*)(ws + 638976);        // 100000*160*2 = 32,000,000 B
  float* Qbuf = (float*)(ws + 638976);       // 16384*128*4  =  8,388,608 B (aliases A1p)
  bf16* h_buf    = (bf16*)(ws + 32638976);   // 100000*256*2
  bf16* item_emb = (bf16*)(ws + 83838976);   // 100000*256*2
  bf16* K_item   = (bf16*)(ws + 135038976);  // 100000*128*2
  bf16* fusedA   = (bf16*)(ws + 160638976);  // 16384*384*2
  bf16* hu_buf   = (bf16*)(ws + 173221888);  // 16384*256*2
  // end: 181,610,496 B

  // ---- packing ----
  k_prep_w<<<160, 256, 0, stream>>>(Wi1, Wi1p, 130, 5, 16);
  k_prep_w<<<256, 256, 0, stream>>>(Wi2, Wi2p, 256, 8, 16);
  k_prep_w<<<128, 256, 0, stream>>>(Wk,  Wkp,  256, 8, 8);
  k_prep_w<<<384, 256, 0, stream>>>(Wu1, Wu1p, 384, 12, 16);
  k_prep_w<<<256, 256, 0, stream>>>(Wu2, Wu2p, 256, 8, 16);
  k_prep_w<<<64,  256, 0, stream>>>(Wq,  Wqp,  128, 4, 8);
  k_prep_a1<<<62500, 256, 0, stream>>>(item_feat, gcn_item, A1p);
  k_prep_user<<<8192, 256, 0, stream>>>(gcn_user, fusedA);

  // ---- item tower (MR=2 -> 32 rows/wave) ----
  const int itiles = NITEMS / 32;            // 3125
  const int iblk = (itiles + 3) / 4;         // 782
  k_gemm<5, 16, 0, 2><<<iblk, 256, 0, stream>>>(A1p, Wi1p, bi1, h_buf, itiles, 160);
  k_gemm<8, 16, 1, 2><<<iblk, 256, 0, stream>>>(h_buf, Wi2p, bi2, item_emb, itiles, 256);
  k_gemm<8, 8, 2, 2><<<iblk, 256, 0, stream>>>(item_emb, Wkp, bk, K_item, itiles, 256);

  // ---- user tower ----
  const int utiles = NUSERS / 32;            // 512
  const int ublk = utiles / 4;               // 128
  k_gemm<4, 8, 4, 2><<<ublk, 256, 0, stream>>>(fusedA, Wqp, bq, Qbuf, utiles, 384);
  k_user_attn<<<NUSERS, 256, 0, stream>>>(Qbuf, hist_idx, hist_len,
                                          item_emb, K_item, fusedA);
  k_gemm<12, 16, 0, 2><<<ublk, 256, 0, stream>>>(fusedA, Wu1p, bu1, hu_buf, utiles, 384);
  k_gemm<8, 16, 3, 2><<<ublk, 256, 0, stream>>>(hu_buf, Wu2p, bu2, (float*)d_out, utiles, 256);
}

// Round 4
// 307.794 us; speedup vs baseline: 4.5898x; 1.0472x over previous
//
#include <hip/hip_runtime.h>
#include <hip/hip_bf16.h>
#include <math.h>

#define NITEMS 100000
#define NUSERS 16384
#define HLEN   48
#define GCN    128
#define ATTN_D 128
#define HID    256
#define TOW    256

typedef __attribute__((ext_vector_type(8))) short short8;
typedef __attribute__((ext_vector_type(4))) float f32x4;
typedef __hip_bfloat16 bf16;

static __device__ __forceinline__ float bfu(unsigned short u) {
  unsigned int x = ((unsigned int)u) << 16;
  float f; __builtin_memcpy(&f, &x, 4); return f;
}

// ---------------------------------------------------------------------------
// Prep: pack fp32 weight [Korig][N] -> bf16 fragment-ordered buffer
// out[((ks*NT + ct)*64 + lane)*8 + i] = W[ks*32 + (lane>>4)*8 + i][ct*16 + (lane&15)]
// ---------------------------------------------------------------------------
__global__ __launch_bounds__(256) void k_prep_w(const float* __restrict__ W,
                                                bf16* __restrict__ out,
                                                int Korig, int KS, int NT) {
  int tid = blockIdx.x * 256 + threadIdx.x;
  int total = KS * NT * 512;
  if (tid >= total) return;
  int i  = tid & 7;
  int l  = (tid >> 3) & 63;
  int ct = (tid >> 9) % NT;
  int ks = (tid >> 9) / NT;
  int k   = ks * 32 + ((l >> 4) << 3) + i;
  int col = ct * 16 + (l & 15);
  int N = NT * 16;
  float v = (k < Korig) ? W[(size_t)k * N + col] : 0.f;
  out[tid] = __float2bfloat16(v);
}

__global__ __launch_bounds__(256) void k_prep_a1(const float* __restrict__ feat,
                                                 const float* __restrict__ gcn,
                                                 bf16* __restrict__ out) {
  size_t tid = (size_t)blockIdx.x * 256 + threadIdx.x;
  if (tid >= (size_t)NITEMS * 160) return;
  int k = (int)(tid % 160);
  size_t row = tid / 160;
  float v = (k < 2) ? feat[row * 2 + k] : ((k < 130) ? gcn[row * GCN + (k - 2)] : 0.f);
  out[tid] = __float2bfloat16(v);
}

__global__ __launch_bounds__(256) void k_prep_user(const float* __restrict__ gcn_user,
                                                   bf16* __restrict__ fused) {
  int tid = blockIdx.x * 256 + threadIdx.x;
  if (tid >= NUSERS * GCN) return;
  int k = tid & 127;
  int u = tid >> 7;
  fused[(size_t)u * (GCN + TOW) + k] = __float2bfloat16(gcn_user[tid]);
}

// ---------------------------------------------------------------------------
// Fold: Wqk[g][t] = (1/sqrt(128)) * sum_d Wq[g][d] * Wk[t][d]   (g<128)
//       b~[t]    = (1/sqrt(128)) * sum_d bq[d]    * Wk[t][d]    (block 16)
// out is fp32 [129][256]; blocks 0..15 each do 8 g-rows, block 16 does b~.
// ---------------------------------------------------------------------------
__global__ __launch_bounds__(256) void k_fold(const float* __restrict__ Wq,
                                              const float* __restrict__ Wk,
                                              const float* __restrict__ bq,
                                              float* __restrict__ out) {
  const float INV_S = 0.08838834764831845f;
  const int t = threadIdx.x;
  const int b = blockIdx.x;
  if (b < 16) {
    __shared__ float wq[8][128];
    for (int s = t; s < 8 * 128; s += 256)
      wq[s >> 7][s & 127] = Wq[(size_t)(b * 8 + (s >> 7)) * ATTN_D + (s & 127)];
    __syncthreads();
    float acc[8] = {0.f, 0.f, 0.f, 0.f, 0.f, 0.f, 0.f, 0.f};
    for (int d = 0; d < 128; ++d) {
      const float wk = Wk[(size_t)t * ATTN_D + d];
      #pragma unroll
      for (int gg = 0; gg < 8; ++gg) acc[gg] = fmaf(wq[gg][d], wk, acc[gg]);
    }
    #pragma unroll
    for (int gg = 0; gg < 8; ++gg)
      out[(size_t)(b * 8 + gg) * TOW + t] = acc[gg] * INV_S;
  } else {
    float a = 0.f;
    for (int d = 0; d < 128; ++d)
      a = fmaf(bq[d], Wk[(size_t)t * ATTN_D + d], a);
    out[(size_t)128 * TOW + t] = a * INV_S;
  }
}

// ---------------------------------------------------------------------------
// Generic MFMA GEMM, MR row-frags (16 rows each) per wave, 4 waves/block.
// MODE 0: relu->bf16; 1: l2norm->bf16; 2: plain->bf16; 3: l2norm->fp32; 4: plain->fp32
// ---------------------------------------------------------------------------
template<int KS, int NT, int MODE, int MR>
__global__ __launch_bounds__(256) void k_gemm(
    const bf16* __restrict__ A,
    const bf16* __restrict__ Wf,
    const float* __restrict__ bias,
    void* __restrict__ Cout,
    int Mtiles, int Astride)
{
  const int l   = threadIdx.x & 63;
  const int wid = threadIdx.x >> 6;
  const int tile = blockIdx.x * 4 + wid;
  if (tile >= Mtiles) return;
  const int N = NT * 16;
  const int r = l & 15, g = l >> 4;

  f32x4 acc[MR][NT];
  #pragma unroll
  for (int mr = 0; mr < MR; ++mr)
    #pragma unroll
    for (int ct = 0; ct < NT; ++ct) acc[mr][ct] = (f32x4){0.f, 0.f, 0.f, 0.f};

  const bf16* arow[MR];
  #pragma unroll
  for (int mr = 0; mr < MR; ++mr)
    arow[mr] = A + (size_t)(tile * (16 * MR) + mr * 16 + r) * Astride + g * 8;
  const bf16* wf = Wf + (size_t)l * 8;

  for (int ks = 0; ks < KS; ++ks) {
    short8 a[MR];
    #pragma unroll
    for (int mr = 0; mr < MR; ++mr) a[mr] = *(const short8*)(arow[mr] + ks * 32);
    #pragma unroll
    for (int ct = 0; ct < NT; ++ct) {
      short8 b = *(const short8*)(wf + (size_t)(ks * NT + ct) * 512);
      #pragma unroll
      for (int mr = 0; mr < MR; ++mr)
        acc[mr][ct] = __builtin_amdgcn_mfma_f32_16x16x32_bf16(a[mr], b, acc[mr][ct], 0, 0, 0);
    }
  }

  #pragma unroll
  for (int mr = 0; mr < MR; ++mr) {
    #pragma unroll
    for (int ct = 0; ct < NT; ++ct) {
      const float bj = bias[ct * 16 + r];
      #pragma unroll
      for (int i = 0; i < 4; ++i) acc[mr][ct][i] += bj;
    }
  }

  if (MODE == 0 || MODE == 2 || MODE == 4) {
    #pragma unroll
    for (int mr = 0; mr < MR; ++mr)
      #pragma unroll
      for (int ct = 0; ct < NT; ++ct)
        #pragma unroll
        for (int i = 0; i < 4; ++i) {
          float v = acc[mr][ct][i];
          if (MODE == 0) v = fmaxf(v, 0.f);
          size_t off = (size_t)(tile * (16 * MR) + mr * 16 + g * 4 + i) * N + ct * 16 + r;
          if (MODE == 4) ((float*)Cout)[off] = v;
          else           ((bf16*)Cout)[off]  = __float2bfloat16(v);
        }
  } else {
    #pragma unroll
    for (int mr = 0; mr < MR; ++mr) {
      float s[4] = {0.f, 0.f, 0.f, 0.f};
      #pragma unroll
      for (int ct = 0; ct < NT; ++ct)
        #pragma unroll
        for (int i = 0; i < 4; ++i) s[i] += acc[mr][ct][i] * acc[mr][ct][i];
      #pragma unroll
      for (int off = 1; off < 16; off <<= 1) {
        #pragma unroll
        for (int i = 0; i < 4; ++i) s[i] += __shfl_xor(s[i], off);
      }
      float rn[4];
      #pragma unroll
      for (int i = 0; i < 4; ++i) rn[i] = 1.f / fmaxf(sqrtf(s[i]), 1e-12f);
      #pragma unroll
      for (int ct = 0; ct < NT; ++ct)
        #pragma unroll
        for (int i = 0; i < 4; ++i) {
          size_t off = (size_t)(tile * (16 * MR) + mr * 16 + g * 4 + i) * N + ct * 16 + r;
          float v = acc[mr][ct][i] * rn[i];
          if (MODE == 3) ((float*)Cout)[off] = v;
          else           ((bf16*)Cout)[off]  = __float2bfloat16(v);
        }
    }
  }
}

// ---------------------------------------------------------------------------
// Attention v3: 1 user/block. Single gather of emb rows into LDS; scores,
// softmax and PV all from LDS. q~ = gcn_user@Wqk + b~ precomputed (fp32).
// ---------------------------------------------------------------------------
__global__ __launch_bounds__(256) void k_user_attn(
    const float* __restrict__ Qt,          // [NUSERS][TOW] fp32
    const int*   __restrict__ hist_idx,
    const int*   __restrict__ hist_len,
    const bf16*  __restrict__ item_emb,    // [NITEMS][TOW] bf16
    bf16* __restrict__ fused)
{
  const int u = blockIdx.x;
  const int j = threadIdx.x;
  const int wid = j >> 6, lane = j & 63;
  __shared__ int    idx[HLEN];
  __shared__ ushort emb[HLEN][TOW];
  __shared__ float  sc[HLEN];
  __shared__ float  attn[HLEN];

  if (j < HLEN) idx[j] = hist_idx[u * HLEN + j];
  __syncthreads();

  // ---- stage 48 emb rows into LDS (6 sweeps x 8 rows, 16B/lane) ----
  {
    const int r0 = j >> 5;          // 0..7
    const int c  = (j & 31) * 8;    // element offset
    #pragma unroll
    for (int s = 0; s < 6; ++s) {
      const int h = s * 8 + r0;
      *(short8*)(&emb[h][c]) = *(const short8*)(item_emb + (size_t)idx[h] * TOW + c);
    }
  }
  __syncthreads();

  // ---- scores: wave wid handles h = wid*12 .. +11; lane covers dims 4l..4l+3
  const f32x4 q = *(const f32x4*)(Qt + (size_t)u * TOW + 4 * lane);
  #pragma unroll
  for (int t = 0; t < 12; ++t) {
    const int h = wid * 12 + t;
    ushort4 e = *(const ushort4*)(&emb[h][4 * lane]);
    float a = q.x * bfu(e.x) + q.y * bfu(e.y) + q.z * bfu(e.z) + q.w * bfu(e.w);
    #pragma unroll
    for (int off = 32; off; off >>= 1) a += __shfl_xor(a, off);
    if (lane == 0) sc[h] = a;   // 1/sqrt(128) folded into Wqk/b~
  }
  __syncthreads();

  // ---- softmax (wave 0, lane-parallel) ----
  if (wid == 0) {
    const int len = hist_len[u];
    const bool valid = (lane < HLEN) && (lane <= len);
    float x = valid ? sc[lane] : -1e30f;
    float m = x;
    #pragma unroll
    for (int off = 32; off; off >>= 1) m = fmaxf(m, __shfl_xor(m, off));
    float e = valid ? expf(x - m) : 0.f;
    float s = e;
    #pragma unroll
    for (int off = 32; off; off >>= 1) s += __shfl_xor(s, off);
    if (lane < HLEN) attn[lane] = e / s;
  }
  __syncthreads();

  // ---- PV from LDS: thread j owns output dim j ----
  float hv0 = 0.f, hv1 = 0.f, hv2 = 0.f, hv3 = 0.f;
  #pragma unroll
  for (int h = 0; h < HLEN; h += 4) {
    hv0 = fmaf(attn[h + 0], bfu(emb[h + 0][j]), hv0);
    hv1 = fmaf(attn[h + 1], bfu(emb[h + 1][j]), hv1);
    hv2 = fmaf(attn[h + 2], bfu(emb[h + 2][j]), hv2);
    hv3 = fmaf(attn[h + 3], bfu(emb[h + 3][j]), hv3);
  }
  fused[(size_t)u * (GCN + TOW) + GCN + j] = __float2bfloat16((hv0 + hv1) + (hv2 + hv3));
}

// ---------------------------------------------------------------------------
extern "C" void kernel_launch(void* const* d_in, const int* in_sizes, int n_in,
                              void* d_out, int out_size, void* d_ws, size_t ws_size,
                              hipStream_t stream) {
  const float* item_feat = (const float*)d_in[0];
  const float* gcn_item  = (const float*)d_in[1];
  const float* gcn_user  = (const float*)d_in[2];
  const int*   hist_idx  = (const int*)d_in[3];
  const int*   hist_len  = (const int*)d_in[4];
  const float* Wi1 = (const float*)d_in[5];
  const float* bi1 = (const float*)d_in[6];
  const float* Wi2 = (const float*)d_in[7];
  const float* bi2 = (const float*)d_in[8];
  const float* Wq  = (const float*)d_in[9];
  const float* bq  = (const float*)d_in[10];
  const float* Wk  = (const float*)d_in[11];
  const float* bk  = (const float*)d_in[12];  // cancels in softmax (shift-invariance)
  const float* Wu1 = (const float*)d_in[13];
  const float* bu1 = (const float*)d_in[14];
  const float* Wu2 = (const float*)d_in[15];
  const float* bu2 = (const float*)d_in[16];
  (void)bk;

  char* ws = (char*)d_ws;
  bf16*  Wi1p  = (bf16*)(ws + 0);            // 40960 el  (81920 B)
  bf16*  Wi2p  = (bf16*)(ws + 81920);        // 65536 el  (131072 B) -> 212992
  bf16*  Wu1p  = (bf16*)(ws + 212992);       // 98304 el  (196608 B) -> 409600
  bf16*  Wu2p  = (bf16*)(ws + 409600);       // 65536 el  (131072 B) -> 540672
  float* Wqkf  = (float*)(ws + 540672);      // 129*256 fp32 (132096 B) -> 672768
  bf16*  Wqkp  = (bf16*)(ws + 672768);       // 4*16*512 el (65536 B) -> 738304
  bf16*  A1p   = (bf16*)(ws + 738304);       // 100000*160*2 = 32,000,000 -> 32,738,304
  float* Qt    = (float*)(ws + 738304);      // 16384*256*4 = 16,777,216 (aliases A1p)
  bf16*  h_buf    = (bf16*)(ws + 32738304);  // 100000*256*2 -> 83,938,304
  bf16*  item_emb = (bf16*)(ws + 83938304);  // 100000*256*2 -> 135,138,304
  bf16*  fusedA   = (bf16*)(ws + 135138304); // 16384*384*2 -> 147,721,216
  bf16*  hu_buf   = (bf16*)(ws + 147721216); // 16384*256*2 -> 156,109,824

  // ---- packing / folding ----
  k_prep_w<<<160, 256, 0, stream>>>(Wi1, Wi1p, 130, 5, 16);
  k_prep_w<<<256, 256, 0, stream>>>(Wi2, Wi2p, 256, 8, 16);
  k_prep_w<<<384, 256, 0, stream>>>(Wu1, Wu1p, 384, 12, 16);
  k_prep_w<<<256, 256, 0, stream>>>(Wu2, Wu2p, 256, 8, 16);
  k_fold<<<17, 256, 0, stream>>>(Wq, Wk, bq, Wqkf);
  k_prep_w<<<128, 256, 0, stream>>>(Wqkf, Wqkp, 128, 4, 16);
  k_prep_a1<<<62500, 256, 0, stream>>>(item_feat, gcn_item, A1p);
  k_prep_user<<<8192, 256, 0, stream>>>(gcn_user, fusedA);

  // ---- item tower ----
  const int itiles = NITEMS / 32;            // 3125
  const int iblk = (itiles + 3) / 4;         // 782
  k_gemm<5, 16, 0, 2><<<iblk, 256, 0, stream>>>(A1p, Wi1p, bi1, h_buf, itiles, 160);
  k_gemm<8, 16, 1, 2><<<iblk, 256, 0, stream>>>(h_buf, Wi2p, bi2, item_emb, itiles, 256);

  // ---- user tower ----
  const int utiles = NUSERS / 32;            // 512
  const int ublk = utiles / 4;               // 128
  k_gemm<4, 16, 4, 2><<<ublk, 256, 0, stream>>>(fusedA, Wqkp, Wqkf + 128 * 256, Qt, utiles, 384);
  k_user_attn<<<NUSERS, 256, 0, stream>>>(Qt, hist_idx, hist_len, item_emb, fusedA);
  k_gemm<12, 16, 0, 2><<<ublk, 256, 0, stream>>>(fusedA, Wu1p, bu1, hu_buf, utiles, 384);
  k_gemm<8, 16, 3, 2><<<ublk, 256, 0, stream>>>(hu_buf, Wu2p, bu2, (float*)d_out, utiles, 256);
}

// Round 5
// 280.053 us; speedup vs baseline: 5.0444x; 1.0991x over previous
//
#include <hip/hip_runtime.h>
#include <hip/hip_bf16.h>
#include <math.h>

#define NITEMS 100000
#define NUSERS 16384
#define HLEN   48
#define GCN    128
#define ATTN_D 128
#define HID    256
#define TOW    256

typedef __attribute__((ext_vector_type(8))) short short8;
typedef __attribute__((ext_vector_type(4))) float f32x4;
typedef __hip_bfloat16 bf16;

static __device__ __forceinline__ float bfu(unsigned short u) {
  unsigned int x = ((unsigned int)u) << 16;
  float f; __builtin_memcpy(&f, &x, 4); return f;
}
static __device__ __forceinline__ short f2bf(float v) {
  bf16 h = __float2bfloat16(v);
  short s; __builtin_memcpy(&s, &h, 2); return s;
}

// ---------------------------------------------------------------------------
// Prep: pack fp32 weight [Korig][N] -> bf16 fragment-ordered buffer
// out[((ks*NT + ct)*64 + lane)*8 + i] = W[ks*32 + (lane>>4)*8 + i][ct*16 + (lane&15)]
// ---------------------------------------------------------------------------
__global__ __launch_bounds__(256) void k_prep_w(const float* __restrict__ W,
                                                bf16* __restrict__ out,
                                                int Korig, int KS, int NT) {
  int tid = blockIdx.x * 256 + threadIdx.x;
  int total = KS * NT * 512;
  if (tid >= total) return;
  int i  = tid & 7;
  int l  = (tid >> 3) & 63;
  int ct = (tid >> 9) % NT;
  int ks = (tid >> 9) / NT;
  int k   = ks * 32 + ((l >> 4) << 3) + i;
  int col = ct * 16 + (l & 15);
  int N = NT * 16;
  float v = (k < Korig) ? W[(size_t)k * N + col] : 0.f;
  out[tid] = __float2bfloat16(v);
}

__global__ __launch_bounds__(256) void k_prep_user(const float* __restrict__ gcn_user,
                                                   bf16* __restrict__ fused) {
  int tid = blockIdx.x * 256 + threadIdx.x;
  if (tid >= NUSERS * GCN) return;
  int k = tid & 127;
  int u = tid >> 7;
  fused[(size_t)u * (GCN + TOW) + k] = __float2bfloat16(gcn_user[tid]);
}

// ---------------------------------------------------------------------------
// Fold: Wqk[g][t] = (1/sqrt(128)) * sum_d Wq[g][d] * Wk[t][d]   (g<128)
//       b~[t]    = (1/sqrt(128)) * sum_d bq[d]    * Wk[t][d]    (block 16)
// ---------------------------------------------------------------------------
__global__ __launch_bounds__(256) void k_fold(const float* __restrict__ Wq,
                                              const float* __restrict__ Wk,
                                              const float* __restrict__ bq,
                                              float* __restrict__ out) {
  const float INV_S = 0.08838834764831845f;
  const int t = threadIdx.x;
  const int b = blockIdx.x;
  if (b < 16) {
    __shared__ float wq[8][128];
    for (int s = t; s < 8 * 128; s += 256)
      wq[s >> 7][s & 127] = Wq[(size_t)(b * 8 + (s >> 7)) * ATTN_D + (s & 127)];
    __syncthreads();
    float acc[8] = {0.f, 0.f, 0.f, 0.f, 0.f, 0.f, 0.f, 0.f};
    for (int d = 0; d < 128; ++d) {
      const float wk = Wk[(size_t)t * ATTN_D + d];
      #pragma unroll
      for (int gg = 0; gg < 8; ++gg) acc[gg] = fmaf(wq[gg][d], wk, acc[gg]);
    }
    #pragma unroll
    for (int gg = 0; gg < 8; ++gg)
      out[(size_t)(b * 8 + gg) * TOW + t] = acc[gg] * INV_S;
  } else {
    float a = 0.f;
    for (int d = 0; d < 128; ++d)
      a = fmaf(bq[d], Wk[(size_t)t * ATTN_D + d], a);
    out[(size_t)128 * TOW + t] = a * INV_S;
  }
}

// ---------------------------------------------------------------------------
// Item GEMM1 fused with input packing: h = relu([feat,gcn]@Wi1+bi1), A built
// in-register from fp32 sources. 32 rows/wave, 4 waves/block. 3125 tiles.
// ---------------------------------------------------------------------------
__global__ __launch_bounds__(256) void k_item_g1(
    const float* __restrict__ feat,
    const float* __restrict__ gcn,
    const bf16* __restrict__ Wf,       // packed KS=5, NT=16
    const float* __restrict__ bias,
    bf16* __restrict__ h_out)
{
  const int l   = threadIdx.x & 63;
  const int wid = threadIdx.x >> 6;
  const int tile = blockIdx.x * 4 + wid;
  if (tile >= NITEMS / 32) return;
  const int r = l & 15, g = l >> 4;

  f32x4 acc[2][16];
  #pragma unroll
  for (int mr = 0; mr < 2; ++mr)
    #pragma unroll
    for (int ct = 0; ct < 16; ++ct) acc[mr][ct] = (f32x4){0.f, 0.f, 0.f, 0.f};

  const bf16* wf = Wf + (size_t)l * 8;

  #pragma unroll
  for (int ks = 0; ks < 5; ++ks) {
    const int k0 = ks * 32 + g * 8;
    short8 a[2];
    #pragma unroll
    for (int mr = 0; mr < 2; ++mr) {
      const size_t row = (size_t)tile * 32 + mr * 16 + r;
      short8 v = (short8){0, 0, 0, 0, 0, 0, 0, 0};
      if (k0 == 0) {
        v[0] = f2bf(feat[row * 2]);
        v[1] = f2bf(feat[row * 2 + 1]);
        const float* p = gcn + row * GCN;
        #pragma unroll
        for (int i = 2; i < 8; ++i) v[i] = f2bf(p[i - 2]);
      } else if (k0 <= 120) {
        const float* p = gcn + row * GCN + (k0 - 2);
        #pragma unroll
        for (int i = 0; i < 8; ++i) v[i] = f2bf(p[i]);
      } else if (k0 == 128) {
        const float* p = gcn + row * GCN;
        v[0] = f2bf(p[126]);
        v[1] = f2bf(p[127]);
      }
      a[mr] = v;
    }
    #pragma unroll
    for (int ct = 0; ct < 16; ++ct) {
      short8 b = *(const short8*)(wf + (size_t)(ks * 16 + ct) * 512);
      #pragma unroll
      for (int mr = 0; mr < 2; ++mr)
        acc[mr][ct] = __builtin_amdgcn_mfma_f32_16x16x32_bf16(a[mr], b, acc[mr][ct], 0, 0, 0);
    }
  }

  #pragma unroll
  for (int mr = 0; mr < 2; ++mr)
    #pragma unroll
    for (int ct = 0; ct < 16; ++ct) {
      const float bj = bias[ct * 16 + r];
      #pragma unroll
      for (int i = 0; i < 4; ++i) {
        float v = fmaxf(acc[mr][ct][i] + bj, 0.f);
        h_out[(size_t)(tile * 32 + mr * 16 + g * 4 + i) * HID + ct * 16 + r] =
            __float2bfloat16(v);
      }
    }
}

// ---------------------------------------------------------------------------
// Generic MFMA GEMM, MR row-frags (16 rows each) per wave, 4 waves/block.
// MODE 0: relu->bf16; 1: l2norm->bf16; 2: plain->bf16; 3: l2norm->fp32; 4: plain->fp32
// ---------------------------------------------------------------------------
template<int KS, int NT, int MODE, int MR>
__global__ __launch_bounds__(256) void k_gemm(
    const bf16* __restrict__ A,
    const bf16* __restrict__ Wf,
    const float* __restrict__ bias,
    void* __restrict__ Cout,
    int Mtiles, int Astride)
{
  const int l   = threadIdx.x & 63;
  const int wid = threadIdx.x >> 6;
  const int tile = blockIdx.x * 4 + wid;
  if (tile >= Mtiles) return;
  const int N = NT * 16;
  const int r = l & 15, g = l >> 4;

  f32x4 acc[MR][NT];
  #pragma unroll
  for (int mr = 0; mr < MR; ++mr)
    #pragma unroll
    for (int ct = 0; ct < NT; ++ct) acc[mr][ct] = (f32x4){0.f, 0.f, 0.f, 0.f};

  const bf16* arow[MR];
  #pragma unroll
  for (int mr = 0; mr < MR; ++mr)
    arow[mr] = A + (size_t)(tile * (16 * MR) + mr * 16 + r) * Astride + g * 8;
  const bf16* wf = Wf + (size_t)l * 8;

  for (int ks = 0; ks < KS; ++ks) {
    short8 a[MR];
    #pragma unroll
    for (int mr = 0; mr < MR; ++mr) a[mr] = *(const short8*)(arow[mr] + ks * 32);
    #pragma unroll
    for (int ct = 0; ct < NT; ++ct) {
      short8 b = *(const short8*)(wf + (size_t)(ks * NT + ct) * 512);
      #pragma unroll
      for (int mr = 0; mr < MR; ++mr)
        acc[mr][ct] = __builtin_amdgcn_mfma_f32_16x16x32_bf16(a[mr], b, acc[mr][ct], 0, 0, 0);
    }
  }

  #pragma unroll
  for (int mr = 0; mr < MR; ++mr) {
    #pragma unroll
    for (int ct = 0; ct < NT; ++ct) {
      const float bj = bias[ct * 16 + r];
      #pragma unroll
      for (int i = 0; i < 4; ++i) acc[mr][ct][i] += bj;
    }
  }

  if (MODE == 0 || MODE == 2 || MODE == 4) {
    #pragma unroll
    for (int mr = 0; mr < MR; ++mr)
      #pragma unroll
      for (int ct = 0; ct < NT; ++ct)
        #pragma unroll
        for (int i = 0; i < 4; ++i) {
          float v = acc[mr][ct][i];
          if (MODE == 0) v = fmaxf(v, 0.f);
          size_t off = (size_t)(tile * (16 * MR) + mr * 16 + g * 4 + i) * N + ct * 16 + r;
          if (MODE == 4) ((float*)Cout)[off] = v;
          else           ((bf16*)Cout)[off]  = __float2bfloat16(v);
        }
  } else {
    #pragma unroll
    for (int mr = 0; mr < MR; ++mr) {
      float s[4] = {0.f, 0.f, 0.f, 0.f};
      #pragma unroll
      for (int ct = 0; ct < NT; ++ct)
        #pragma unroll
        for (int i = 0; i < 4; ++i) s[i] += acc[mr][ct][i] * acc[mr][ct][i];
      #pragma unroll
      for (int off = 1; off < 16; off <<= 1) {
        #pragma unroll
        for (int i = 0; i < 4; ++i) s[i] += __shfl_xor(s[i], off);
      }
      float rn[4];
      #pragma unroll
      for (int i = 0; i < 4; ++i) rn[i] = 1.f / fmaxf(sqrtf(s[i]), 1e-12f);
      #pragma unroll
      for (int ct = 0; ct < NT; ++ct)
        #pragma unroll
        for (int i = 0; i < 4; ++i) {
          size_t off = (size_t)(tile * (16 * MR) + mr * 16 + g * 4 + i) * N + ct * 16 + r;
          float v = acc[mr][ct][i] * rn[i];
          if (MODE == 3) ((float*)Cout)[off] = v;
          else           ((bf16*)Cout)[off]  = __float2bfloat16(v);
        }
    }
  }
}

// ---------------------------------------------------------------------------
// Attention v4: 1 user/block. Only len+1 (rounded up to 8) rows gathered,
// scored, and accumulated; bounds are block-uniform so no divergence.
// ---------------------------------------------------------------------------
__global__ __launch_bounds__(256) void k_user_attn(
    const float* __restrict__ Qt,          // [NUSERS][TOW] fp32
    const int*   __restrict__ hist_idx,
    const int*   __restrict__ hist_len,
    const bf16*  __restrict__ item_emb,    // [NITEMS][TOW] bf16
    bf16* __restrict__ fused)
{
  const int u = blockIdx.x;
  const int j = threadIdx.x;
  const int wid = j >> 6, lane = j & 63;
  __shared__ int    idx[HLEN];
  __shared__ ushort emb[HLEN][TOW];
  __shared__ float  sc[HLEN];
  __shared__ float  attn[HLEN];

  const int nv = hist_len[u] + 1;        // 1..48 valid entries
  const int n8 = (nv + 7) & ~7;          // staged rows (multiple of 8)

  if (j < HLEN) idx[j] = hist_idx[u * HLEN + j];
  __syncthreads();

  // ---- stage n8 emb rows into LDS (8 rows/sweep, 16B/lane; pad rows = 0) ----
  {
    const int r0 = j >> 5;          // 0..7
    const int c  = (j & 31) * 8;    // element offset
    for (int s = 0; s < n8; s += 8) {
      const int h = s + r0;
      short8 v = (short8){0, 0, 0, 0, 0, 0, 0, 0};
      if (h < nv) v = *(const short8*)(item_emb + (size_t)idx[h] * TOW + c);
      *(short8*)(&emb[h][c]) = v;
    }
  }
  __syncthreads();

  // ---- scores: wave wid handles h = wid, wid+4, ... < nv ----
  const f32x4 q = *(const f32x4*)(Qt + (size_t)u * TOW + 4 * lane);
  for (int h = wid; h < nv; h += 4) {
    ushort4 e = *(const ushort4*)(&emb[h][4 * lane]);
    float a = q.x * bfu(e.x) + q.y * bfu(e.y) + q.z * bfu(e.z) + q.w * bfu(e.w);
    #pragma unroll
    for (int off = 32; off; off >>= 1) a += __shfl_xor(a, off);
    if (lane == 0) sc[h] = a;   // 1/sqrt(128) folded into Wqk/b~
  }
  __syncthreads();

  // ---- softmax (wave 0, lane-parallel); attn[h]=0 for h>=nv ----
  if (wid == 0) {
    const bool valid = lane < nv;
    float x = valid ? sc[lane] : -1e30f;
    float m = x;
    #pragma unroll
    for (int off = 32; off; off >>= 1) m = fmaxf(m, __shfl_xor(m, off));
    float e = valid ? expf(x - m) : 0.f;
    float s = e;
    #pragma unroll
    for (int off = 32; off; off >>= 1) s += __shfl_xor(s, off);
    if (lane < HLEN) attn[lane] = e / s;
  }
  __syncthreads();

  // ---- PV from LDS over n8 rows (pad rows: attn=0, emb=0) ----
  float hv0 = 0.f, hv1 = 0.f, hv2 = 0.f, hv3 = 0.f;
  for (int h = 0; h < n8; h += 8) {
    hv0 = fmaf(attn[h + 0], bfu(emb[h + 0][j]), hv0);
    hv1 = fmaf(attn[h + 1], bfu(emb[h + 1][j]), hv1);
    hv2 = fmaf(attn[h + 2], bfu(emb[h + 2][j]), hv2);
    hv3 = fmaf(attn[h + 3], bfu(emb[h + 3][j]), hv3);
    hv0 = fmaf(attn[h + 4], bfu(emb[h + 4][j]), hv0);
    hv1 = fmaf(attn[h + 5], bfu(emb[h + 5][j]), hv1);
    hv2 = fmaf(attn[h + 6], bfu(emb[h + 6][j]), hv2);
    hv3 = fmaf(attn[h + 7], bfu(emb[h + 7][j]), hv3);
  }
  fused[(size_t)u * (GCN + TOW) + GCN + j] = __float2bfloat16((hv0 + hv1) + (hv2 + hv3));
}

// ---------------------------------------------------------------------------
extern "C" void kernel_launch(void* const* d_in, const int* in_sizes, int n_in,
                              void* d_out, int out_size, void* d_ws, size_t ws_size,
                              hipStream_t stream) {
  const float* item_feat = (const float*)d_in[0];
  const float* gcn_item  = (const float*)d_in[1];
  const float* gcn_user  = (const float*)d_in[2];
  const int*   hist_idx  = (const int*)d_in[3];
  const int*   hist_len  = (const int*)d_in[4];
  const float* Wi1 = (const float*)d_in[5];
  const float* bi1 = (const float*)d_in[6];
  const float* Wi2 = (const float*)d_in[7];
  const float* bi2 = (const float*)d_in[8];
  const float* Wq  = (const float*)d_in[9];
  const float* bq  = (const float*)d_in[10];
  const float* Wk  = (const float*)d_in[11];
  const float* bk  = (const float*)d_in[12];  // cancels in softmax (shift-invariance)
  const float* Wu1 = (const float*)d_in[13];
  const float* bu1 = (const float*)d_in[14];
  const float* Wu2 = (const float*)d_in[15];
  const float* bu2 = (const float*)d_in[16];
  (void)bk;

  char* ws = (char*)d_ws;
  bf16*  Wi1p  = (bf16*)(ws + 0);            // 81920 B
  bf16*  Wi2p  = (bf16*)(ws + 81920);        // 131072 B -> 212992
  bf16*  Wu1p  = (bf16*)(ws + 212992);       // 196608 B -> 409600
  bf16*  Wu2p  = (bf16*)(ws + 409600);       // 131072 B -> 540672
  float* Wqkf  = (float*)(ws + 540672);      // 132096 B -> 672768
  bf16*  Wqkp  = (bf16*)(ws + 672768);       // 65536 B -> 738304
  float* Qt    = (float*)(ws + 738304);      // 16384*256*4 = 16,777,216 -> 17,515,520
  bf16*  h_buf    = (bf16*)(ws + 17515520);  // 100000*256*2 -> 68,715,520
  bf16*  item_emb = (bf16*)(ws + 68715520);  // 100000*256*2 -> 119,915,520
  bf16*  fusedA   = (bf16*)(ws + 119915520); // 16384*384*2 -> 132,498,432
  bf16*  hu_buf   = (bf16*)(ws + 132498432); // 16384*256*2 -> 140,886,016

  // ---- packing / folding ----
  k_prep_w<<<160, 256, 0, stream>>>(Wi1, Wi1p, 130, 5, 16);
  k_prep_w<<<256, 256, 0, stream>>>(Wi2, Wi2p, 256, 8, 16);
  k_prep_w<<<384, 256, 0, stream>>>(Wu1, Wu1p, 384, 12, 16);
  k_prep_w<<<256, 256, 0, stream>>>(Wu2, Wu2p, 256, 8, 16);
  k_fold<<<17, 256, 0, stream>>>(Wq, Wk, bq, Wqkf);
  k_prep_w<<<128, 256, 0, stream>>>(Wqkf, Wqkp, 128, 4, 16);
  k_prep_user<<<8192, 256, 0, stream>>>(gcn_user, fusedA);

  // ---- item tower ----
  const int itiles = NITEMS / 32;            // 3125
  const int iblk = (itiles + 3) / 4;         // 782
  k_item_g1<<<iblk, 256, 0, stream>>>(item_feat, gcn_item, Wi1p, bi1, h_buf);
  k_gemm<8, 16, 1, 2><<<iblk, 256, 0, stream>>>(h_buf, Wi2p, bi2, item_emb, itiles, 256);

  // ---- user tower ----
  const int utiles = NUSERS / 32;            // 512
  const int ublk = utiles / 4;               // 128
  k_gemm<4, 16, 4, 2><<<ublk, 256, 0, stream>>>(fusedA, Wqkp, Wqkf + 128 * 256, Qt, utiles, 384);
  k_user_attn<<<NUSERS, 256, 0, stream>>>(Qt, hist_idx, hist_len, item_emb, fusedA);
  k_gemm<12, 16, 0, 2><<<ublk, 256, 0, stream>>>(fusedA, Wu1p, bu1, hu_buf, utiles, 384);
  k_gemm<8, 16, 3, 2><<<ublk, 256, 0, stream>>>(hu_buf, Wu2p, bu2, (float*)d_out, utiles, 256);
}

// Round 6
// 270.773 us; speedup vs baseline: 5.2173x; 1.0343x over previous
//
#include <hip/hip_runtime.h>
#include <hip/hip_bf16.h>
#include <math.h>

#define NITEMS 100000
#define NUSERS 16384
#define HLEN   48
#define GCN    128
#define ATTN_D 128
#define HID    256
#define TOW    256

typedef __attribute__((ext_vector_type(8))) short short8;
typedef __attribute__((ext_vector_type(4))) float f32x4;
typedef __hip_bfloat16 bf16;

static __device__ __forceinline__ float bfu(unsigned short u) {
  unsigned int x = ((unsigned int)u) << 16;
  float f; __builtin_memcpy(&f, &x, 4); return f;
}
static __device__ __forceinline__ short f2bf(float v) {
  bf16 h = __float2bfloat16(v);
  short s; __builtin_memcpy(&s, &h, 2); return s;
}

// ---------------------------------------------------------------------------
// Prep: pack fp32 weight [Korig][N] -> bf16 fragment-ordered buffer.
// perm=1: source row permuted gcn-first (srck = k<128 ? k+2 : k-128), matching
// the A1p layout [gcn(128), feat(2), pad(30)].
// out[((ks*NT + ct)*64 + lane)*8 + i] = W[src(ks*32 + (lane>>4)*8 + i)][ct*16 + (lane&15)]
// ---------------------------------------------------------------------------
__global__ __launch_bounds__(256) void k_prep_w(const float* __restrict__ W,
                                                bf16* __restrict__ out,
                                                int Korig, int KS, int NT, int perm) {
  int tid = blockIdx.x * 256 + threadIdx.x;
  int total = KS * NT * 512;
  if (tid >= total) return;
  int i  = tid & 7;
  int l  = (tid >> 3) & 63;
  int ct = (tid >> 9) % NT;
  int ks = (tid >> 9) / NT;
  int k   = ks * 32 + ((l >> 4) << 3) + i;
  int col = ct * 16 + (l & 15);
  int N = NT * 16;
  int srck = perm ? ((k < 128) ? (k + 2) : (k - 128)) : k;
  float v = (k < Korig) ? W[(size_t)srck * N + col] : 0.f;
  out[tid] = __float2bfloat16(v);
}

// ---------------------------------------------------------------------------
// Prep item A: A1p[row] = [gcn(128), feat(2), pad(30)] bf16, K=160.
// 20 threads/row; t<16: two float4 loads of gcn, t==16: feat; all stores 16B.
// ---------------------------------------------------------------------------
__global__ __launch_bounds__(256) void k_prep_a1(const float* __restrict__ feat,
                                                 const float* __restrict__ gcn,
                                                 bf16* __restrict__ out) {
  int tid = blockIdx.x * 256 + threadIdx.x;
  if (tid >= NITEMS * 20) return;
  int t = tid % 20;
  size_t row = tid / 20;
  short8 v = (short8){0, 0, 0, 0, 0, 0, 0, 0};
  if (t < 16) {
    const float4* p = (const float4*)(gcn + row * GCN + 8 * t);
    float4 a = p[0], b = p[1];
    v[0] = f2bf(a.x); v[1] = f2bf(a.y); v[2] = f2bf(a.z); v[3] = f2bf(a.w);
    v[4] = f2bf(b.x); v[5] = f2bf(b.y); v[6] = f2bf(b.z); v[7] = f2bf(b.w);
  } else if (t == 16) {
    v[0] = f2bf(feat[row * 2]);
    v[1] = f2bf(feat[row * 2 + 1]);
  }
  *(short8*)(out + row * 160 + 8 * t) = v;
}

__global__ __launch_bounds__(256) void k_prep_user(const float* __restrict__ gcn_user,
                                                   bf16* __restrict__ fused) {
  int tid = blockIdx.x * 256 + threadIdx.x;
  if (tid >= NUSERS * GCN) return;
  int k = tid & 127;
  int u = tid >> 7;
  fused[(size_t)u * (GCN + TOW) + k] = __float2bfloat16(gcn_user[tid]);
}

// ---------------------------------------------------------------------------
// Fold: Wqk[g][t] = (1/sqrt(128)) * sum_d Wq[g][d] * Wk[t][d]   (g<128)
//       b~[t]    = (1/sqrt(128)) * sum_d bq[d]    * Wk[t][d]    (block 16)
// ---------------------------------------------------------------------------
__global__ __launch_bounds__(256) void k_fold(const float* __restrict__ Wq,
                                              const float* __restrict__ Wk,
                                              const float* __restrict__ bq,
                                              float* __restrict__ out) {
  const float INV_S = 0.08838834764831845f;
  const int t = threadIdx.x;
  const int b = blockIdx.x;
  if (b < 16) {
    __shared__ float wq[8][128];
    for (int s = t; s < 8 * 128; s += 256)
      wq[s >> 7][s & 127] = Wq[(size_t)(b * 8 + (s >> 7)) * ATTN_D + (s & 127)];
    __syncthreads();
    float acc[8] = {0.f, 0.f, 0.f, 0.f, 0.f, 0.f, 0.f, 0.f};
    for (int d = 0; d < 128; ++d) {
      const float wk = Wk[(size_t)t * ATTN_D + d];
      #pragma unroll
      for (int gg = 0; gg < 8; ++gg) acc[gg] = fmaf(wq[gg][d], wk, acc[gg]);
    }
    #pragma unroll
    for (int gg = 0; gg < 8; ++gg)
      out[(size_t)(b * 8 + gg) * TOW + t] = acc[gg] * INV_S;
  } else {
    float a = 0.f;
    for (int d = 0; d < 128; ++d)
      a = fmaf(bq[d], Wk[(size_t)t * ATTN_D + d], a);
    out[(size_t)128 * TOW + t] = a * INV_S;
  }
}

// ---------------------------------------------------------------------------
// Generic MFMA GEMM, MR row-frags (16 rows each) per wave, 4 waves/block.
// MODE 0: relu->bf16; 1: l2norm->bf16; 2: plain->bf16; 3: l2norm->fp32; 4: plain->fp32
// ---------------------------------------------------------------------------
template<int KS, int NT, int MODE, int MR>
__global__ __launch_bounds__(256) void k_gemm(
    const bf16* __restrict__ A,
    const bf16* __restrict__ Wf,
    const float* __restrict__ bias,
    void* __restrict__ Cout,
    int Mtiles, int Astride)
{
  const int l   = threadIdx.x & 63;
  const int wid = threadIdx.x >> 6;
  const int tile = blockIdx.x * 4 + wid;
  if (tile >= Mtiles) return;
  const int N = NT * 16;
  const int r = l & 15, g = l >> 4;

  f32x4 acc[MR][NT];
  #pragma unroll
  for (int mr = 0; mr < MR; ++mr)
    #pragma unroll
    for (int ct = 0; ct < NT; ++ct) acc[mr][ct] = (f32x4){0.f, 0.f, 0.f, 0.f};

  const bf16* arow[MR];
  #pragma unroll
  for (int mr = 0; mr < MR; ++mr)
    arow[mr] = A + (size_t)(tile * (16 * MR) + mr * 16 + r) * Astride + g * 8;
  const bf16* wf = Wf + (size_t)l * 8;

  for (int ks = 0; ks < KS; ++ks) {
    short8 a[MR];
    #pragma unroll
    for (int mr = 0; mr < MR; ++mr) a[mr] = *(const short8*)(arow[mr] + ks * 32);
    #pragma unroll
    for (int ct = 0; ct < NT; ++ct) {
      short8 b = *(const short8*)(wf + (size_t)(ks * NT + ct) * 512);
      #pragma unroll
      for (int mr = 0; mr < MR; ++mr)
        acc[mr][ct] = __builtin_amdgcn_mfma_f32_16x16x32_bf16(a[mr], b, acc[mr][ct], 0, 0, 0);
    }
  }

  #pragma unroll
  for (int mr = 0; mr < MR; ++mr) {
    #pragma unroll
    for (int ct = 0; ct < NT; ++ct) {
      const float bj = bias[ct * 16 + r];
      #pragma unroll
      for (int i = 0; i < 4; ++i) acc[mr][ct][i] += bj;
    }
  }

  if (MODE == 0 || MODE == 2 || MODE == 4) {
    #pragma unroll
    for (int mr = 0; mr < MR; ++mr)
      #pragma unroll
      for (int ct = 0; ct < NT; ++ct)
        #pragma unroll
        for (int i = 0; i < 4; ++i) {
          float v = acc[mr][ct][i];
          if (MODE == 0) v = fmaxf(v, 0.f);
          size_t off = (size_t)(tile * (16 * MR) + mr * 16 + g * 4 + i) * N + ct * 16 + r;
          if (MODE == 4) ((float*)Cout)[off] = v;
          else           ((bf16*)Cout)[off]  = __float2bfloat16(v);
        }
  } else {
    #pragma unroll
    for (int mr = 0; mr < MR; ++mr) {
      float s[4] = {0.f, 0.f, 0.f, 0.f};
      #pragma unroll
      for (int ct = 0; ct < NT; ++ct)
        #pragma unroll
        for (int i = 0; i < 4; ++i) s[i] += acc[mr][ct][i] * acc[mr][ct][i];
      #pragma unroll
      for (int off = 1; off < 16; off <<= 1) {
        #pragma unroll
        for (int i = 0; i < 4; ++i) s[i] += __shfl_xor(s[i], off);
      }
      float rn[4];
      #pragma unroll
      for (int i = 0; i < 4; ++i) rn[i] = 1.f / fmaxf(sqrtf(s[i]), 1e-12f);
      #pragma unroll
      for (int ct = 0; ct < NT; ++ct)
        #pragma unroll
        for (int i = 0; i < 4; ++i) {
          size_t off = (size_t)(tile * (16 * MR) + mr * 16 + g * 4 + i) * N + ct * 16 + r;
          float v = acc[mr][ct][i] * rn[i];
          if (MODE == 3) ((float*)Cout)[off] = v;
          else           ((bf16*)Cout)[off]  = __float2bfloat16(v);
        }
    }
  }
}

// ---------------------------------------------------------------------------
// Attention v4: 1 user/block. Only len+1 (rounded up to 8) rows gathered,
// scored, and accumulated; bounds are block-uniform so no divergence.
// ---------------------------------------------------------------------------
__global__ __launch_bounds__(256) void k_user_attn(
    const float* __restrict__ Qt,          // [NUSERS][TOW] fp32
    const int*   __restrict__ hist_idx,
    const int*   __restrict__ hist_len,
    const bf16*  __restrict__ item_emb,    // [NITEMS][TOW] bf16
    bf16* __restrict__ fused)
{
  const int u = blockIdx.x;
  const int j = threadIdx.x;
  const int wid = j >> 6, lane = j & 63;
  __shared__ int    idx[HLEN];
  __shared__ ushort emb[HLEN][TOW];
  __shared__ float  sc[HLEN];
  __shared__ float  attn[HLEN];

  const int nv = hist_len[u] + 1;        // 1..48 valid entries
  const int n8 = (nv + 7) & ~7;          // staged rows (multiple of 8)

  if (j < HLEN) idx[j] = hist_idx[u * HLEN + j];
  __syncthreads();

  // ---- stage n8 emb rows into LDS (8 rows/sweep, 16B/lane; pad rows = 0) ----
  {
    const int r0 = j >> 5;          // 0..7
    const int c  = (j & 31) * 8;    // element offset
    for (int s = 0; s < n8; s += 8) {
      const int h = s + r0;
      short8 v = (short8){0, 0, 0, 0, 0, 0, 0, 0};
      if (h < nv) v = *(const short8*)(item_emb + (size_t)idx[h] * TOW + c);
      *(short8*)(&emb[h][c]) = v;
    }
  }
  __syncthreads();

  // ---- scores: wave wid handles h = wid, wid+4, ... < nv ----
  const f32x4 q = *(const f32x4*)(Qt + (size_t)u * TOW + 4 * lane);
  for (int h = wid; h < nv; h += 4) {
    ushort4 e = *(const ushort4*)(&emb[h][4 * lane]);
    float a = q.x * bfu(e.x) + q.y * bfu(e.y) + q.z * bfu(e.z) + q.w * bfu(e.w);
    #pragma unroll
    for (int off = 32; off; off >>= 1) a += __shfl_xor(a, off);
    if (lane == 0) sc[h] = a;   // 1/sqrt(128) folded into Wqk/b~
  }
  __syncthreads();

  // ---- softmax (wave 0, lane-parallel); attn[h]=0 for h>=nv ----
  if (wid == 0) {
    const bool valid = lane < nv;
    float x = valid ? sc[lane] : -1e30f;
    float m = x;
    #pragma unroll
    for (int off = 32; off; off >>= 1) m = fmaxf(m, __shfl_xor(m, off));
    float e = valid ? expf(x - m) : 0.f;
    float s = e;
    #pragma unroll
    for (int off = 32; off; off >>= 1) s += __shfl_xor(s, off);
    if (lane < HLEN) attn[lane] = e / s;
  }
  __syncthreads();

  // ---- PV from LDS over n8 rows (pad rows: attn=0, emb=0) ----
  float hv0 = 0.f, hv1 = 0.f, hv2 = 0.f, hv3 = 0.f;
  for (int h = 0; h < n8; h += 8) {
    hv0 = fmaf(attn[h + 0], bfu(emb[h + 0][j]), hv0);
    hv1 = fmaf(attn[h + 1], bfu(emb[h + 1][j]), hv1);
    hv2 = fmaf(attn[h + 2], bfu(emb[h + 2][j]), hv2);
    hv3 = fmaf(attn[h + 3], bfu(emb[h + 3][j]), hv3);
    hv0 = fmaf(attn[h + 4], bfu(emb[h + 4][j]), hv0);
    hv1 = fmaf(attn[h + 5], bfu(emb[h + 5][j]), hv1);
    hv2 = fmaf(attn[h + 6], bfu(emb[h + 6][j]), hv2);
    hv3 = fmaf(attn[h + 7], bfu(emb[h + 7][j]), hv3);
  }
  fused[(size_t)u * (GCN + TOW) + GCN + j] = __float2bfloat16((hv0 + hv1) + (hv2 + hv3));
}

// ---------------------------------------------------------------------------
extern "C" void kernel_launch(void* const* d_in, const int* in_sizes, int n_in,
                              void* d_out, int out_size, void* d_ws, size_t ws_size,
                              hipStream_t stream) {
  const float* item_feat = (const float*)d_in[0];
  const float* gcn_item  = (const float*)d_in[1];
  const float* gcn_user  = (const float*)d_in[2];
  const int*   hist_idx  = (const int*)d_in[3];
  const int*   hist_len  = (const int*)d_in[4];
  const float* Wi1 = (const float*)d_in[5];
  const float* bi1 = (const float*)d_in[6];
  const float* Wi2 = (const float*)d_in[7];
  const float* bi2 = (const float*)d_in[8];
  const float* Wq  = (const float*)d_in[9];
  const float* bq  = (const float*)d_in[10];
  const float* Wk  = (const float*)d_in[11];
  const float* bk  = (const float*)d_in[12];  // cancels in softmax (shift-invariance)
  const float* Wu1 = (const float*)d_in[13];
  const float* bu1 = (const float*)d_in[14];
  const float* Wu2 = (const float*)d_in[15];
  const float* bu2 = (const float*)d_in[16];
  (void)bk;

  char* ws = (char*)d_ws;
  bf16*  Wi1p  = (bf16*)(ws + 0);            // 81920 B
  bf16*  Wi2p  = (bf16*)(ws + 81920);        // 131072 B -> 212992
  bf16*  Wu1p  = (bf16*)(ws + 212992);       // 196608 B -> 409600
  bf16*  Wu2p  = (bf16*)(ws + 409600);       // 131072 B -> 540672
  float* Wqkf  = (float*)(ws + 540672);      // 132096 B -> 672768
  bf16*  Wqkp  = (bf16*)(ws + 672768);       // 65536 B -> 738304
  bf16*  A1p   = (bf16*)(ws + 738304);       // 100000*160*2 = 32,000,000 -> 32,738,304
  float* Qt    = (float*)(ws + 738304);      // 16384*256*4 (aliases A1p; A1p dead by then)
  bf16*  h_buf    = (bf16*)(ws + 32738304);  // 100000*256*2 -> 83,938,304
  bf16*  item_emb = (bf16*)(ws + 83938304);  // 100000*256*2 -> 135,138,304
  bf16*  fusedA   = (bf16*)(ws + 135138304); // 16384*384*2 -> 147,721,216
  bf16*  hu_buf   = (bf16*)(ws + 147721216); // 16384*256*2 -> 156,109,824

  // ---- packing / folding ----
  k_prep_w<<<160, 256, 0, stream>>>(Wi1, Wi1p, 130, 5, 16, 1);   // permuted (gcn-first)
  k_prep_w<<<256, 256, 0, stream>>>(Wi2, Wi2p, 256, 8, 16, 0);
  k_prep_w<<<384, 256, 0, stream>>>(Wu1, Wu1p, 384, 12, 16, 0);
  k_prep_w<<<256, 256, 0, stream>>>(Wu2, Wu2p, 256, 8, 16, 0);
  k_fold<<<17, 256, 0, stream>>>(Wq, Wk, bq, Wqkf);
  k_prep_w<<<128, 256, 0, stream>>>(Wqkf, Wqkp, 128, 4, 16, 0);
  k_prep_a1<<<7813, 256, 0, stream>>>(item_feat, gcn_item, A1p);
  k_prep_user<<<8192, 256, 0, stream>>>(gcn_user, fusedA);

  // ---- item tower ----
  const int itiles = NITEMS / 32;            // 3125
  const int iblk = (itiles + 3) / 4;         // 782
  k_gemm<5, 16, 0, 2><<<iblk, 256, 0, stream>>>(A1p, Wi1p, bi1, h_buf, itiles, 160);
  k_gemm<8, 16, 1, 2><<<iblk, 256, 0, stream>>>(h_buf, Wi2p, bi2, item_emb, itiles, 256);

  // ---- user tower ----
  const int utiles = NUSERS / 32;            // 512
  const int ublk = utiles / 4;               // 128
  k_gemm<4, 16, 4, 2><<<ublk, 256, 0, stream>>>(fusedA, Wqkp, Wqkf + 128 * 256, Qt, utiles, 384);
  k_user_attn<<<NUSERS, 256, 0, stream>>>(Qt, hist_idx, hist_len, item_emb, fusedA);
  k_gemm<12, 16, 0, 2><<<ublk, 256, 0, stream>>>(fusedA, Wu1p, bu1, hu_buf, utiles, 384);
  k_gemm<8, 16, 3, 2><<<ublk, 256, 0, stream>>>(hu_buf, Wu2p, bu2, (float*)d_out, utiles, 256);
}

// Round 7
// 262.181 us; speedup vs baseline: 5.3883x; 1.0328x over previous
//
#include <hip/hip_runtime.h>
#include <hip/hip_bf16.h>
#include <math.h>

#define NITEMS 100000
#define NUSERS 16384
#define HLEN   48
#define GCN    128
#define ATTN_D 128
#define HID    256
#define TOW    256

typedef __attribute__((ext_vector_type(8))) short short8;
typedef __attribute__((ext_vector_type(4))) float f32x4;
typedef __hip_bfloat16 bf16;

static __device__ __forceinline__ float bfu(unsigned short u) {
  unsigned int x = ((unsigned int)u) << 16;
  float f; __builtin_memcpy(&f, &x, 4); return f;
}
static __device__ __forceinline__ short f2bf(float v) {
  bf16 h = __float2bfloat16(v);
  short s; __builtin_memcpy(&s, &h, 2); return s;
}

// ---------------------------------------------------------------------------
// Prep: pack fp32 weight [Korig][N] -> bf16 fragment-ordered buffer.
// perm=1: source row permuted gcn-first (srck = k<128 ? k+2 : k-128).
// ---------------------------------------------------------------------------
__global__ __launch_bounds__(256) void k_prep_w(const float* __restrict__ W,
                                                bf16* __restrict__ out,
                                                int Korig, int KS, int NT, int perm) {
  int tid = blockIdx.x * 256 + threadIdx.x;
  int total = KS * NT * 512;
  if (tid >= total) return;
  int i  = tid & 7;
  int l  = (tid >> 3) & 63;
  int ct = (tid >> 9) % NT;
  int ks = (tid >> 9) / NT;
  int k   = ks * 32 + ((l >> 4) << 3) + i;
  int col = ct * 16 + (l & 15);
  int N = NT * 16;
  int srck = perm ? ((k < 128) ? (k + 2) : (k - 128)) : k;
  float v = (k < Korig) ? W[(size_t)srck * N + col] : 0.f;
  out[tid] = __float2bfloat16(v);
}

// ---------------------------------------------------------------------------
// Prep item A: A1p[row] = [gcn(128), feat(2), pad(30)] bf16, K=160.
// ---------------------------------------------------------------------------
__global__ __launch_bounds__(256) void k_prep_a1(const float* __restrict__ feat,
                                                 const float* __restrict__ gcn,
                                                 bf16* __restrict__ out) {
  int tid = blockIdx.x * 256 + threadIdx.x;
  if (tid >= NITEMS * 20) return;
  int t = tid % 20;
  size_t row = tid / 20;
  short8 v = (short8){0, 0, 0, 0, 0, 0, 0, 0};
  if (t < 16) {
    const float4* p = (const float4*)(gcn + row * GCN + 8 * t);
    float4 a = p[0], b = p[1];
    v[0] = f2bf(a.x); v[1] = f2bf(a.y); v[2] = f2bf(a.z); v[3] = f2bf(a.w);
    v[4] = f2bf(b.x); v[5] = f2bf(b.y); v[6] = f2bf(b.z); v[7] = f2bf(b.w);
  } else if (t == 16) {
    v[0] = f2bf(feat[row * 2]);
    v[1] = f2bf(feat[row * 2 + 1]);
  }
  *(short8*)(out + row * 160 + 8 * t) = v;
}

__global__ __launch_bounds__(256) void k_prep_user(const float* __restrict__ gcn_user,
                                                   bf16* __restrict__ fused) {
  int tid = blockIdx.x * 256 + threadIdx.x;
  if (tid >= NUSERS * GCN) return;
  int k = tid & 127;
  int u = tid >> 7;
  fused[(size_t)u * (GCN + TOW) + k] = __float2bfloat16(gcn_user[tid]);
}

// ---------------------------------------------------------------------------
// Fold: Wqk[g][t] = (1/sqrt(128)) * sum_d Wq[g][d] * Wk[t][d]   (g<128)
//       b~[t]    = (1/sqrt(128)) * sum_d bq[d]    * Wk[t][d]    (block 16)
// ---------------------------------------------------------------------------
__global__ __launch_bounds__(256) void k_fold(const float* __restrict__ Wq,
                                              const float* __restrict__ Wk,
                                              const float* __restrict__ bq,
                                              float* __restrict__ out) {
  const float INV_S = 0.08838834764831845f;
  const int t = threadIdx.x;
  const int b = blockIdx.x;
  if (b < 16) {
    __shared__ float wq[8][128];
    for (int s = t; s < 8 * 128; s += 256)
      wq[s >> 7][s & 127] = Wq[(size_t)(b * 8 + (s >> 7)) * ATTN_D + (s & 127)];
    __syncthreads();
    float acc[8] = {0.f, 0.f, 0.f, 0.f, 0.f, 0.f, 0.f, 0.f};
    for (int d = 0; d < 128; ++d) {
      const float wk = Wk[(size_t)t * ATTN_D + d];
      #pragma unroll
      for (int gg = 0; gg < 8; ++gg) acc[gg] = fmaf(wq[gg][d], wk, acc[gg]);
    }
    #pragma unroll
    for (int gg = 0; gg < 8; ++gg)
      out[(size_t)(b * 8 + gg) * TOW + t] = acc[gg] * INV_S;
  } else {
    float a = 0.f;
    for (int d = 0; d < 128; ++d)
      a = fmaf(bq[d], Wk[(size_t)t * ATTN_D + d], a);
    out[(size_t)128 * TOW + t] = a * INV_S;
  }
}

// ---------------------------------------------------------------------------
// Fused item tower: item_emb = l2norm(relu(A1p@W1+b1)@W2+b2).
// Per-wave 32 rows; h tile (32x256 bf16) round-trips through wave-private LDS
// (padded stride 264 keeps ds_read_b128 16B-aligned). No cross-wave barriers.
// ---------------------------------------------------------------------------
#define HP 264
__global__ __launch_bounds__(256) void k_item_fused(
    const bf16* __restrict__ A,          // [NITEMS][160]
    const bf16* __restrict__ W1,         // packed KS=5, NT=16
    const float* __restrict__ b1,
    const bf16* __restrict__ W2,         // packed KS=8, NT=16
    const float* __restrict__ b2,
    bf16* __restrict__ item_emb)         // [NITEMS][256]
{
  const int l   = threadIdx.x & 63;
  const int wid = threadIdx.x >> 6;
  const int tile = blockIdx.x * 4 + wid;
  if (tile >= NITEMS / 32) return;
  const int r = l & 15, g = l >> 4;

  __shared__ ushort hl[4][32 * HP];
  ushort* hw = hl[wid];

  // ---- phase 1: h = relu(A@W1 + b1) ----
  f32x4 acc[2][16];
  #pragma unroll
  for (int mr = 0; mr < 2; ++mr)
    #pragma unroll
    for (int ct = 0; ct < 16; ++ct) acc[mr][ct] = (f32x4){0.f, 0.f, 0.f, 0.f};

  const bf16* arow0 = A + (size_t)(tile * 32 + r) * 160 + g * 8;
  const bf16* arow1 = arow0 + 16 * 160;
  const bf16* wf1 = W1 + (size_t)l * 8;

  #pragma unroll
  for (int ks = 0; ks < 5; ++ks) {
    short8 a0 = *(const short8*)(arow0 + ks * 32);
    short8 a1 = *(const short8*)(arow1 + ks * 32);
    #pragma unroll
    for (int ct = 0; ct < 16; ++ct) {
      short8 b = *(const short8*)(wf1 + (size_t)(ks * 16 + ct) * 512);
      acc[0][ct] = __builtin_amdgcn_mfma_f32_16x16x32_bf16(a0, b, acc[0][ct], 0, 0, 0);
      acc[1][ct] = __builtin_amdgcn_mfma_f32_16x16x32_bf16(a1, b, acc[1][ct], 0, 0, 0);
    }
  }

  #pragma unroll
  for (int mr = 0; mr < 2; ++mr)
    #pragma unroll
    for (int ct = 0; ct < 16; ++ct) {
      const float bj = b1[ct * 16 + r];
      #pragma unroll
      for (int i = 0; i < 4; ++i) {
        float v = fmaxf(acc[mr][ct][i] + bj, 0.f);
        hw[(mr * 16 + g * 4 + i) * HP + ct * 16 + r] = (ushort)f2bf(v);
      }
    }

  // ---- phase 2: item_emb = l2norm(h@W2 + b2) ----
  f32x4 acc2[2][16];
  #pragma unroll
  for (int mr = 0; mr < 2; ++mr)
    #pragma unroll
    for (int ct = 0; ct < 16; ++ct) acc2[mr][ct] = (f32x4){0.f, 0.f, 0.f, 0.f};

  const bf16* wf2 = W2 + (size_t)l * 8;
  #pragma unroll
  for (int ks = 0; ks < 8; ++ks) {
    short8 a0 = *(const short8*)(hw + (size_t)r * HP + g * 8 + ks * 32);
    short8 a1 = *(const short8*)(hw + (size_t)(16 + r) * HP + g * 8 + ks * 32);
    #pragma unroll
    for (int ct = 0; ct < 16; ++ct) {
      short8 b = *(const short8*)(wf2 + (size_t)(ks * 16 + ct) * 512);
      acc2[0][ct] = __builtin_amdgcn_mfma_f32_16x16x32_bf16(a0, b, acc2[0][ct], 0, 0, 0);
      acc2[1][ct] = __builtin_amdgcn_mfma_f32_16x16x32_bf16(a1, b, acc2[1][ct], 0, 0, 0);
    }
  }

  #pragma unroll
  for (int mr = 0; mr < 2; ++mr) {
    float s[4] = {0.f, 0.f, 0.f, 0.f};
    #pragma unroll
    for (int ct = 0; ct < 16; ++ct) {
      const float bj = b2[ct * 16 + r];
      #pragma unroll
      for (int i = 0; i < 4; ++i) {
        acc2[mr][ct][i] += bj;
        s[i] += acc2[mr][ct][i] * acc2[mr][ct][i];
      }
    }
    #pragma unroll
    for (int off = 1; off < 16; off <<= 1) {
      #pragma unroll
      for (int i = 0; i < 4; ++i) s[i] += __shfl_xor(s[i], off);
    }
    float rn[4];
    #pragma unroll
    for (int i = 0; i < 4; ++i) rn[i] = 1.f / fmaxf(sqrtf(s[i]), 1e-12f);
    #pragma unroll
    for (int ct = 0; ct < 16; ++ct)
      #pragma unroll
      for (int i = 0; i < 4; ++i)
        item_emb[(size_t)(tile * 32 + mr * 16 + g * 4 + i) * TOW + ct * 16 + r] =
            __float2bfloat16(acc2[mr][ct][i] * rn[i]);
  }
}
#undef HP

// ---------------------------------------------------------------------------
// Generic MFMA GEMM, MR row-frags (16 rows each) per wave, 4 waves/block.
// MODE 0: relu->bf16; 1: l2norm->bf16; 2: plain->bf16; 3: l2norm->fp32; 4: plain->fp32
// ---------------------------------------------------------------------------
template<int KS, int NT, int MODE, int MR>
__global__ __launch_bounds__(256) void k_gemm(
    const bf16* __restrict__ A,
    const bf16* __restrict__ Wf,
    const float* __restrict__ bias,
    void* __restrict__ Cout,
    int Mtiles, int Astride)
{
  const int l   = threadIdx.x & 63;
  const int wid = threadIdx.x >> 6;
  const int tile = blockIdx.x * 4 + wid;
  if (tile >= Mtiles) return;
  const int N = NT * 16;
  const int r = l & 15, g = l >> 4;

  f32x4 acc[MR][NT];
  #pragma unroll
  for (int mr = 0; mr < MR; ++mr)
    #pragma unroll
    for (int ct = 0; ct < NT; ++ct) acc[mr][ct] = (f32x4){0.f, 0.f, 0.f, 0.f};

  const bf16* arow[MR];
  #pragma unroll
  for (int mr = 0; mr < MR; ++mr)
    arow[mr] = A + (size_t)(tile * (16 * MR) + mr * 16 + r) * Astride + g * 8;
  const bf16* wf = Wf + (size_t)l * 8;

  #pragma unroll
  for (int ks = 0; ks < KS; ++ks) {
    short8 a[MR];
    #pragma unroll
    for (int mr = 0; mr < MR; ++mr) a[mr] = *(const short8*)(arow[mr] + ks * 32);
    #pragma unroll
    for (int ct = 0; ct < NT; ++ct) {
      short8 b = *(const short8*)(wf + (size_t)(ks * NT + ct) * 512);
      #pragma unroll
      for (int mr = 0; mr < MR; ++mr)
        acc[mr][ct] = __builtin_amdgcn_mfma_f32_16x16x32_bf16(a[mr], b, acc[mr][ct], 0, 0, 0);
    }
  }

  #pragma unroll
  for (int mr = 0; mr < MR; ++mr) {
    #pragma unroll
    for (int ct = 0; ct < NT; ++ct) {
      const float bj = bias[ct * 16 + r];
      #pragma unroll
      for (int i = 0; i < 4; ++i) acc[mr][ct][i] += bj;
    }
  }

  if (MODE == 0 || MODE == 2 || MODE == 4) {
    #pragma unroll
    for (int mr = 0; mr < MR; ++mr)
      #pragma unroll
      for (int ct = 0; ct < NT; ++ct)
        #pragma unroll
        for (int i = 0; i < 4; ++i) {
          float v = acc[mr][ct][i];
          if (MODE == 0) v = fmaxf(v, 0.f);
          size_t off = (size_t)(tile * (16 * MR) + mr * 16 + g * 4 + i) * N + ct * 16 + r;
          if (MODE == 4) ((float*)Cout)[off] = v;
          else           ((bf16*)Cout)[off]  = __float2bfloat16(v);
        }
  } else {
    #pragma unroll
    for (int mr = 0; mr < MR; ++mr) {
      float s[4] = {0.f, 0.f, 0.f, 0.f};
      #pragma unroll
      for (int ct = 0; ct < NT; ++ct)
        #pragma unroll
        for (int i = 0; i < 4; ++i) s[i] += acc[mr][ct][i] * acc[mr][ct][i];
      #pragma unroll
      for (int off = 1; off < 16; off <<= 1) {
        #pragma unroll
        for (int i = 0; i < 4; ++i) s[i] += __shfl_xor(s[i], off);
      }
      float rn[4];
      #pragma unroll
      for (int i = 0; i < 4; ++i) rn[i] = 1.f / fmaxf(sqrtf(s[i]), 1e-12f);
      #pragma unroll
      for (int ct = 0; ct < NT; ++ct)
        #pragma unroll
        for (int i = 0; i < 4; ++i) {
          size_t off = (size_t)(tile * (16 * MR) + mr * 16 + g * 4 + i) * N + ct * 16 + r;
          float v = acc[mr][ct][i] * rn[i];
          if (MODE == 3) ((float*)Cout)[off] = v;
          else           ((bf16*)Cout)[off]  = __float2bfloat16(v);
        }
    }
  }
}

// ---------------------------------------------------------------------------
// Attention v5: 1 user/block; 4-row staging sweeps (len rounded up to 4).
// ---------------------------------------------------------------------------
__global__ __launch_bounds__(256) void k_user_attn(
    const float* __restrict__ Qt,          // [NUSERS][TOW] fp32
    const int*   __restrict__ hist_idx,
    const int*   __restrict__ hist_len,
    const bf16*  __restrict__ item_emb,    // [NITEMS][TOW] bf16
    bf16* __restrict__ fused)
{
  const int u = blockIdx.x;
  const int j = threadIdx.x;
  const int wid = j >> 6, lane = j & 63;
  __shared__ int    idx[HLEN];
  __shared__ ushort emb[HLEN][TOW];
  __shared__ float  sc[HLEN];
  __shared__ float  attn[HLEN];

  const int nv = hist_len[u] + 1;        // 1..48 valid entries
  const int n4 = (nv + 3) & ~3;          // staged rows (multiple of 4)

  if (j < HLEN) idx[j] = hist_idx[u * HLEN + j];
  __syncthreads();

  // ---- stage n4 emb rows into LDS (4 rows/sweep, 8B/lane; pad rows = 0) ----
  {
    const int c = lane * 4;              // element offset within row
    for (int s = 0; s < n4; s += 4) {
      const int h = s + wid;
      ushort4 v = (ushort4){0, 0, 0, 0};
      if (h < nv) v = *(const ushort4*)(item_emb + (size_t)idx[h] * TOW + c);
      *(ushort4*)(&emb[h][c]) = v;
    }
  }
  __syncthreads();

  // ---- scores: wave wid handles h = wid, wid+4, ... < nv ----
  const f32x4 q = *(const f32x4*)(Qt + (size_t)u * TOW + 4 * lane);
  for (int h = wid; h < nv; h += 4) {
    ushort4 e = *(const ushort4*)(&emb[h][4 * lane]);
    float a = q.x * bfu(e.x) + q.y * bfu(e.y) + q.z * bfu(e.z) + q.w * bfu(e.w);
    #pragma unroll
    for (int off = 32; off; off >>= 1) a += __shfl_xor(a, off);
    if (lane == 0) sc[h] = a;   // 1/sqrt(128) folded into Wqk/b~
  }
  __syncthreads();

  // ---- softmax (wave 0, lane-parallel); attn[h]=0 for h>=nv ----
  if (wid == 0) {
    const bool valid = lane < nv;
    float x = valid ? sc[lane] : -1e30f;
    float m = x;
    #pragma unroll
    for (int off = 32; off; off >>= 1) m = fmaxf(m, __shfl_xor(m, off));
    float e = valid ? expf(x - m) : 0.f;
    float s = e;
    #pragma unroll
    for (int off = 32; off; off >>= 1) s += __shfl_xor(s, off);
    if (lane < HLEN) attn[lane] = e / s;
  }
  __syncthreads();

  // ---- PV from LDS over n4 rows (pad rows: attn=0, emb=0) ----
  float hv0 = 0.f, hv1 = 0.f, hv2 = 0.f, hv3 = 0.f;
  for (int h = 0; h < n4; h += 4) {
    hv0 = fmaf(attn[h + 0], bfu(emb[h + 0][j]), hv0);
    hv1 = fmaf(attn[h + 1], bfu(emb[h + 1][j]), hv1);
    hv2 = fmaf(attn[h + 2], bfu(emb[h + 2][j]), hv2);
    hv3 = fmaf(attn[h + 3], bfu(emb[h + 3][j]), hv3);
  }
  fused[(size_t)u * (GCN + TOW) + GCN + j] = __float2bfloat16((hv0 + hv1) + (hv2 + hv3));
}

// ---------------------------------------------------------------------------
extern "C" void kernel_launch(void* const* d_in, const int* in_sizes, int n_in,
                              void* d_out, int out_size, void* d_ws, size_t ws_size,
                              hipStream_t stream) {
  const float* item_feat = (const float*)d_in[0];
  const float* gcn_item  = (const float*)d_in[1];
  const float* gcn_user  = (const float*)d_in[2];
  const int*   hist_idx  = (const int*)d_in[3];
  const int*   hist_len  = (const int*)d_in[4];
  const float* Wi1 = (const float*)d_in[5];
  const float* bi1 = (const float*)d_in[6];
  const float* Wi2 = (const float*)d_in[7];
  const float* bi2 = (const float*)d_in[8];
  const float* Wq  = (const float*)d_in[9];
  const float* bq  = (const float*)d_in[10];
  const float* Wk  = (const float*)d_in[11];
  const float* bk  = (const float*)d_in[12];  // cancels in softmax (shift-invariance)
  const float* Wu1 = (const float*)d_in[13];
  const float* bu1 = (const float*)d_in[14];
  const float* Wu2 = (const float*)d_in[15];
  const float* bu2 = (const float*)d_in[16];
  (void)bk;

  char* ws = (char*)d_ws;
  bf16*  Wi1p  = (bf16*)(ws + 0);            // 81920 B
  bf16*  Wi2p  = (bf16*)(ws + 81920);        // 131072 B -> 212992
  bf16*  Wu1p  = (bf16*)(ws + 212992);       // 196608 B -> 409600
  bf16*  Wu2p  = (bf16*)(ws + 409600);       // 131072 B -> 540672
  float* Wqkf  = (float*)(ws + 540672);      // 132096 B -> 672768
  bf16*  Wqkp  = (bf16*)(ws + 672768);       // 65536 B -> 738304
  bf16*  A1p   = (bf16*)(ws + 738304);       // 100000*160*2 = 32,000,000 -> 32,738,304
  float* Qt    = (float*)(ws + 738304);      // 16384*256*4 (aliases A1p; A1p dead by then)
  bf16*  item_emb = (bf16*)(ws + 32738304);  // 100000*256*2 -> 83,938,304
  bf16*  fusedA   = (bf16*)(ws + 83938304);  // 16384*384*2 -> 96,521,216
  bf16*  hu_buf   = (bf16*)(ws + 96521216);  // 16384*256*2 -> 104,909,824

  // ---- packing / folding ----
  k_prep_w<<<160, 256, 0, stream>>>(Wi1, Wi1p, 130, 5, 16, 1);   // permuted (gcn-first)
  k_prep_w<<<256, 256, 0, stream>>>(Wi2, Wi2p, 256, 8, 16, 0);
  k_prep_w<<<384, 256, 0, stream>>>(Wu1, Wu1p, 384, 12, 16, 0);
  k_prep_w<<<256, 256, 0, stream>>>(Wu2, Wu2p, 256, 8, 16, 0);
  k_fold<<<17, 256, 0, stream>>>(Wq, Wk, bq, Wqkf);
  k_prep_w<<<128, 256, 0, stream>>>(Wqkf, Wqkp, 128, 4, 16, 0);
  k_prep_a1<<<7813, 256, 0, stream>>>(item_feat, gcn_item, A1p);
  k_prep_user<<<8192, 256, 0, stream>>>(gcn_user, fusedA);

  // ---- item tower (fused GEMM1+GEMM2) ----
  const int iblk = (NITEMS / 32 + 3) / 4;    // 782
  k_item_fused<<<iblk, 256, 0, stream>>>(A1p, Wi1p, bi1, Wi2p, bi2, item_emb);

  // ---- user tower ----
  const int utiles = NUSERS / 32;            // 512
  const int ublk = utiles / 4;               // 128
  k_gemm<4, 16, 4, 2><<<ublk, 256, 0, stream>>>(fusedA, Wqkp, Wqkf + 128 * 256, Qt, utiles, 384);
  k_user_attn<<<NUSERS, 256, 0, stream>>>(Qt, hist_idx, hist_len, item_emb, fusedA);
  k_gemm<12, 16, 0, 2><<<ublk, 256, 0, stream>>>(fusedA, Wu1p, bu1, hu_buf, utiles, 384);
  k_gemm<8, 16, 3, 2><<<ublk, 256, 0, stream>>>(hu_buf, Wu2p, bu2, (float*)d_out, utiles, 256);
}

// Round 8
// 238.865 us; speedup vs baseline: 5.9143x; 1.0976x over previous
//
#include <hip/hip_runtime.h>
#include <hip/hip_bf16.h>
#include <math.h>

#define NITEMS 100000
#define NUSERS 16384
#define HLEN   48
#define GCN    128
#define ATTN_D 128
#define HID    256
#define TOW    256

typedef __attribute__((ext_vector_type(8))) short short8;
typedef __attribute__((ext_vector_type(4))) float f32x4;
typedef __hip_bfloat16 bf16;

static __device__ __forceinline__ float bfu(unsigned short u) {
  unsigned int x = ((unsigned int)u) << 16;
  float f; __builtin_memcpy(&f, &x, 4); return f;
}
static __device__ __forceinline__ short f2bf(float v) {
  bf16 h = __float2bfloat16(v);
  short s; __builtin_memcpy(&s, &h, 2); return s;
}

// ---------------------------------------------------------------------------
// Prep: pack fp32 weight [Korig][N] -> bf16 fragment-ordered buffer.
// perm=1: source row permuted gcn-first (srck = k<128 ? k+2 : k-128).
// ---------------------------------------------------------------------------
__global__ __launch_bounds__(256) void k_prep_w(const float* __restrict__ W,
                                                bf16* __restrict__ out,
                                                int Korig, int KS, int NT, int perm) {
  int tid = blockIdx.x * 256 + threadIdx.x;
  int total = KS * NT * 512;
  if (tid >= total) return;
  int i  = tid & 7;
  int l  = (tid >> 3) & 63;
  int ct = (tid >> 9) % NT;
  int ks = (tid >> 9) / NT;
  int k   = ks * 32 + ((l >> 4) << 3) + i;
  int col = ct * 16 + (l & 15);
  int N = NT * 16;
  int srck = perm ? ((k < 128) ? (k + 2) : (k - 128)) : k;
  float v = (k < Korig) ? W[(size_t)srck * N + col] : 0.f;
  out[tid] = __float2bfloat16(v);
}

// ---------------------------------------------------------------------------
// Prep item A: A1p[row] = [gcn(128), feat(2), pad(30)] bf16, K=160.
// ---------------------------------------------------------------------------
__global__ __launch_bounds__(256) void k_prep_a1(const float* __restrict__ feat,
                                                 const float* __restrict__ gcn,
                                                 bf16* __restrict__ out) {
  int tid = blockIdx.x * 256 + threadIdx.x;
  if (tid >= NITEMS * 20) return;
  int t = tid % 20;
  size_t row = tid / 20;
  short8 v = (short8){0, 0, 0, 0, 0, 0, 0, 0};
  if (t < 16) {
    const float4* p = (const float4*)(gcn + row * GCN + 8 * t);
    float4 a = p[0], b = p[1];
    v[0] = f2bf(a.x); v[1] = f2bf(a.y); v[2] = f2bf(a.z); v[3] = f2bf(a.w);
    v[4] = f2bf(b.x); v[5] = f2bf(b.y); v[6] = f2bf(b.z); v[7] = f2bf(b.w);
  } else if (t == 16) {
    v[0] = f2bf(feat[row * 2]);
    v[1] = f2bf(feat[row * 2 + 1]);
  }
  *(short8*)(out + row * 160 + 8 * t) = v;
}

__global__ __launch_bounds__(256) void k_prep_user(const float* __restrict__ gcn_user,
                                                   bf16* __restrict__ fused) {
  int tid = blockIdx.x * 256 + threadIdx.x;
  if (tid >= NUSERS * GCN) return;
  int k = tid & 127;
  int u = tid >> 7;
  fused[(size_t)u * (GCN + TOW) + k] = __float2bfloat16(gcn_user[tid]);
}

// ---------------------------------------------------------------------------
// Fold: Wqk[g][t] = (1/sqrt(128)) * sum_d Wq[g][d] * Wk[t][d]   (g<128)
//       b~[t]    = (1/sqrt(128)) * sum_d bq[d]    * Wk[t][d]    (block 16)
// ---------------------------------------------------------------------------
__global__ __launch_bounds__(256) void k_fold(const float* __restrict__ Wq,
                                              const float* __restrict__ Wk,
                                              const float* __restrict__ bq,
                                              float* __restrict__ out) {
  const float INV_S = 0.08838834764831845f;
  const int t = threadIdx.x;
  const int b = blockIdx.x;
  if (b < 16) {
    __shared__ float wq[8][128];
    for (int s = t; s < 8 * 128; s += 256)
      wq[s >> 7][s & 127] = Wq[(size_t)(b * 8 + (s >> 7)) * ATTN_D + (s & 127)];
    __syncthreads();
    float acc[8] = {0.f, 0.f, 0.f, 0.f, 0.f, 0.f, 0.f, 0.f};
    for (int d = 0; d < 128; ++d) {
      const float wk = Wk[(size_t)t * ATTN_D + d];
      #pragma unroll
      for (int gg = 0; gg < 8; ++gg) acc[gg] = fmaf(wq[gg][d], wk, acc[gg]);
    }
    #pragma unroll
    for (int gg = 0; gg < 8; ++gg)
      out[(size_t)(b * 8 + gg) * TOW + t] = acc[gg] * INV_S;
  } else {
    float a = 0.f;
    for (int d = 0; d < 128; ++d)
      a = fmaf(bq[d], Wk[(size_t)t * ATTN_D + d], a);
    out[(size_t)128 * TOW + t] = a * INV_S;
  }
}

// ---------------------------------------------------------------------------
// MFMA GEMM with LDS-staged, double-buffered B (shared by the 4 waves).
// Per K-step: issue A loads, then next B-slice loads; MFMA from LDS; ds_write
// the staged slice; one barrier. Tail waves clamp tile (benign dup stores).
// MODE 0: relu->bf16; 1: l2norm->bf16; 2: plain->bf16; 3: l2norm->fp32; 4: plain->fp32
// ---------------------------------------------------------------------------
template<int KS, int NT, int MODE, int MR>
__global__ __launch_bounds__(256) void k_gemm(
    const bf16* __restrict__ A,
    const bf16* __restrict__ Wf,
    const float* __restrict__ bias,
    void* __restrict__ Cout,
    int Mtiles, int Astride)
{
  static_assert(NT % 4 == 0, "NT must be divisible by 4");
  constexpr int BSZ = NT * 512;          // bf16 elements per K-step B slice
  constexpr int CH  = NT / 4;            // short8 chunks per thread per slice
  __shared__ bf16 bs[2][BSZ];
  const int j   = threadIdx.x;
  const int l   = j & 63;
  const int wid = j >> 6;
  int tile = blockIdx.x * 4 + wid;
  if (tile >= Mtiles) tile = Mtiles - 1;
  const int N = NT * 16;
  const int r = l & 15, g = l >> 4;

  // prologue: stage slice 0
  {
    const short8* src = (const short8*)Wf;
    short8* dst = (short8*)bs[0];
    #pragma unroll
    for (int c = 0; c < CH; ++c) dst[c * 256 + j] = src[c * 256 + j];
  }

  f32x4 acc[MR][NT];
  #pragma unroll
  for (int mr = 0; mr < MR; ++mr)
    #pragma unroll
    for (int ct = 0; ct < NT; ++ct) acc[mr][ct] = (f32x4){0.f, 0.f, 0.f, 0.f};

  const bf16* arow[MR];
  #pragma unroll
  for (int mr = 0; mr < MR; ++mr)
    arow[mr] = A + (size_t)(tile * (16 * MR) + mr * 16 + r) * Astride + g * 8;

  __syncthreads();

  #pragma unroll
  for (int ks = 0; ks < KS; ++ks) {
    const int cur = ks & 1;
    // A fragments first (MFMA waits only on these)
    short8 a[MR];
    #pragma unroll
    for (int mr = 0; mr < MR; ++mr) a[mr] = *(const short8*)(arow[mr] + ks * 32);
    // issue next B-slice loads (stay in flight under the MFMA cluster)
    short8 st[CH];
    if (ks + 1 < KS) {
      const short8* src = (const short8*)(Wf + (size_t)(ks + 1) * BSZ);
      #pragma unroll
      for (int c = 0; c < CH; ++c) st[c] = src[c * 256 + j];
    }
    // MFMA from LDS
    const bf16* wb = bs[cur] + (size_t)l * 8;
    #pragma unroll
    for (int ct = 0; ct < NT; ++ct) {
      short8 b = *(const short8*)(wb + ct * 512);
      #pragma unroll
      for (int mr = 0; mr < MR; ++mr)
        acc[mr][ct] = __builtin_amdgcn_mfma_f32_16x16x32_bf16(a[mr], b, acc[mr][ct], 0, 0, 0);
    }
    // write staged slice
    if (ks + 1 < KS) {
      short8* dst = (short8*)bs[cur ^ 1];
      #pragma unroll
      for (int c = 0; c < CH; ++c) dst[c * 256 + j] = st[c];
    }
    __syncthreads();
  }

  #pragma unroll
  for (int mr = 0; mr < MR; ++mr) {
    #pragma unroll
    for (int ct = 0; ct < NT; ++ct) {
      const float bj = bias[ct * 16 + r];
      #pragma unroll
      for (int i = 0; i < 4; ++i) acc[mr][ct][i] += bj;
    }
  }

  if (MODE == 0 || MODE == 2 || MODE == 4) {
    #pragma unroll
    for (int mr = 0; mr < MR; ++mr)
      #pragma unroll
      for (int ct = 0; ct < NT; ++ct)
        #pragma unroll
        for (int i = 0; i < 4; ++i) {
          float v = acc[mr][ct][i];
          if (MODE == 0) v = fmaxf(v, 0.f);
          size_t off = (size_t)(tile * (16 * MR) + mr * 16 + g * 4 + i) * N + ct * 16 + r;
          if (MODE == 4) ((float*)Cout)[off] = v;
          else           ((bf16*)Cout)[off]  = __float2bfloat16(v);
        }
  } else {
    #pragma unroll
    for (int mr = 0; mr < MR; ++mr) {
      float s[4] = {0.f, 0.f, 0.f, 0.f};
      #pragma unroll
      for (int ct = 0; ct < NT; ++ct)
        #pragma unroll
        for (int i = 0; i < 4; ++i) s[i] += acc[mr][ct][i] * acc[mr][ct][i];
      #pragma unroll
      for (int off = 1; off < 16; off <<= 1) {
        #pragma unroll
        for (int i = 0; i < 4; ++i) s[i] += __shfl_xor(s[i], off);
      }
      float rn[4];
      #pragma unroll
      for (int i = 0; i < 4; ++i) rn[i] = 1.f / fmaxf(sqrtf(s[i]), 1e-12f);
      #pragma unroll
      for (int ct = 0; ct < NT; ++ct)
        #pragma unroll
        for (int i = 0; i < 4; ++i) {
          size_t off = (size_t)(tile * (16 * MR) + mr * 16 + g * 4 + i) * N + ct * 16 + r;
          float v = acc[mr][ct][i] * rn[i];
          if (MODE == 3) ((float*)Cout)[off] = v;
          else           ((bf16*)Cout)[off]  = __float2bfloat16(v);
        }
    }
  }
}

// ---------------------------------------------------------------------------
// Attention v5: 1 user/block; 4-row staging sweeps (len rounded up to 4).
// ---------------------------------------------------------------------------
__global__ __launch_bounds__(256) void k_user_attn(
    const float* __restrict__ Qt,          // [NUSERS][TOW] fp32
    const int*   __restrict__ hist_idx,
    const int*   __restrict__ hist_len,
    const bf16*  __restrict__ item_emb,    // [NITEMS][TOW] bf16
    bf16* __restrict__ fused)
{
  const int u = blockIdx.x;
  const int j = threadIdx.x;
  const int wid = j >> 6, lane = j & 63;
  __shared__ int    idx[HLEN];
  __shared__ ushort emb[HLEN][TOW];
  __shared__ float  sc[HLEN];
  __shared__ float  attn[HLEN];

  const int nv = hist_len[u] + 1;        // 1..48 valid entries
  const int n4 = (nv + 3) & ~3;          // staged rows (multiple of 4)

  if (j < HLEN) idx[j] = hist_idx[u * HLEN + j];
  __syncthreads();

  // ---- stage n4 emb rows into LDS (4 rows/sweep, 8B/lane; pad rows = 0) ----
  {
    const int c = lane * 4;              // element offset within row
    for (int s = 0; s < n4; s += 4) {
      const int h = s + wid;
      ushort4 v = (ushort4){0, 0, 0, 0};
      if (h < nv) v = *(const ushort4*)(item_emb + (size_t)idx[h] * TOW + c);
      *(ushort4*)(&emb[h][c]) = v;
    }
  }
  __syncthreads();

  // ---- scores: wave wid handles h = wid, wid+4, ... < nv ----
  const f32x4 q = *(const f32x4*)(Qt + (size_t)u * TOW + 4 * lane);
  for (int h = wid; h < nv; h += 4) {
    ushort4 e = *(const ushort4*)(&emb[h][4 * lane]);
    float a = q.x * bfu(e.x) + q.y * bfu(e.y) + q.z * bfu(e.z) + q.w * bfu(e.w);
    #pragma unroll
    for (int off = 32; off; off >>= 1) a += __shfl_xor(a, off);
    if (lane == 0) sc[h] = a;   // 1/sqrt(128) folded into Wqk/b~
  }
  __syncthreads();

  // ---- softmax (wave 0, lane-parallel); attn[h]=0 for h>=nv ----
  if (wid == 0) {
    const bool valid = lane < nv;
    float x = valid ? sc[lane] : -1e30f;
    float m = x;
    #pragma unroll
    for (int off = 32; off; off >>= 1) m = fmaxf(m, __shfl_xor(m, off));
    float e = valid ? expf(x - m) : 0.f;
    float s = e;
    #pragma unroll
    for (int off = 32; off; off >>= 1) s += __shfl_xor(s, off);
    if (lane < HLEN) attn[lane] = e / s;
  }
  __syncthreads();

  // ---- PV from LDS over n4 rows (pad rows: attn=0, emb=0) ----
  float hv0 = 0.f, hv1 = 0.f, hv2 = 0.f, hv3 = 0.f;
  for (int h = 0; h < n4; h += 4) {
    hv0 = fmaf(attn[h + 0], bfu(emb[h + 0][j]), hv0);
    hv1 = fmaf(attn[h + 1], bfu(emb[h + 1][j]), hv1);
    hv2 = fmaf(attn[h + 2], bfu(emb[h + 2][j]), hv2);
    hv3 = fmaf(attn[h + 3], bfu(emb[h + 3][j]), hv3);
  }
  fused[(size_t)u * (GCN + TOW) + GCN + j] = __float2bfloat16((hv0 + hv1) + (hv2 + hv3));
}

// ---------------------------------------------------------------------------
extern "C" void kernel_launch(void* const* d_in, const int* in_sizes, int n_in,
                              void* d_out, int out_size, void* d_ws, size_t ws_size,
                              hipStream_t stream) {
  const float* item_feat = (const float*)d_in[0];
  const float* gcn_item  = (const float*)d_in[1];
  const float* gcn_user  = (const float*)d_in[2];
  const int*   hist_idx  = (const int*)d_in[3];
  const int*   hist_len  = (const int*)d_in[4];
  const float* Wi1 = (const float*)d_in[5];
  const float* bi1 = (const float*)d_in[6];
  const float* Wi2 = (const float*)d_in[7];
  const float* bi2 = (const float*)d_in[8];
  const float* Wq  = (const float*)d_in[9];
  const float* bq  = (const float*)d_in[10];
  const float* Wk  = (const float*)d_in[11];
  const float* bk  = (const float*)d_in[12];  // cancels in softmax (shift-invariance)
  const float* Wu1 = (const float*)d_in[13];
  const float* bu1 = (const float*)d_in[14];
  const float* Wu2 = (const float*)d_in[15];
  const float* bu2 = (const float*)d_in[16];
  (void)bk;

  char* ws = (char*)d_ws;
  bf16*  Wi1p  = (bf16*)(ws + 0);            // 81920 B
  bf16*  Wi2p  = (bf16*)(ws + 81920);        // 131072 B -> 212992
  bf16*  Wu1p  = (bf16*)(ws + 212992);       // 196608 B -> 409600
  bf16*  Wu2p  = (bf16*)(ws + 409600);       // 131072 B -> 540672
  float* Wqkf  = (float*)(ws + 540672);      // 132096 B -> 672768
  bf16*  Wqkp  = (bf16*)(ws + 672768);       // 65536 B -> 738304
  bf16*  A1p   = (bf16*)(ws + 738304);       // 100000*160*2 = 32,000,000 -> 32,738,304
  float* Qt    = (float*)(ws + 738304);      // 16384*256*4 (aliases A1p; A1p dead by then)
  bf16*  h_buf    = (bf16*)(ws + 32738304);  // 100000*256*2 -> 83,938,304
  bf16*  item_emb = (bf16*)(ws + 83938304);  // 100000*256*2 -> 135,138,304
  bf16*  fusedA   = (bf16*)(ws + 135138304); // 16384*384*2 -> 147,721,216
  bf16*  hu_buf   = (bf16*)(ws + 147721216); // 16384*256*2 -> 156,109,824

  // ---- packing / folding ----
  k_prep_w<<<160, 256, 0, stream>>>(Wi1, Wi1p, 130, 5, 16, 1);   // permuted (gcn-first)
  k_prep_w<<<256, 256, 0, stream>>>(Wi2, Wi2p, 256, 8, 16, 0);
  k_prep_w<<<384, 256, 0, stream>>>(Wu1, Wu1p, 384, 12, 16, 0);
  k_prep_w<<<256, 256, 0, stream>>>(Wu2, Wu2p, 256, 8, 16, 0);
  k_fold<<<17, 256, 0, stream>>>(Wq, Wk, bq, Wqkf);
  k_prep_w<<<128, 256, 0, stream>>>(Wqkf, Wqkp, 128, 4, 16, 0);
  k_prep_a1<<<7813, 256, 0, stream>>>(item_feat, gcn_item, A1p);
  k_prep_user<<<8192, 256, 0, stream>>>(gcn_user, fusedA);

  // ---- item tower (split GEMMs, B staged in LDS) ----
  const int itiles = NITEMS / 32;            // 3125
  const int iblk = (itiles + 3) / 4;         // 782
  k_gemm<5, 16, 0, 2><<<iblk, 256, 0, stream>>>(A1p, Wi1p, bi1, h_buf, itiles, 160);
  k_gemm<8, 16, 1, 2><<<iblk, 256, 0, stream>>>(h_buf, Wi2p, bi2, item_emb, itiles, 256);

  // ---- user tower ----
  const int utiles = NUSERS / 32;            // 512
  const int ublk = utiles / 4;               // 128
  k_gemm<4, 16, 4, 2><<<ublk, 256, 0, stream>>>(fusedA, Wqkp, Wqkf + 128 * 256, Qt, utiles, 384);
  k_user_attn<<<NUSERS, 256, 0, stream>>>(Qt, hist_idx, hist_len, item_emb, fusedA);
  k_gemm<12, 16, 0, 2><<<ublk, 256, 0, stream>>>(fusedA, Wu1p, bu1, hu_buf, utiles, 384);
  k_gemm<8, 16, 3, 2><<<ublk, 256, 0, stream>>>(hu_buf, Wu2p, bu2, (float*)d_out, utiles, 256);
}

// Round 9
// 212.870 us; speedup vs baseline: 6.6365x; 1.1221x over previous
//
#include <hip/hip_runtime.h>
#include <hip/hip_bf16.h>
#include <math.h>

#define NITEMS 100000
#define NUSERS 16384
#define HLEN   48
#define GCN    128
#define ATTN_D 128
#define HID    256
#define TOW    256

typedef __attribute__((ext_vector_type(8))) short short8;
typedef __attribute__((ext_vector_type(4))) float f32x4;
typedef __hip_bfloat16 bf16;

static __device__ __forceinline__ float bfu(unsigned short u) {
  unsigned int x = ((unsigned int)u) << 16;
  float f; __builtin_memcpy(&f, &x, 4); return f;
}
static __device__ __forceinline__ short f2bf(float v) {
  bf16 h = __float2bfloat16(v);
  short s; __builtin_memcpy(&s, &h, 2); return s;
}

// ---------------------------------------------------------------------------
// Prep: pack fp32 weight [Korig][N] -> bf16 fragment-ordered buffer.
// perm=1: source row permuted gcn-first (srck = k<128 ? k+2 : k-128).
// ---------------------------------------------------------------------------
__global__ __launch_bounds__(256) void k_prep_w(const float* __restrict__ W,
                                                bf16* __restrict__ out,
                                                int Korig, int KS, int NT, int perm) {
  int tid = blockIdx.x * 256 + threadIdx.x;
  int total = KS * NT * 512;
  if (tid >= total) return;
  int i  = tid & 7;
  int l  = (tid >> 3) & 63;
  int ct = (tid >> 9) % NT;
  int ks = (tid >> 9) / NT;
  int k   = ks * 32 + ((l >> 4) << 3) + i;
  int col = ct * 16 + (l & 15);
  int N = NT * 16;
  int srck = perm ? ((k < 128) ? (k + 2) : (k - 128)) : k;
  float v = (k < Korig) ? W[(size_t)srck * N + col] : 0.f;
  out[tid] = __float2bfloat16(v);
}

// ---------------------------------------------------------------------------
// Prep item A: A1p[row] = [gcn(128), feat(2), pad(30)] bf16, K=160.
// ---------------------------------------------------------------------------
__global__ __launch_bounds__(256) void k_prep_a1(const float* __restrict__ feat,
                                                 const float* __restrict__ gcn,
                                                 bf16* __restrict__ out) {
  int tid = blockIdx.x * 256 + threadIdx.x;
  if (tid >= NITEMS * 20) return;
  int t = tid % 20;
  size_t row = tid / 20;
  short8 v = (short8){0, 0, 0, 0, 0, 0, 0, 0};
  if (t < 16) {
    const float4* p = (const float4*)(gcn + row * GCN + 8 * t);
    float4 a = p[0], b = p[1];
    v[0] = f2bf(a.x); v[1] = f2bf(a.y); v[2] = f2bf(a.z); v[3] = f2bf(a.w);
    v[4] = f2bf(b.x); v[5] = f2bf(b.y); v[6] = f2bf(b.z); v[7] = f2bf(b.w);
  } else if (t == 16) {
    v[0] = f2bf(feat[row * 2]);
    v[1] = f2bf(feat[row * 2 + 1]);
  }
  *(short8*)(out + row * 160 + 8 * t) = v;
}

__global__ __launch_bounds__(256) void k_prep_user(const float* __restrict__ gcn_user,
                                                   bf16* __restrict__ fused) {
  int tid = blockIdx.x * 256 + threadIdx.x;
  if (tid >= NUSERS * GCN) return;
  int k = tid & 127;
  int u = tid >> 7;
  fused[(size_t)u * (GCN + TOW) + k] = __float2bfloat16(gcn_user[tid]);
}

// ---------------------------------------------------------------------------
// Fold: Wqk[g][t] = (1/sqrt(128)) * sum_d Wq[g][d] * Wk[t][d]   (g<128)
//       b~[t]    = (1/sqrt(128)) * sum_d bq[d]    * Wk[t][d]    (block 16)
// ---------------------------------------------------------------------------
__global__ __launch_bounds__(256) void k_fold(const float* __restrict__ Wq,
                                              const float* __restrict__ Wk,
                                              const float* __restrict__ bq,
                                              float* __restrict__ out) {
  const float INV_S = 0.08838834764831845f;
  const int t = threadIdx.x;
  const int b = blockIdx.x;
  if (b < 16) {
    __shared__ float wq[8][128];
    for (int s = t; s < 8 * 128; s += 256)
      wq[s >> 7][s & 127] = Wq[(size_t)(b * 8 + (s >> 7)) * ATTN_D + (s & 127)];
    __syncthreads();
    float acc[8] = {0.f, 0.f, 0.f, 0.f, 0.f, 0.f, 0.f, 0.f};
    for (int d = 0; d < 128; ++d) {
      const float wk = Wk[(size_t)t * ATTN_D + d];
      #pragma unroll
      for (int gg = 0; gg < 8; ++gg) acc[gg] = fmaf(wq[gg][d], wk, acc[gg]);
    }
    #pragma unroll
    for (int gg = 0; gg < 8; ++gg)
      out[(size_t)(b * 8 + gg) * TOW + t] = acc[gg] * INV_S;
  } else {
    float a = 0.f;
    for (int d = 0; d < 128; ++d)
      a = fmaf(bq[d], Wk[(size_t)t * ATTN_D + d], a);
    out[(size_t)128 * TOW + t] = a * INV_S;
  }
}

// ---------------------------------------------------------------------------
// MFMA GEMM with LDS-staged, double-buffered B (shared by the 4 waves).
// MODE 0: relu->bf16; 1: l2norm->bf16; 2: plain->bf16; 3: l2norm->fp32; 4: plain->fp32
// ---------------------------------------------------------------------------
template<int KS, int NT, int MODE, int MR>
__global__ __launch_bounds__(256) void k_gemm(
    const bf16* __restrict__ A,
    const bf16* __restrict__ Wf,
    const float* __restrict__ bias,
    void* __restrict__ Cout,
    int Mtiles, int Astride)
{
  static_assert(NT % 4 == 0, "NT must be divisible by 4");
  constexpr int BSZ = NT * 512;          // bf16 elements per K-step B slice
  constexpr int CH  = NT / 4;            // short8 chunks per thread per slice
  __shared__ bf16 bs[2][BSZ];
  const int j   = threadIdx.x;
  const int l   = j & 63;
  const int wid = j >> 6;
  int tile = blockIdx.x * 4 + wid;
  if (tile >= Mtiles) tile = Mtiles - 1;
  const int N = NT * 16;
  const int r = l & 15, g = l >> 4;

  // prologue: stage slice 0
  {
    const short8* src = (const short8*)Wf;
    short8* dst = (short8*)bs[0];
    #pragma unroll
    for (int c = 0; c < CH; ++c) dst[c * 256 + j] = src[c * 256 + j];
  }

  f32x4 acc[MR][NT];
  #pragma unroll
  for (int mr = 0; mr < MR; ++mr)
    #pragma unroll
    for (int ct = 0; ct < NT; ++ct) acc[mr][ct] = (f32x4){0.f, 0.f, 0.f, 0.f};

  const bf16* arow[MR];
  #pragma unroll
  for (int mr = 0; mr < MR; ++mr)
    arow[mr] = A + (size_t)(tile * (16 * MR) + mr * 16 + r) * Astride + g * 8;

  __syncthreads();

  #pragma unroll
  for (int ks = 0; ks < KS; ++ks) {
    const int cur = ks & 1;
    short8 a[MR];
    #pragma unroll
    for (int mr = 0; mr < MR; ++mr) a[mr] = *(const short8*)(arow[mr] + ks * 32);
    short8 st[CH];
    if (ks + 1 < KS) {
      const short8* src = (const short8*)(Wf + (size_t)(ks + 1) * BSZ);
      #pragma unroll
      for (int c = 0; c < CH; ++c) st[c] = src[c * 256 + j];
    }
    const bf16* wb = bs[cur] + (size_t)l * 8;
    #pragma unroll
    for (int ct = 0; ct < NT; ++ct) {
      short8 b = *(const short8*)(wb + ct * 512);
      #pragma unroll
      for (int mr = 0; mr < MR; ++mr)
        acc[mr][ct] = __builtin_amdgcn_mfma_f32_16x16x32_bf16(a[mr], b, acc[mr][ct], 0, 0, 0);
    }
    if (ks + 1 < KS) {
      short8* dst = (short8*)bs[cur ^ 1];
      #pragma unroll
      for (int c = 0; c < CH; ++c) dst[c * 256 + j] = st[c];
    }
    __syncthreads();
  }

  #pragma unroll
  for (int mr = 0; mr < MR; ++mr) {
    #pragma unroll
    for (int ct = 0; ct < NT; ++ct) {
      const float bj = bias[ct * 16 + r];
      #pragma unroll
      for (int i = 0; i < 4; ++i) acc[mr][ct][i] += bj;
    }
  }

  if (MODE == 0 || MODE == 2 || MODE == 4) {
    #pragma unroll
    for (int mr = 0; mr < MR; ++mr)
      #pragma unroll
      for (int ct = 0; ct < NT; ++ct)
        #pragma unroll
        for (int i = 0; i < 4; ++i) {
          float v = acc[mr][ct][i];
          if (MODE == 0) v = fmaxf(v, 0.f);
          size_t off = (size_t)(tile * (16 * MR) + mr * 16 + g * 4 + i) * N + ct * 16 + r;
          if (MODE == 4) ((float*)Cout)[off] = v;
          else           ((bf16*)Cout)[off]  = __float2bfloat16(v);
        }
  } else {
    #pragma unroll
    for (int mr = 0; mr < MR; ++mr) {
      float s[4] = {0.f, 0.f, 0.f, 0.f};
      #pragma unroll
      for (int ct = 0; ct < NT; ++ct)
        #pragma unroll
        for (int i = 0; i < 4; ++i) s[i] += acc[mr][ct][i] * acc[mr][ct][i];
      #pragma unroll
      for (int off = 1; off < 16; off <<= 1) {
        #pragma unroll
        for (int i = 0; i < 4; ++i) s[i] += __shfl_xor(s[i], off);
      }
      float rn[4];
      #pragma unroll
      for (int i = 0; i < 4; ++i) rn[i] = 1.f / fmaxf(sqrtf(s[i]), 1e-12f);
      #pragma unroll
      for (int ct = 0; ct < NT; ++ct)
        #pragma unroll
        for (int i = 0; i < 4; ++i) {
          size_t off = (size_t)(tile * (16 * MR) + mr * 16 + g * 4 + i) * N + ct * 16 + r;
          float v = acc[mr][ct][i] * rn[i];
          if (MODE == 3) ((float*)Cout)[off] = v;
          else           ((bf16*)Cout)[off]  = __float2bfloat16(v);
        }
    }
  }
}

// ---------------------------------------------------------------------------
// Attention v6: single-pass online softmax, no emb staging.
// Wave w handles rows h = w, w+4, ...; per row: one coalesced 8B/lane global
// read, shfl-reduced score, lane-local (m,l,O) update on 4 dims/lane.
// Epilogue merges the 4 waves' partials through 4.3 KB LDS.
// ---------------------------------------------------------------------------
__global__ __launch_bounds__(256) void k_user_attn(
    const float* __restrict__ Qt,          // [NUSERS][TOW] fp32 (Wqk-folded)
    const int*   __restrict__ hist_idx,
    const int*   __restrict__ hist_len,
    const bf16*  __restrict__ item_emb,    // [NITEMS][TOW] bf16
    bf16* __restrict__ fused)
{
  const int u = blockIdx.x;
  const int j = threadIdx.x;
  const int wid = j >> 6, lane = j & 63;
  __shared__ int   idx[HLEN];
  __shared__ float red[4][TOW];
  __shared__ float ml[4][2];

  const int nv = hist_len[u] + 1;        // 1..48 valid entries

  if (j < HLEN) idx[j] = hist_idx[u * HLEN + j];
  const f32x4 q = *(const f32x4*)(Qt + (size_t)u * TOW + 4 * lane);
  __syncthreads();

  float m = -1e30f, l = 0.f;
  f32x4 O = (f32x4){0.f, 0.f, 0.f, 0.f};

  int h = wid;
  ushort4 cur = (ushort4){0, 0, 0, 0};
  if (h < nv) cur = *(const ushort4*)(item_emb + (size_t)idx[h] * TOW + 4 * lane);
  for (; h < nv; h += 4) {
    const ushort4 e = cur;
    if (h + 4 < nv)
      cur = *(const ushort4*)(item_emb + (size_t)idx[h + 4] * TOW + 4 * lane);
    const float ex = bfu(e.x), ey = bfu(e.y), ez = bfu(e.z), ew = bfu(e.w);
    float sc = q.x * ex + q.y * ey + q.z * ez + q.w * ew;
    #pragma unroll
    for (int off = 32; off; off >>= 1) sc += __shfl_xor(sc, off);
    const float mn = fmaxf(m, sc);
    const float rs = __expf(m - mn);     // 1 when m==mn
    const float p  = __expf(sc - mn);
    m = mn;
    l = l * rs + p;
    O.x = O.x * rs + p * ex;
    O.y = O.y * rs + p * ey;
    O.z = O.z * rs + p * ez;
    O.w = O.w * rs + p * ew;
  }

  *(f32x4*)(&red[wid][4 * lane]) = O;
  if (lane == 0) { ml[wid][0] = m; ml[wid][1] = l; }
  __syncthreads();

  // combine: thread j owns output dim j
  const float M = fmaxf(fmaxf(ml[0][0], ml[1][0]), fmaxf(ml[2][0], ml[3][0]));
  float L = 0.f, val = 0.f;
  #pragma unroll
  for (int w = 0; w < 4; ++w) {
    const float wgt = __expf(ml[w][0] - M);   // 0 for waves with no rows
    L   += ml[w][1] * wgt;
    val += red[w][j] * wgt;
  }
  fused[(size_t)u * (GCN + TOW) + GCN + j] = __float2bfloat16(val / L);
}

// ---------------------------------------------------------------------------
extern "C" void kernel_launch(void* const* d_in, const int* in_sizes, int n_in,
                              void* d_out, int out_size, void* d_ws, size_t ws_size,
                              hipStream_t stream) {
  const float* item_feat = (const float*)d_in[0];
  const float* gcn_item  = (const float*)d_in[1];
  const float* gcn_user  = (const float*)d_in[2];
  const int*   hist_idx  = (const int*)d_in[3];
  const int*   hist_len  = (const int*)d_in[4];
  const float* Wi1 = (const float*)d_in[5];
  const float* bi1 = (const float*)d_in[6];
  const float* Wi2 = (const float*)d_in[7];
  const float* bi2 = (const float*)d_in[8];
  const float* Wq  = (const float*)d_in[9];
  const float* bq  = (const float*)d_in[10];
  const float* Wk  = (const float*)d_in[11];
  const float* bk  = (const float*)d_in[12];  // cancels in softmax (shift-invariance)
  const float* Wu1 = (const float*)d_in[13];
  const float* bu1 = (const float*)d_in[14];
  const float* Wu2 = (const float*)d_in[15];
  const float* bu2 = (const float*)d_in[16];
  (void)bk;

  char* ws = (char*)d_ws;
  bf16*  Wi1p  = (bf16*)(ws + 0);            // 81920 B
  bf16*  Wi2p  = (bf16*)(ws + 81920);        // 131072 B -> 212992
  bf16*  Wu1p  = (bf16*)(ws + 212992);       // 196608 B -> 409600
  bf16*  Wu2p  = (bf16*)(ws + 409600);       // 131072 B -> 540672
  float* Wqkf  = (float*)(ws + 540672);      // 132096 B -> 672768
  bf16*  Wqkp  = (bf16*)(ws + 672768);       // 65536 B -> 738304
  bf16*  A1p   = (bf16*)(ws + 738304);       // 100000*160*2 = 32,000,000 -> 32,738,304
  float* Qt    = (float*)(ws + 738304);      // 16384*256*4 (aliases A1p; A1p dead by then)
  bf16*  h_buf    = (bf16*)(ws + 32738304);  // 100000*256*2 -> 83,938,304
  bf16*  item_emb = (bf16*)(ws + 83938304);  // 100000*256*2 -> 135,138,304
  bf16*  fusedA   = (bf16*)(ws + 135138304); // 16384*384*2 -> 147,721,216
  bf16*  hu_buf   = (bf16*)(ws + 147721216); // 16384*256*2 -> 156,109,824

  // ---- packing / folding ----
  k_prep_w<<<160, 256, 0, stream>>>(Wi1, Wi1p, 130, 5, 16, 1);   // permuted (gcn-first)
  k_prep_w<<<256, 256, 0, stream>>>(Wi2, Wi2p, 256, 8, 16, 0);
  k_prep_w<<<384, 256, 0, stream>>>(Wu1, Wu1p, 384, 12, 16, 0);
  k_prep_w<<<256, 256, 0, stream>>>(Wu2, Wu2p, 256, 8, 16, 0);
  k_fold<<<17, 256, 0, stream>>>(Wq, Wk, bq, Wqkf);
  k_prep_w<<<128, 256, 0, stream>>>(Wqkf, Wqkp, 128, 4, 16, 0);
  k_prep_a1<<<7813, 256, 0, stream>>>(item_feat, gcn_item, A1p);
  k_prep_user<<<8192, 256, 0, stream>>>(gcn_user, fusedA);

  // ---- item tower (split GEMMs, B staged in LDS) ----
  const int itiles = NITEMS / 32;            // 3125
  const int iblk = (itiles + 3) / 4;         // 782
  k_gemm<5, 16, 0, 2><<<iblk, 256, 0, stream>>>(A1p, Wi1p, bi1, h_buf, itiles, 160);
  k_gemm<8, 16, 1, 2><<<iblk, 256, 0, stream>>>(h_buf, Wi2p, bi2, item_emb, itiles, 256);

  // ---- user tower ----
  const int utiles = NUSERS / 32;            // 512
  const int ublk = utiles / 4;               // 128
  k_gemm<4, 16, 4, 2><<<ublk, 256, 0, stream>>>(fusedA, Wqkp, Wqkf + 128 * 256, Qt, utiles, 384);
  k_user_attn<<<NUSERS, 256, 0, stream>>>(Qt, hist_idx, hist_len, item_emb, fusedA);
  k_gemm<12, 16, 0, 2><<<ublk, 256, 0, stream>>>(fusedA, Wu1p, bu1, hu_buf, utiles, 384);
  k_gemm<8, 16, 3, 2><<<ublk, 256, 0, stream>>>(hu_buf, Wu2p, bu2, (float*)d_out, utiles, 256);
}

// Round 10
// 185.684 us; speedup vs baseline: 7.6081x; 1.1464x over previous
//
#include <hip/hip_runtime.h>
#include <hip/hip_bf16.h>
#include <math.h>

#define NITEMS 100000
#define NUSERS 16384
#define HLEN   48
#define GCN    128
#define ATTN_D 128
#define HID    256
#define TOW    256

typedef __attribute__((ext_vector_type(8))) short short8;
typedef __attribute__((ext_vector_type(4))) float f32x4;
typedef __hip_bfloat16 bf16;

static __device__ __forceinline__ float bfu(unsigned short u) {
  unsigned int x = ((unsigned int)u) << 16;
  float f; __builtin_memcpy(&f, &x, 4); return f;
}
static __device__ __forceinline__ short f2bf(float v) {
  bf16 h = __float2bfloat16(v);
  short s; __builtin_memcpy(&s, &h, 2); return s;
}

// global->LDS direct copy, 16B per lane; lds dest = wave-uniform base + lane*16
#define GLDS16(g, l)                                                            \
  __builtin_amdgcn_global_load_lds(                                             \
      (const __attribute__((address_space(1))) unsigned int*)(g),               \
      (__attribute__((address_space(3))) unsigned int*)(l), 16, 0, 0)

// ---------------------------------------------------------------------------
// Prep: pack fp32 weight [Korig][N] -> bf16 fragment-ordered buffer.
// perm=1: source row permuted gcn-first (srck = k<128 ? k+2 : k-128).
// ---------------------------------------------------------------------------
__global__ __launch_bounds__(256) void k_prep_w(const float* __restrict__ W,
                                                bf16* __restrict__ out,
                                                int Korig, int KS, int NT, int perm) {
  int tid = blockIdx.x * 256 + threadIdx.x;
  int total = KS * NT * 512;
  if (tid >= total) return;
  int i  = tid & 7;
  int l  = (tid >> 3) & 63;
  int ct = (tid >> 9) % NT;
  int ks = (tid >> 9) / NT;
  int k   = ks * 32 + ((l >> 4) << 3) + i;
  int col = ct * 16 + (l & 15);
  int N = NT * 16;
  int srck = perm ? ((k < 128) ? (k + 2) : (k - 128)) : k;
  float v = (k < Korig) ? W[(size_t)srck * N + col] : 0.f;
  out[tid] = __float2bfloat16(v);
}

// ---------------------------------------------------------------------------
// Prep item A: A1p[row] = [gcn(128), feat(2), pad(30)] bf16, K=160.
// ---------------------------------------------------------------------------
__global__ __launch_bounds__(256) void k_prep_a1(const float* __restrict__ feat,
                                                 const float* __restrict__ gcn,
                                                 bf16* __restrict__ out) {
  int tid = blockIdx.x * 256 + threadIdx.x;
  if (tid >= NITEMS * 20) return;
  int t = tid % 20;
  size_t row = tid / 20;
  short8 v = (short8){0, 0, 0, 0, 0, 0, 0, 0};
  if (t < 16) {
    const float4* p = (const float4*)(gcn + row * GCN + 8 * t);
    float4 a = p[0], b = p[1];
    v[0] = f2bf(a.x); v[1] = f2bf(a.y); v[2] = f2bf(a.z); v[3] = f2bf(a.w);
    v[4] = f2bf(b.x); v[5] = f2bf(b.y); v[6] = f2bf(b.z); v[7] = f2bf(b.w);
  } else if (t == 16) {
    v[0] = f2bf(feat[row * 2]);
    v[1] = f2bf(feat[row * 2 + 1]);
  }
  *(short8*)(out + row * 160 + 8 * t) = v;
}

__global__ __launch_bounds__(256) void k_prep_user(const float* __restrict__ gcn_user,
                                                   bf16* __restrict__ fused) {
  int tid = blockIdx.x * 256 + threadIdx.x;
  if (tid >= NUSERS * GCN) return;
  int k = tid & 127;
  int u = tid >> 7;
  fused[(size_t)u * (GCN + TOW) + k] = __float2bfloat16(gcn_user[tid]);
}

// ---------------------------------------------------------------------------
// Fold: Wqk[g][t] = (1/sqrt(128)) * sum_d Wq[g][d] * Wk[t][d]   (g<128)
//       b~[t]    = (1/sqrt(128)) * sum_d bq[d]    * Wk[t][d]    (block 16)
// ---------------------------------------------------------------------------
__global__ __launch_bounds__(256) void k_fold(const float* __restrict__ Wq,
                                              const float* __restrict__ Wk,
                                              const float* __restrict__ bq,
                                              float* __restrict__ out) {
  const float INV_S = 0.08838834764831845f;
  const int t = threadIdx.x;
  const int b = blockIdx.x;
  if (b < 16) {
    __shared__ float wq[8][128];
    for (int s = t; s < 8 * 128; s += 256)
      wq[s >> 7][s & 127] = Wq[(size_t)(b * 8 + (s >> 7)) * ATTN_D + (s & 127)];
    __syncthreads();
    float acc[8] = {0.f, 0.f, 0.f, 0.f, 0.f, 0.f, 0.f, 0.f};
    for (int d = 0; d < 128; ++d) {
      const float wk = Wk[(size_t)t * ATTN_D + d];
      #pragma unroll
      for (int gg = 0; gg < 8; ++gg) acc[gg] = fmaf(wq[gg][d], wk, acc[gg]);
    }
    #pragma unroll
    for (int gg = 0; gg < 8; ++gg)
      out[(size_t)(b * 8 + gg) * TOW + t] = acc[gg] * INV_S;
  } else {
    float a = 0.f;
    for (int d = 0; d < 128; ++d)
      a = fmaf(bq[d], Wk[(size_t)t * ATTN_D + d], a);
    out[(size_t)128 * TOW + t] = a * INV_S;
  }
}

// ---------------------------------------------------------------------------
// Big-M MFMA GEMM: 8 waves (512 thr), block = 128 rows x 256 cols.
// Wave w: rows (w&3)*32..+32 (MR=2), cols (w>>2)*128..+128 (NT=8, acc=64 VGPR).
// B slice (16KB/K-step) staged via global_load_lds, double-buffered; A
// register-prefetched one K-step ahead. One barrier per K-step.
// MODE 0: relu->bf16.  MODE 1: l2norm->bf16 (cross-half LDS reduce).
// Caller must pad output buffer: last block writes rows up to 128*gridDim-1.
// ---------------------------------------------------------------------------
template<int KS, int MODE>
__global__ __launch_bounds__(512, 3) void k_gemm_big(
    const bf16* __restrict__ A,
    const bf16* __restrict__ Wf,      // packed NT=16 fragment order
    const float* __restrict__ bias,
    bf16* __restrict__ Cout,
    int Astride)
{
  __shared__ bf16 bs[2][8192];        // 2 x 16KB
  __shared__ float sred[4][2][32];
  const int j  = threadIdx.x;
  const int l  = j & 63;
  const int w  = j >> 6;              // 0..7
  const int rw = w & 3;               // row-wave
  const int ch = w >> 2;              // col half
  const int r = l & 15, g = l >> 4;
  const int R0 = blockIdx.x * 128 + rw * 32;
  const int jb = (j & ~63) * 8;       // wave-uniform LDS element base

  // prologue: stage slice 0 + first A frags
  GLDS16(Wf + (size_t)j * 8,        &bs[0][jb]);
  GLDS16(Wf + 4096 + (size_t)j * 8, &bs[0][4096 + jb]);

  const bf16* arow0 = A + (size_t)(R0 + r) * Astride + g * 8;
  const bf16* arow1 = A + (size_t)(R0 + 16 + r) * Astride + g * 8;
  short8 a0 = *(const short8*)(arow0);
  short8 a1 = *(const short8*)(arow1);

  f32x4 acc[2][8];
  #pragma unroll
  for (int mr = 0; mr < 2; ++mr)
    #pragma unroll
    for (int ct = 0; ct < 8; ++ct) acc[mr][ct] = (f32x4){0.f, 0.f, 0.f, 0.f};

  __syncthreads();  // vmcnt drained: bs[0] + a0/a1 ready

  #pragma unroll
  for (int ks = 0; ks < KS; ++ks) {
    const int cur = ks & 1;
    short8 an0 = a0, an1 = a1;
    if (ks + 1 < KS) {
      an0 = *(const short8*)(arow0 + (ks + 1) * 32);
      an1 = *(const short8*)(arow1 + (ks + 1) * 32);
      const bf16* src = Wf + (size_t)(ks + 1) * 8192;
      GLDS16(src + (size_t)j * 8,        &bs[cur ^ 1][jb]);
      GLDS16(src + 4096 + (size_t)j * 8, &bs[cur ^ 1][4096 + jb]);
    }
    const bf16* wb = &bs[cur][(size_t)(ch * 8) * 512 + (size_t)l * 8];
    #pragma unroll
    for (int ct = 0; ct < 8; ++ct) {
      short8 b = *(const short8*)(wb + ct * 512);
      acc[0][ct] = __builtin_amdgcn_mfma_f32_16x16x32_bf16(a0, b, acc[0][ct], 0, 0, 0);
      acc[1][ct] = __builtin_amdgcn_mfma_f32_16x16x32_bf16(a1, b, acc[1][ct], 0, 0, 0);
    }
    __syncthreads();  // drains stage vmcnt; all waves done with bs[cur]
    a0 = an0; a1 = an1;
  }

  // bias
  #pragma unroll
  for (int ct = 0; ct < 8; ++ct) {
    const float bj = bias[ch * 128 + ct * 16 + r];
    #pragma unroll
    for (int mr = 0; mr < 2; ++mr)
      #pragma unroll
      for (int i = 0; i < 4; ++i) acc[mr][ct][i] += bj;
  }

  if (MODE == 0) {
    #pragma unroll
    for (int mr = 0; mr < 2; ++mr)
      #pragma unroll
      for (int ct = 0; ct < 8; ++ct)
        #pragma unroll
        for (int i = 0; i < 4; ++i)
          Cout[(size_t)(R0 + mr * 16 + g * 4 + i) * 256 + ch * 128 + ct * 16 + r] =
              __float2bfloat16(fmaxf(acc[mr][ct][i], 0.f));
  } else {
    // per-half sumsq, reduce over 16 lanes, combine halves via LDS
    float s0[4] = {0.f, 0.f, 0.f, 0.f}, s1[4] = {0.f, 0.f, 0.f, 0.f};
    #pragma unroll
    for (int ct = 0; ct < 8; ++ct)
      #pragma unroll
      for (int i = 0; i < 4; ++i) {
        s0[i] += acc[0][ct][i] * acc[0][ct][i];
        s1[i] += acc[1][ct][i] * acc[1][ct][i];
      }
    #pragma unroll
    for (int off = 1; off < 16; off <<= 1) {
      #pragma unroll
      for (int i = 0; i < 4; ++i) {
        s0[i] += __shfl_xor(s0[i], off);
        s1[i] += __shfl_xor(s1[i], off);
      }
    }
    if (r == 0) {
      #pragma unroll
      for (int i = 0; i < 4; ++i) {
        sred[rw][ch][g * 4 + i]      = s0[i];
        sred[rw][ch][16 + g * 4 + i] = s1[i];
      }
    }
    __syncthreads();
    float rn0[4], rn1[4];
    #pragma unroll
    for (int i = 0; i < 4; ++i) {
      float t0 = sred[rw][0][g * 4 + i]      + sred[rw][1][g * 4 + i];
      float t1 = sred[rw][0][16 + g * 4 + i] + sred[rw][1][16 + g * 4 + i];
      rn0[i] = 1.f / fmaxf(sqrtf(t0), 1e-12f);
      rn1[i] = 1.f / fmaxf(sqrtf(t1), 1e-12f);
    }
    #pragma unroll
    for (int ct = 0; ct < 8; ++ct)
      #pragma unroll
      for (int i = 0; i < 4; ++i) {
        Cout[(size_t)(R0 + g * 4 + i) * 256 + ch * 128 + ct * 16 + r] =
            __float2bfloat16(acc[0][ct][i] * rn0[i]);
        Cout[(size_t)(R0 + 16 + g * 4 + i) * 256 + ch * 128 + ct * 16 + r] =
            __float2bfloat16(acc[1][ct][i] * rn1[i]);
      }
  }
}

// ---------------------------------------------------------------------------
// Generic MFMA GEMM (user tower), LDS-staged double-buffered B, 4 waves.
// MODE 0: relu->bf16; 3: l2norm->fp32; 4: plain->fp32
// ---------------------------------------------------------------------------
template<int KS, int NT, int MODE, int MR>
__global__ __launch_bounds__(256) void k_gemm(
    const bf16* __restrict__ A,
    const bf16* __restrict__ Wf,
    const float* __restrict__ bias,
    void* __restrict__ Cout,
    int Mtiles, int Astride)
{
  static_assert(NT % 4 == 0, "NT must be divisible by 4");
  constexpr int BSZ = NT * 512;
  constexpr int CH  = NT / 4;
  __shared__ bf16 bs[2][BSZ];
  const int j   = threadIdx.x;
  const int l   = j & 63;
  const int wid = j >> 6;
  int tile = blockIdx.x * 4 + wid;
  if (tile >= Mtiles) tile = Mtiles - 1;
  const int N = NT * 16;
  const int r = l & 15, g = l >> 4;

  {
    const short8* src = (const short8*)Wf;
    short8* dst = (short8*)bs[0];
    #pragma unroll
    for (int c = 0; c < CH; ++c) dst[c * 256 + j] = src[c * 256 + j];
  }

  f32x4 acc[MR][NT];
  #pragma unroll
  for (int mr = 0; mr < MR; ++mr)
    #pragma unroll
    for (int ct = 0; ct < NT; ++ct) acc[mr][ct] = (f32x4){0.f, 0.f, 0.f, 0.f};

  const bf16* arow[MR];
  #pragma unroll
  for (int mr = 0; mr < MR; ++mr)
    arow[mr] = A + (size_t)(tile * (16 * MR) + mr * 16 + r) * Astride + g * 8;

  __syncthreads();

  #pragma unroll
  for (int ks = 0; ks < KS; ++ks) {
    const int cur = ks & 1;
    short8 a[MR];
    #pragma unroll
    for (int mr = 0; mr < MR; ++mr) a[mr] = *(const short8*)(arow[mr] + ks * 32);
    short8 st[CH];
    if (ks + 1 < KS) {
      const short8* src = (const short8*)(Wf + (size_t)(ks + 1) * BSZ);
      #pragma unroll
      for (int c = 0; c < CH; ++c) st[c] = src[c * 256 + j];
    }
    const bf16* wb = bs[cur] + (size_t)l * 8;
    #pragma unroll
    for (int ct = 0; ct < NT; ++ct) {
      short8 b = *(const short8*)(wb + ct * 512);
      #pragma unroll
      for (int mr = 0; mr < MR; ++mr)
        acc[mr][ct] = __builtin_amdgcn_mfma_f32_16x16x32_bf16(a[mr], b, acc[mr][ct], 0, 0, 0);
    }
    if (ks + 1 < KS) {
      short8* dst = (short8*)bs[cur ^ 1];
      #pragma unroll
      for (int c = 0; c < CH; ++c) dst[c * 256 + j] = st[c];
    }
    __syncthreads();
  }

  #pragma unroll
  for (int mr = 0; mr < MR; ++mr) {
    #pragma unroll
    for (int ct = 0; ct < NT; ++ct) {
      const float bj = bias[ct * 16 + r];
      #pragma unroll
      for (int i = 0; i < 4; ++i) acc[mr][ct][i] += bj;
    }
  }

  if (MODE == 0 || MODE == 2 || MODE == 4) {
    #pragma unroll
    for (int mr = 0; mr < MR; ++mr)
      #pragma unroll
      for (int ct = 0; ct < NT; ++ct)
        #pragma unroll
        for (int i = 0; i < 4; ++i) {
          float v = acc[mr][ct][i];
          if (MODE == 0) v = fmaxf(v, 0.f);
          size_t off = (size_t)(tile * (16 * MR) + mr * 16 + g * 4 + i) * N + ct * 16 + r;
          if (MODE == 4) ((float*)Cout)[off] = v;
          else           ((bf16*)Cout)[off]  = __float2bfloat16(v);
        }
  } else {
    #pragma unroll
    for (int mr = 0; mr < MR; ++mr) {
      float s[4] = {0.f, 0.f, 0.f, 0.f};
      #pragma unroll
      for (int ct = 0; ct < NT; ++ct)
        #pragma unroll
        for (int i = 0; i < 4; ++i) s[i] += acc[mr][ct][i] * acc[mr][ct][i];
      #pragma unroll
      for (int off = 1; off < 16; off <<= 1) {
        #pragma unroll
        for (int i = 0; i < 4; ++i) s[i] += __shfl_xor(s[i], off);
      }
      float rn[4];
      #pragma unroll
      for (int i = 0; i < 4; ++i) rn[i] = 1.f / fmaxf(sqrtf(s[i]), 1e-12f);
      #pragma unroll
      for (int ct = 0; ct < NT; ++ct)
        #pragma unroll
        for (int i = 0; i < 4; ++i) {
          size_t off = (size_t)(tile * (16 * MR) + mr * 16 + g * 4 + i) * N + ct * 16 + r;
          float v = acc[mr][ct][i] * rn[i];
          if (MODE == 3) ((float*)Cout)[off] = v;
          else           ((bf16*)Cout)[off]  = __float2bfloat16(v);
        }
    }
  }
}

// ---------------------------------------------------------------------------
// Attention v6: single-pass online softmax, no emb staging.
// ---------------------------------------------------------------------------
__global__ __launch_bounds__(256) void k_user_attn(
    const float* __restrict__ Qt,          // [NUSERS][TOW] fp32 (Wqk-folded)
    const int*   __restrict__ hist_idx,
    const int*   __restrict__ hist_len,
    const bf16*  __restrict__ item_emb,    // [NITEMS][TOW] bf16
    bf16* __restrict__ fused)
{
  const int u = blockIdx.x;
  const int j = threadIdx.x;
  const int wid = j >> 6, lane = j & 63;
  __shared__ int   idx[HLEN];
  __shared__ float red[4][TOW];
  __shared__ float ml[4][2];

  const int nv = hist_len[u] + 1;

  if (j < HLEN) idx[j] = hist_idx[u * HLEN + j];
  const f32x4 q = *(const f32x4*)(Qt + (size_t)u * TOW + 4 * lane);
  __syncthreads();

  float m = -1e30f, l = 0.f;
  f32x4 O = (f32x4){0.f, 0.f, 0.f, 0.f};

  int h = wid;
  ushort4 cur = (ushort4){0, 0, 0, 0};
  if (h < nv) cur = *(const ushort4*)(item_emb + (size_t)idx[h] * TOW + 4 * lane);
  for (; h < nv; h += 4) {
    const ushort4 e = cur;
    if (h + 4 < nv)
      cur = *(const ushort4*)(item_emb + (size_t)idx[h + 4] * TOW + 4 * lane);
    const float ex = bfu(e.x), ey = bfu(e.y), ez = bfu(e.z), ew = bfu(e.w);
    float sc = q.x * ex + q.y * ey + q.z * ez + q.w * ew;
    #pragma unroll
    for (int off = 32; off; off >>= 1) sc += __shfl_xor(sc, off);
    const float mn = fmaxf(m, sc);
    const float rs = __expf(m - mn);
    const float p  = __expf(sc - mn);
    m = mn;
    l = l * rs + p;
    O.x = O.x * rs + p * ex;
    O.y = O.y * rs + p * ey;
    O.z = O.z * rs + p * ez;
    O.w = O.w * rs + p * ew;
  }

  *(f32x4*)(&red[wid][4 * lane]) = O;
  if (lane == 0) { ml[wid][0] = m; ml[wid][1] = l; }
  __syncthreads();

  const float M = fmaxf(fmaxf(ml[0][0], ml[1][0]), fmaxf(ml[2][0], ml[3][0]));
  float L = 0.f, val = 0.f;
  #pragma unroll
  for (int w = 0; w < 4; ++w) {
    const float wgt = __expf(ml[w][0] - M);
    L   += ml[w][1] * wgt;
    val += red[w][j] * wgt;
  }
  fused[(size_t)u * (GCN + TOW) + GCN + j] = __float2bfloat16(val / L);
}

// ---------------------------------------------------------------------------
extern "C" void kernel_launch(void* const* d_in, const int* in_sizes, int n_in,
                              void* d_out, int out_size, void* d_ws, size_t ws_size,
                              hipStream_t stream) {
  const float* item_feat = (const float*)d_in[0];
  const float* gcn_item  = (const float*)d_in[1];
  const float* gcn_user  = (const float*)d_in[2];
  const int*   hist_idx  = (const int*)d_in[3];
  const int*   hist_len  = (const int*)d_in[4];
  const float* Wi1 = (const float*)d_in[5];
  const float* bi1 = (const float*)d_in[6];
  const float* Wi2 = (const float*)d_in[7];
  const float* bi2 = (const float*)d_in[8];
  const float* Wq  = (const float*)d_in[9];
  const float* bq  = (const float*)d_in[10];
  const float* Wk  = (const float*)d_in[11];
  const float* bk  = (const float*)d_in[12];  // cancels in softmax
  const float* Wu1 = (const float*)d_in[13];
  const float* bu1 = (const float*)d_in[14];
  const float* Wu2 = (const float*)d_in[15];
  const float* bu2 = (const float*)d_in[16];
  (void)bk;

  char* ws = (char*)d_ws;
  bf16*  Wi1p  = (bf16*)(ws + 0);            // 81920 B
  bf16*  Wi2p  = (bf16*)(ws + 81920);        // -> 212992
  bf16*  Wu1p  = (bf16*)(ws + 212992);       // -> 409600
  bf16*  Wu2p  = (bf16*)(ws + 409600);       // -> 540672
  float* Wqkf  = (float*)(ws + 540672);      // -> 672768
  bf16*  Wqkp  = (bf16*)(ws + 672768);       // -> 738304
  bf16*  A1p   = (bf16*)(ws + 738304);       // 32,000,000 -> 32,738,304
  float* Qt    = (float*)(ws + 738304);      // aliases A1p (dead by then)
  // 64KB pads after h_buf and item_emb absorb last-block (rows>=NITEMS) spill
  bf16*  h_buf    = (bf16*)(ws + 32738304);  // 51,200,000 + 65,536 pad -> 84,003,840
  bf16*  item_emb = (bf16*)(ws + 84003840);  // 51,200,000 + 65,536 pad -> 135,269,376
  bf16*  fusedA   = (bf16*)(ws + 135269376); // 12,582,912 -> 147,852,288
  bf16*  hu_buf   = (bf16*)(ws + 147852288); // 8,388,608 -> 156,240,896

  // ---- packing / folding ----
  k_prep_w<<<160, 256, 0, stream>>>(Wi1, Wi1p, 130, 5, 16, 1);   // permuted (gcn-first)
  k_prep_w<<<256, 256, 0, stream>>>(Wi2, Wi2p, 256, 8, 16, 0);
  k_prep_w<<<384, 256, 0, stream>>>(Wu1, Wu1p, 384, 12, 16, 0);
  k_prep_w<<<256, 256, 0, stream>>>(Wu2, Wu2p, 256, 8, 16, 0);
  k_fold<<<17, 256, 0, stream>>>(Wq, Wk, bq, Wqkf);
  k_prep_w<<<128, 256, 0, stream>>>(Wqkf, Wqkp, 128, 4, 16, 0);
  k_prep_a1<<<7813, 256, 0, stream>>>(item_feat, gcn_item, A1p);
  k_prep_user<<<8192, 256, 0, stream>>>(gcn_user, fusedA);

  // ---- item tower: 8-wave blocks, 128 rows each ----
  const int iblk = (NITEMS + 127) / 128;     // 782
  k_gemm_big<5, 0><<<iblk, 512, 0, stream>>>(A1p, Wi1p, bi1, h_buf, 160);
  k_gemm_big<8, 1><<<iblk, 512, 0, stream>>>(h_buf, Wi2p, bi2, item_emb, 256);

  // ---- user tower ----
  const int utiles = NUSERS / 32;            // 512
  const int ublk = utiles / 4;               // 128
  k_gemm<4, 16, 4, 2><<<ublk, 256, 0, stream>>>(fusedA, Wqkp, Wqkf + 128 * 256, Qt, utiles, 384);
  k_user_attn<<<NUSERS, 256, 0, stream>>>(Qt, hist_idx, hist_len, item_emb, fusedA);
  k_gemm<12, 16, 0, 2><<<ublk, 256, 0, stream>>>(fusedA, Wu1p, bu1, hu_buf, utiles, 384);
  k_gemm<8, 16, 3, 2><<<ublk, 256, 0, stream>>>(hu_buf, Wu2p, bu2, (float*)d_out, utiles, 256);
}

// Round 11
// 174.300 us; speedup vs baseline: 8.1051x; 1.0653x over previous
//
#include <hip/hip_runtime.h>
#include <hip/hip_bf16.h>
#include <math.h>

#define NITEMS 100000
#define NUSERS 16384
#define HLEN   48
#define GCN    128
#define ATTN_D 128
#define HID    256
#define TOW    256

typedef __attribute__((ext_vector_type(8))) short short8;
typedef __attribute__((ext_vector_type(4))) float f32x4;
typedef __hip_bfloat16 bf16;

static __device__ __forceinline__ float bfu(unsigned short u) {
  unsigned int x = ((unsigned int)u) << 16;
  float f; __builtin_memcpy(&f, &x, 4); return f;
}
static __device__ __forceinline__ short f2bf(float v) {
  bf16 h = __float2bfloat16(v);
  short s; __builtin_memcpy(&s, &h, 2); return s;
}

// global->LDS direct copy, 16B per lane; lds dest = wave-uniform base + lane*16
#define GLDS16(g, l)                                                            \
  __builtin_amdgcn_global_load_lds(                                             \
      (const __attribute__((address_space(1))) unsigned int*)(g),               \
      (__attribute__((address_space(3))) unsigned int*)(l), 16, 0, 0)

// ---------------------------------------------------------------------------
// Prep: pack fp32 weight [Korig][N] -> bf16 fragment-ordered buffer.
// perm=1: source row permuted gcn-first (srck = k<128 ? k+2 : k-128).
// ---------------------------------------------------------------------------
__global__ __launch_bounds__(256) void k_prep_w(const float* __restrict__ W,
                                                bf16* __restrict__ out,
                                                int Korig, int KS, int NT, int perm) {
  int tid = blockIdx.x * 256 + threadIdx.x;
  int total = KS * NT * 512;
  if (tid >= total) return;
  int i  = tid & 7;
  int l  = (tid >> 3) & 63;
  int ct = (tid >> 9) % NT;
  int ks = (tid >> 9) / NT;
  int k   = ks * 32 + ((l >> 4) << 3) + i;
  int col = ct * 16 + (l & 15);
  int N = NT * 16;
  int srck = perm ? ((k < 128) ? (k + 2) : (k - 128)) : k;
  float v = (k < Korig) ? W[(size_t)srck * N + col] : 0.f;
  out[tid] = __float2bfloat16(v);
}

// ---------------------------------------------------------------------------
// Prep item A: A1p[row] = [gcn(128), feat(2), pad(30)] bf16, K=160.
// ---------------------------------------------------------------------------
__global__ __launch_bounds__(256) void k_prep_a1(const float* __restrict__ feat,
                                                 const float* __restrict__ gcn,
                                                 bf16* __restrict__ out) {
  int tid = blockIdx.x * 256 + threadIdx.x;
  if (tid >= NITEMS * 20) return;
  int t = tid % 20;
  size_t row = tid / 20;
  short8 v = (short8){0, 0, 0, 0, 0, 0, 0, 0};
  if (t < 16) {
    const float4* p = (const float4*)(gcn + row * GCN + 8 * t);
    float4 a = p[0], b = p[1];
    v[0] = f2bf(a.x); v[1] = f2bf(a.y); v[2] = f2bf(a.z); v[3] = f2bf(a.w);
    v[4] = f2bf(b.x); v[5] = f2bf(b.y); v[6] = f2bf(b.z); v[7] = f2bf(b.w);
  } else if (t == 16) {
    v[0] = f2bf(feat[row * 2]);
    v[1] = f2bf(feat[row * 2 + 1]);
  }
  *(short8*)(out + row * 160 + 8 * t) = v;
}

__global__ __launch_bounds__(256) void k_prep_user(const float* __restrict__ gcn_user,
                                                   bf16* __restrict__ fused) {
  int tid = blockIdx.x * 256 + threadIdx.x;
  if (tid >= NUSERS * GCN) return;
  int k = tid & 127;
  int u = tid >> 7;
  fused[(size_t)u * (GCN + TOW) + k] = __float2bfloat16(gcn_user[tid]);
}

// ---------------------------------------------------------------------------
// Fold: Wqk[g][t] = (1/sqrt(128)) * sum_d Wq[g][d] * Wk[t][d]   (g<128)
//       b~[t]    = (1/sqrt(128)) * sum_d bq[d]    * Wk[t][d]    (block 16)
// ---------------------------------------------------------------------------
__global__ __launch_bounds__(256) void k_fold(const float* __restrict__ Wq,
                                              const float* __restrict__ Wk,
                                              const float* __restrict__ bq,
                                              float* __restrict__ out) {
  const float INV_S = 0.08838834764831845f;
  const int t = threadIdx.x;
  const int b = blockIdx.x;
  if (b < 16) {
    __shared__ float wq[8][128];
    for (int s = t; s < 8 * 128; s += 256)
      wq[s >> 7][s & 127] = Wq[(size_t)(b * 8 + (s >> 7)) * ATTN_D + (s & 127)];
    __syncthreads();
    float acc[8] = {0.f, 0.f, 0.f, 0.f, 0.f, 0.f, 0.f, 0.f};
    for (int d = 0; d < 128; ++d) {
      const float wk = Wk[(size_t)t * ATTN_D + d];
      #pragma unroll
      for (int gg = 0; gg < 8; ++gg) acc[gg] = fmaf(wq[gg][d], wk, acc[gg]);
    }
    #pragma unroll
    for (int gg = 0; gg < 8; ++gg)
      out[(size_t)(b * 8 + gg) * TOW + t] = acc[gg] * INV_S;
  } else {
    float a = 0.f;
    for (int d = 0; d < 128; ++d)
      a = fmaf(bq[d], Wk[(size_t)t * ATTN_D + d], a);
    out[(size_t)128 * TOW + t] = a * INV_S;
  }
}

// ---------------------------------------------------------------------------
// Big-M MFMA GEMM: 8 waves (512 thr), block = 128 rows x 256 cols.
// ---------------------------------------------------------------------------
template<int KS, int MODE>
__global__ __launch_bounds__(512, 3) void k_gemm_big(
    const bf16* __restrict__ A,
    const bf16* __restrict__ Wf,
    const float* __restrict__ bias,
    bf16* __restrict__ Cout,
    int Astride)
{
  __shared__ bf16 bs[2][8192];
  __shared__ float sred[4][2][32];
  const int j  = threadIdx.x;
  const int l  = j & 63;
  const int w  = j >> 6;
  const int rw = w & 3;
  const int ch = w >> 2;
  const int r = l & 15, g = l >> 4;
  const int R0 = blockIdx.x * 128 + rw * 32;
  const int jb = (j & ~63) * 8;

  GLDS16(Wf + (size_t)j * 8,        &bs[0][jb]);
  GLDS16(Wf + 4096 + (size_t)j * 8, &bs[0][4096 + jb]);

  const bf16* arow0 = A + (size_t)(R0 + r) * Astride + g * 8;
  const bf16* arow1 = A + (size_t)(R0 + 16 + r) * Astride + g * 8;
  short8 a0 = *(const short8*)(arow0);
  short8 a1 = *(const short8*)(arow1);

  f32x4 acc[2][8];
  #pragma unroll
  for (int mr = 0; mr < 2; ++mr)
    #pragma unroll
    for (int ct = 0; ct < 8; ++ct) acc[mr][ct] = (f32x4){0.f, 0.f, 0.f, 0.f};

  __syncthreads();

  #pragma unroll
  for (int ks = 0; ks < KS; ++ks) {
    const int cur = ks & 1;
    short8 an0 = a0, an1 = a1;
    if (ks + 1 < KS) {
      an0 = *(const short8*)(arow0 + (ks + 1) * 32);
      an1 = *(const short8*)(arow1 + (ks + 1) * 32);
      const bf16* src = Wf + (size_t)(ks + 1) * 8192;
      GLDS16(src + (size_t)j * 8,        &bs[cur ^ 1][jb]);
      GLDS16(src + 4096 + (size_t)j * 8, &bs[cur ^ 1][4096 + jb]);
    }
    const bf16* wb = &bs[cur][(size_t)(ch * 8) * 512 + (size_t)l * 8];
    #pragma unroll
    for (int ct = 0; ct < 8; ++ct) {
      short8 b = *(const short8*)(wb + ct * 512);
      acc[0][ct] = __builtin_amdgcn_mfma_f32_16x16x32_bf16(a0, b, acc[0][ct], 0, 0, 0);
      acc[1][ct] = __builtin_amdgcn_mfma_f32_16x16x32_bf16(a1, b, acc[1][ct], 0, 0, 0);
    }
    __syncthreads();
    a0 = an0; a1 = an1;
  }

  #pragma unroll
  for (int ct = 0; ct < 8; ++ct) {
    const float bj = bias[ch * 128 + ct * 16 + r];
    #pragma unroll
    for (int mr = 0; mr < 2; ++mr)
      #pragma unroll
      for (int i = 0; i < 4; ++i) acc[mr][ct][i] += bj;
  }

  if (MODE == 0) {
    #pragma unroll
    for (int mr = 0; mr < 2; ++mr)
      #pragma unroll
      for (int ct = 0; ct < 8; ++ct)
        #pragma unroll
        for (int i = 0; i < 4; ++i)
          Cout[(size_t)(R0 + mr * 16 + g * 4 + i) * 256 + ch * 128 + ct * 16 + r] =
              __float2bfloat16(fmaxf(acc[mr][ct][i], 0.f));
  } else {
    float s0[4] = {0.f, 0.f, 0.f, 0.f}, s1[4] = {0.f, 0.f, 0.f, 0.f};
    #pragma unroll
    for (int ct = 0; ct < 8; ++ct)
      #pragma unroll
      for (int i = 0; i < 4; ++i) {
        s0[i] += acc[0][ct][i] * acc[0][ct][i];
        s1[i] += acc[1][ct][i] * acc[1][ct][i];
      }
    #pragma unroll
    for (int off = 1; off < 16; off <<= 1) {
      #pragma unroll
      for (int i = 0; i < 4; ++i) {
        s0[i] += __shfl_xor(s0[i], off);
        s1[i] += __shfl_xor(s1[i], off);
      }
    }
    if (r == 0) {
      #pragma unroll
      for (int i = 0; i < 4; ++i) {
        sred[rw][ch][g * 4 + i]      = s0[i];
        sred[rw][ch][16 + g * 4 + i] = s1[i];
      }
    }
    __syncthreads();
    float rn0[4], rn1[4];
    #pragma unroll
    for (int i = 0; i < 4; ++i) {
      float t0 = sred[rw][0][g * 4 + i]      + sred[rw][1][g * 4 + i];
      float t1 = sred[rw][0][16 + g * 4 + i] + sred[rw][1][16 + g * 4 + i];
      rn0[i] = 1.f / fmaxf(sqrtf(t0), 1e-12f);
      rn1[i] = 1.f / fmaxf(sqrtf(t1), 1e-12f);
    }
    #pragma unroll
    for (int ct = 0; ct < 8; ++ct)
      #pragma unroll
      for (int i = 0; i < 4; ++i) {
        Cout[(size_t)(R0 + g * 4 + i) * 256 + ch * 128 + ct * 16 + r] =
            __float2bfloat16(acc[0][ct][i] * rn0[i]);
        Cout[(size_t)(R0 + 16 + g * 4 + i) * 256 + ch * 128 + ct * 16 + r] =
            __float2bfloat16(acc[1][ct][i] * rn1[i]);
      }
  }
}

// ---------------------------------------------------------------------------
// Generic MFMA GEMM (user tower), LDS-staged double-buffered B, 4 waves.
// MODE 0: relu->bf16; 3: l2norm->fp32; 4: plain->fp32
// ---------------------------------------------------------------------------
template<int KS, int NT, int MODE, int MR>
__global__ __launch_bounds__(256) void k_gemm(
    const bf16* __restrict__ A,
    const bf16* __restrict__ Wf,
    const float* __restrict__ bias,
    void* __restrict__ Cout,
    int Mtiles, int Astride)
{
  static_assert(NT % 4 == 0, "NT must be divisible by 4");
  constexpr int BSZ = NT * 512;
  constexpr int CH  = NT / 4;
  __shared__ bf16 bs[2][BSZ];
  const int j   = threadIdx.x;
  const int l   = j & 63;
  const int wid = j >> 6;
  int tile = blockIdx.x * 4 + wid;
  if (tile >= Mtiles) tile = Mtiles - 1;
  const int N = NT * 16;
  const int r = l & 15, g = l >> 4;

  {
    const short8* src = (const short8*)Wf;
    short8* dst = (short8*)bs[0];
    #pragma unroll
    for (int c = 0; c < CH; ++c) dst[c * 256 + j] = src[c * 256 + j];
  }

  f32x4 acc[MR][NT];
  #pragma unroll
  for (int mr = 0; mr < MR; ++mr)
    #pragma unroll
    for (int ct = 0; ct < NT; ++ct) acc[mr][ct] = (f32x4){0.f, 0.f, 0.f, 0.f};

  const bf16* arow[MR];
  #pragma unroll
  for (int mr = 0; mr < MR; ++mr)
    arow[mr] = A + (size_t)(tile * (16 * MR) + mr * 16 + r) * Astride + g * 8;

  __syncthreads();

  #pragma unroll
  for (int ks = 0; ks < KS; ++ks) {
    const int cur = ks & 1;
    short8 a[MR];
    #pragma unroll
    for (int mr = 0; mr < MR; ++mr) a[mr] = *(const short8*)(arow[mr] + ks * 32);
    short8 st[CH];
    if (ks + 1 < KS) {
      const short8* src = (const short8*)(Wf + (size_t)(ks + 1) * BSZ);
      #pragma unroll
      for (int c = 0; c < CH; ++c) st[c] = src[c * 256 + j];
    }
    const bf16* wb = bs[cur] + (size_t)l * 8;
    #pragma unroll
    for (int ct = 0; ct < NT; ++ct) {
      short8 b = *(const short8*)(wb + ct * 512);
      #pragma unroll
      for (int mr = 0; mr < MR; ++mr)
        acc[mr][ct] = __builtin_amdgcn_mfma_f32_16x16x32_bf16(a[mr], b, acc[mr][ct], 0, 0, 0);
    }
    if (ks + 1 < KS) {
      short8* dst = (short8*)bs[cur ^ 1];
      #pragma unroll
      for (int c = 0; c < CH; ++c) dst[c * 256 + j] = st[c];
    }
    __syncthreads();
  }

  #pragma unroll
  for (int mr = 0; mr < MR; ++mr) {
    #pragma unroll
    for (int ct = 0; ct < NT; ++ct) {
      const float bj = bias[ct * 16 + r];
      #pragma unroll
      for (int i = 0; i < 4; ++i) acc[mr][ct][i] += bj;
    }
  }

  if (MODE == 0 || MODE == 2 || MODE == 4) {
    #pragma unroll
    for (int mr = 0; mr < MR; ++mr)
      #pragma unroll
      for (int ct = 0; ct < NT; ++ct)
        #pragma unroll
        for (int i = 0; i < 4; ++i) {
          float v = acc[mr][ct][i];
          if (MODE == 0) v = fmaxf(v, 0.f);
          size_t off = (size_t)(tile * (16 * MR) + mr * 16 + g * 4 + i) * N + ct * 16 + r;
          if (MODE == 4) ((float*)Cout)[off] = v;
          else           ((bf16*)Cout)[off]  = __float2bfloat16(v);
        }
  } else {
    #pragma unroll
    for (int mr = 0; mr < MR; ++mr) {
      float s[4] = {0.f, 0.f, 0.f, 0.f};
      #pragma unroll
      for (int ct = 0; ct < NT; ++ct)
        #pragma unroll
        for (int i = 0; i < 4; ++i) s[i] += acc[mr][ct][i] * acc[mr][ct][i];
      #pragma unroll
      for (int off = 1; off < 16; off <<= 1) {
        #pragma unroll
        for (int i = 0; i < 4; ++i) s[i] += __shfl_xor(s[i], off);
      }
      float rn[4];
      #pragma unroll
      for (int i = 0; i < 4; ++i) rn[i] = 1.f / fmaxf(sqrtf(s[i]), 1e-12f);
      #pragma unroll
      for (int ct = 0; ct < NT; ++ct)
        #pragma unroll
        for (int i = 0; i < 4; ++i) {
          size_t off = (size_t)(tile * (16 * MR) + mr * 16 + g * 4 + i) * N + ct * 16 + r;
          float v = acc[mr][ct][i] * rn[i];
          if (MODE == 3) ((float*)Cout)[off] = v;
          else           ((bf16*)Cout)[off]  = __float2bfloat16(v);
        }
    }
  }
}

// ---------------------------------------------------------------------------
// Attention v7: 16-lane row groups, no-max softmax (scores |s|<0.1 by
// construction: |Wqk|~4e-4, ||emb||=1 — exp() safe; max-shift cancels).
// 16 partials (4 waves x 4 groups), lane holds 16 dims; plain sum merge.
// ---------------------------------------------------------------------------
__global__ __launch_bounds__(256) void k_user_attn(
    const float* __restrict__ Qt,          // [NUSERS][TOW] fp32 (Wqk-folded)
    const int*   __restrict__ hist_idx,
    const int*   __restrict__ hist_len,
    const bf16*  __restrict__ item_emb,    // [NITEMS][TOW] bf16
    bf16* __restrict__ fused)
{
  const int u = blockIdx.x;
  const int j = threadIdx.x;
  const int wid = j >> 6, lane = j & 63;
  const int g = lane >> 4, r = lane & 15;   // group 0..3, lane-in-group 0..15
  const int part = wid * 4 + g;             // partial id 0..15
  __shared__ int   idx[HLEN];
  __shared__ float redO[16][TOW + 4];
  __shared__ float redL[16];

  const int nv = hist_len[u] + 1;           // 1..48 valid entries

  if (j < HLEN) idx[j] = hist_idx[u * HLEN + j];
  // q dims r*16 .. r*16+15 (same for all 4 groups of a wave)
  const float* qp = Qt + (size_t)u * TOW + r * 16;
  f32x4 q0 = *(const f32x4*)(qp);
  f32x4 q1 = *(const f32x4*)(qp + 4);
  f32x4 q2 = *(const f32x4*)(qp + 8);
  f32x4 q3 = *(const f32x4*)(qp + 12);
  __syncthreads();

  float l = 0.f;
  f32x4 O0 = (f32x4){0.f,0.f,0.f,0.f}, O1 = O0, O2 = O0, O3 = O0;

  for (int h = part; h < nv; h += 16) {
    const bf16* e = item_emb + (size_t)idx[h] * TOW + r * 16;
    short8 e0 = *(const short8*)e;
    short8 e1 = *(const short8*)(e + 8);
    float ef[16];
    #pragma unroll
    for (int i = 0; i < 8; ++i) ef[i]     = bfu((unsigned short)e0[i]);
    #pragma unroll
    for (int i = 0; i < 8; ++i) ef[8 + i] = bfu((unsigned short)e1[i]);

    float sc = q0.x*ef[0] + q0.y*ef[1] + q0.z*ef[2] + q0.w*ef[3]
             + q1.x*ef[4] + q1.y*ef[5] + q1.z*ef[6] + q1.w*ef[7]
             + q2.x*ef[8] + q2.y*ef[9] + q2.z*ef[10]+ q2.w*ef[11]
             + q3.x*ef[12]+ q3.y*ef[13]+ q3.z*ef[14]+ q3.w*ef[15];
    // reduce within the 16-lane group (xor offsets 1,2,4,8 stay in-group)
    #pragma unroll
    for (int off = 1; off < 16; off <<= 1) sc += __shfl_xor(sc, off);
    const float p = __expf(sc);
    l += p;
    O0.x += p*ef[0];  O0.y += p*ef[1];  O0.z += p*ef[2];  O0.w += p*ef[3];
    O1.x += p*ef[4];  O1.y += p*ef[5];  O1.z += p*ef[6];  O1.w += p*ef[7];
    O2.x += p*ef[8];  O2.y += p*ef[9];  O2.z += p*ef[10]; O2.w += p*ef[11];
    O3.x += p*ef[12]; O3.y += p*ef[13]; O3.z += p*ef[14]; O3.w += p*ef[15];
  }

  *(f32x4*)(&redO[part][r * 16])      = O0;
  *(f32x4*)(&redO[part][r * 16 + 4])  = O1;
  *(f32x4*)(&redO[part][r * 16 + 8])  = O2;
  *(f32x4*)(&redO[part][r * 16 + 12]) = O3;
  if (r == 0) redL[part] = l;
  __syncthreads();

  // combine: thread j owns output dim j (partials with no rows are 0)
  float L = 0.f, val = 0.f;
  #pragma unroll
  for (int w = 0; w < 16; ++w) {
    L   += redL[w];
    val += redO[w][j];
  }
  fused[(size_t)u * (GCN + TOW) + GCN + j] = __float2bfloat16(val / L);
}

// ---------------------------------------------------------------------------
extern "C" void kernel_launch(void* const* d_in, const int* in_sizes, int n_in,
                              void* d_out, int out_size, void* d_ws, size_t ws_size,
                              hipStream_t stream) {
  const float* item_feat = (const float*)d_in[0];
  const float* gcn_item  = (const float*)d_in[1];
  const float* gcn_user  = (const float*)d_in[2];
  const int*   hist_idx  = (const int*)d_in[3];
  const int*   hist_len  = (const int*)d_in[4];
  const float* Wi1 = (const float*)d_in[5];
  const float* bi1 = (const float*)d_in[6];
  const float* Wi2 = (const float*)d_in[7];
  const float* bi2 = (const float*)d_in[8];
  const float* Wq  = (const float*)d_in[9];
  const float* bq  = (const float*)d_in[10];
  const float* Wk  = (const float*)d_in[11];
  const float* bk  = (const float*)d_in[12];  // cancels in softmax
  const float* Wu1 = (const float*)d_in[13];
  const float* bu1 = (const float*)d_in[14];
  const float* Wu2 = (const float*)d_in[15];
  const float* bu2 = (const float*)d_in[16];
  (void)bk;

  char* ws = (char*)d_ws;
  bf16*  Wi1p  = (bf16*)(ws + 0);            // 81920 B
  bf16*  Wi2p  = (bf16*)(ws + 81920);        // -> 212992
  bf16*  Wu1p  = (bf16*)(ws + 212992);       // -> 409600
  bf16*  Wu2p  = (bf16*)(ws + 409600);       // -> 540672
  float* Wqkf  = (float*)(ws + 540672);      // -> 672768
  bf16*  Wqkp  = (bf16*)(ws + 672768);       // -> 738304
  bf16*  A1p   = (bf16*)(ws + 738304);       // 32,000,000 -> 32,738,304
  float* Qt    = (float*)(ws + 738304);      // aliases A1p (dead by then)
  bf16*  h_buf    = (bf16*)(ws + 32738304);  // 51,200,000 + 64KB pad -> 84,003,840
  bf16*  item_emb = (bf16*)(ws + 84003840);  // 51,200,000 + 64KB pad -> 135,269,376
  bf16*  fusedA   = (bf16*)(ws + 135269376); // 12,582,912 -> 147,852,288
  bf16*  hu_buf   = (bf16*)(ws + 147852288); // 8,388,608 -> 156,240,896

  // ---- packing / folding ----
  k_prep_w<<<160, 256, 0, stream>>>(Wi1, Wi1p, 130, 5, 16, 1);   // permuted (gcn-first)
  k_prep_w<<<256, 256, 0, stream>>>(Wi2, Wi2p, 256, 8, 16, 0);
  k_prep_w<<<384, 256, 0, stream>>>(Wu1, Wu1p, 384, 12, 16, 0);
  k_prep_w<<<256, 256, 0, stream>>>(Wu2, Wu2p, 256, 8, 16, 0);
  k_fold<<<17, 256, 0, stream>>>(Wq, Wk, bq, Wqkf);
  k_prep_w<<<128, 256, 0, stream>>>(Wqkf, Wqkp, 128, 4, 16, 0);
  k_prep_a1<<<7813, 256, 0, stream>>>(item_feat, gcn_item, A1p);
  k_prep_user<<<8192, 256, 0, stream>>>(gcn_user, fusedA);

  // ---- item tower: 8-wave blocks, 128 rows each ----
  const int iblk = (NITEMS + 127) / 128;     // 782
  k_gemm_big<5, 0><<<iblk, 512, 0, stream>>>(A1p, Wi1p, bi1, h_buf, 160);
  k_gemm_big<8, 1><<<iblk, 512, 0, stream>>>(h_buf, Wi2p, bi2, item_emb, 256);

  // ---- user tower ----
  const int utiles = NUSERS / 32;            // 512
  const int ublk = utiles / 4;               // 128
  k_gemm<4, 16, 4, 2><<<ublk, 256, 0, stream>>>(fusedA, Wqkp, Wqkf + 128 * 256, Qt, utiles, 384);
  k_user_attn<<<NUSERS, 256, 0, stream>>>(Qt, hist_idx, hist_len, item_emb, fusedA);
  k_gemm<12, 16, 0, 2><<<ublk, 256, 0, stream>>>(fusedA, Wu1p, bu1, hu_buf, utiles, 384);
  k_gemm<8, 16, 3, 2><<<ublk, 256, 0, stream>>>(hu_buf, Wu2p, bu2, (float*)d_out, utiles, 256);
}

// Round 12
// 167.791 us; speedup vs baseline: 8.4194x; 1.0388x over previous
//
#include <hip/hip_runtime.h>
#include <hip/hip_bf16.h>
#include <math.h>

#define NITEMS 100000
#define NUSERS 16384
#define HLEN   48
#define GCN    128
#define ATTN_D 128
#define HID    256
#define TOW    256

typedef __attribute__((ext_vector_type(8))) short short8;
typedef __attribute__((ext_vector_type(4))) float f32x4;
typedef __hip_bfloat16 bf16;

static __device__ __forceinline__ float bfu(unsigned short u) {
  unsigned int x = ((unsigned int)u) << 16;
  float f; __builtin_memcpy(&f, &x, 4); return f;
}
static __device__ __forceinline__ short f2bf(float v) {
  bf16 h = __float2bfloat16(v);
  short s; __builtin_memcpy(&s, &h, 2); return s;
}

// global->LDS direct copy, 16B per lane; lds dest = wave-uniform base + lane*16
#define GLDS16(g, l)                                                            \
  __builtin_amdgcn_global_load_lds(                                             \
      (const __attribute__((address_space(1))) unsigned int*)(g),               \
      (__attribute__((address_space(3))) unsigned int*)(l), 16, 0, 0)

// ---------------------------------------------------------------------------
// Prep: pack fp32 weight [Korig][N] -> bf16 fragment-ordered buffer.
// perm=1: source row permuted gcn-first (srck = k<128 ? k+2 : k-128).
// ---------------------------------------------------------------------------
__global__ __launch_bounds__(256) void k_prep_w(const float* __restrict__ W,
                                                bf16* __restrict__ out,
                                                int Korig, int KS, int NT, int perm) {
  int tid = blockIdx.x * 256 + threadIdx.x;
  int total = KS * NT * 512;
  if (tid >= total) return;
  int i  = tid & 7;
  int l  = (tid >> 3) & 63;
  int ct = (tid >> 9) % NT;
  int ks = (tid >> 9) / NT;
  int k   = ks * 32 + ((l >> 4) << 3) + i;
  int col = ct * 16 + (l & 15);
  int N = NT * 16;
  int srck = perm ? ((k < 128) ? (k + 2) : (k - 128)) : k;
  float v = (k < Korig) ? W[(size_t)srck * N + col] : 0.f;
  out[tid] = __float2bfloat16(v);
}

// ---------------------------------------------------------------------------
// Prep item A: A1p[row] = [gcn(128), feat(2), pad(30)] bf16, K=160.
// ---------------------------------------------------------------------------
__global__ __launch_bounds__(256) void k_prep_a1(const float* __restrict__ feat,
                                                 const float* __restrict__ gcn,
                                                 bf16* __restrict__ out) {
  int tid = blockIdx.x * 256 + threadIdx.x;
  if (tid >= NITEMS * 20) return;
  int t = tid % 20;
  size_t row = tid / 20;
  short8 v = (short8){0, 0, 0, 0, 0, 0, 0, 0};
  if (t < 16) {
    const float4* p = (const float4*)(gcn + row * GCN + 8 * t);
    float4 a = p[0], b = p[1];
    v[0] = f2bf(a.x); v[1] = f2bf(a.y); v[2] = f2bf(a.z); v[3] = f2bf(a.w);
    v[4] = f2bf(b.x); v[5] = f2bf(b.y); v[6] = f2bf(b.z); v[7] = f2bf(b.w);
  } else if (t == 16) {
    v[0] = f2bf(feat[row * 2]);
    v[1] = f2bf(feat[row * 2 + 1]);
  }
  *(short8*)(out + row * 160 + 8 * t) = v;
}

__global__ __launch_bounds__(256) void k_prep_user(const float* __restrict__ gcn_user,
                                                   bf16* __restrict__ fused) {
  int tid = blockIdx.x * 256 + threadIdx.x;
  if (tid >= NUSERS * GCN) return;
  int k = tid & 127;
  int u = tid >> 7;
  fused[(size_t)u * (GCN + TOW) + k] = __float2bfloat16(gcn_user[tid]);
}

// ---------------------------------------------------------------------------
// Fold: Wqk[g][t] = (1/sqrt(128)) * sum_d Wq[g][d] * Wk[t][d]   (g<128)
//       b~[t]    = (1/sqrt(128)) * sum_d bq[d]    * Wk[t][d]    (block 16)
// ---------------------------------------------------------------------------
__global__ __launch_bounds__(256) void k_fold(const float* __restrict__ Wq,
                                              const float* __restrict__ Wk,
                                              const float* __restrict__ bq,
                                              float* __restrict__ out) {
  const float INV_S = 0.08838834764831845f;
  const int t = threadIdx.x;
  const int b = blockIdx.x;
  if (b < 16) {
    __shared__ float wq[8][128];
    for (int s = t; s < 8 * 128; s += 256)
      wq[s >> 7][s & 127] = Wq[(size_t)(b * 8 + (s >> 7)) * ATTN_D + (s & 127)];
    __syncthreads();
    float acc[8] = {0.f, 0.f, 0.f, 0.f, 0.f, 0.f, 0.f, 0.f};
    for (int d = 0; d < 128; ++d) {
      const float wk = Wk[(size_t)t * ATTN_D + d];
      #pragma unroll
      for (int gg = 0; gg < 8; ++gg) acc[gg] = fmaf(wq[gg][d], wk, acc[gg]);
    }
    #pragma unroll
    for (int gg = 0; gg < 8; ++gg)
      out[(size_t)(b * 8 + gg) * TOW + t] = acc[gg] * INV_S;
  } else {
    float a = 0.f;
    for (int d = 0; d < 128; ++d)
      a = fmaf(bq[d], Wk[(size_t)t * ATTN_D + d], a);
    out[(size_t)128 * TOW + t] = a * INV_S;
  }
}

// ---------------------------------------------------------------------------
// Persistent-B MFMA GEMM: whole packed B (KS*16KB <= 128KB) staged in LDS
// ONCE per block; 8 waves then grind 256-row tiles barrier-free, grid-stride.
// Wave w: rows w*32..+32 of the tile (MR=2), all 256 cols (NT=16, acc=128 VGPR).
// MODE 0: relu->bf16.  MODE 1: l2norm->bf16 (wave owns full row: shfl only).
// Caller pads A and Cout so tile ntiles*256 rows are readable/writable.
// ---------------------------------------------------------------------------
template<int KS, int MODE>
__global__ __launch_bounds__(512, 2) void k_gemm_pers(
    const bf16* __restrict__ A,
    const bf16* __restrict__ Wf,      // packed NT=16 fragment order
    const float* __restrict__ bias,
    bf16* __restrict__ Cout,
    int ntiles, int Astride)
{
  __shared__ bf16 bs[KS * 8192];      // KS * 16 KB = full B
  const int j = threadIdx.x;
  const int l = j & 63;
  const int w = j >> 6;               // 0..7 row-wave
  const int r = l & 15, g = l >> 4;
  const int jb = (j & ~63) * 8;       // wave-uniform LDS element base

  // stage full B once: 2*KS sweeps x 8KB
  #pragma unroll
  for (int s = 0; s < 2 * KS; ++s)
    GLDS16(Wf + (size_t)s * 4096 + (size_t)j * 8, &bs[s * 4096 + jb]);

  // per-lane bias (col = ct*16 + r)
  float bj[16];
  #pragma unroll
  for (int ct = 0; ct < 16; ++ct) bj[ct] = bias[ct * 16 + r];

  __syncthreads();   // drains the global_load_lds queue; only barrier

  for (int t = blockIdx.x; t < ntiles; t += gridDim.x) {
    const int R0 = t * 256 + w * 32;
    const bf16* arow0 = A + (size_t)(R0 + r) * Astride + g * 8;
    const bf16* arow1 = arow0 + (size_t)16 * Astride;

    f32x4 acc[2][16];
    #pragma unroll
    for (int mr = 0; mr < 2; ++mr)
      #pragma unroll
      for (int ct = 0; ct < 16; ++ct) acc[mr][ct] = (f32x4){0.f, 0.f, 0.f, 0.f};

    #pragma unroll
    for (int ks = 0; ks < KS; ++ks) {
      short8 a0 = *(const short8*)(arow0 + ks * 32);
      short8 a1 = *(const short8*)(arow1 + ks * 32);
      const bf16* wb = bs + (size_t)(ks * 16) * 512 + (size_t)l * 8;
      #pragma unroll
      for (int ct = 0; ct < 16; ++ct) {
        short8 b = *(const short8*)(wb + ct * 512);
        acc[0][ct] = __builtin_amdgcn_mfma_f32_16x16x32_bf16(a0, b, acc[0][ct], 0, 0, 0);
        acc[1][ct] = __builtin_amdgcn_mfma_f32_16x16x32_bf16(a1, b, acc[1][ct], 0, 0, 0);
      }
    }

    // bias
    #pragma unroll
    for (int mr = 0; mr < 2; ++mr)
      #pragma unroll
      for (int ct = 0; ct < 16; ++ct)
        #pragma unroll
        for (int i = 0; i < 4; ++i) acc[mr][ct][i] += bj[ct];

    if (MODE == 0) {
      #pragma unroll
      for (int mr = 0; mr < 2; ++mr)
        #pragma unroll
        for (int ct = 0; ct < 16; ++ct)
          #pragma unroll
          for (int i = 0; i < 4; ++i)
            Cout[(size_t)(R0 + mr * 16 + g * 4 + i) * 256 + ct * 16 + r] =
                __float2bfloat16(fmaxf(acc[mr][ct][i], 0.f));
    } else {
      #pragma unroll
      for (int mr = 0; mr < 2; ++mr) {
        float s[4] = {0.f, 0.f, 0.f, 0.f};
        #pragma unroll
        for (int ct = 0; ct < 16; ++ct)
          #pragma unroll
          for (int i = 0; i < 4; ++i) s[i] += acc[mr][ct][i] * acc[mr][ct][i];
        #pragma unroll
        for (int off = 1; off < 16; off <<= 1) {
          #pragma unroll
          for (int i = 0; i < 4; ++i) s[i] += __shfl_xor(s[i], off);
        }
        float rn[4];
        #pragma unroll
        for (int i = 0; i < 4; ++i) rn[i] = 1.f / fmaxf(sqrtf(s[i]), 1e-12f);
        #pragma unroll
        for (int ct = 0; ct < 16; ++ct)
          #pragma unroll
          for (int i = 0; i < 4; ++i)
            Cout[(size_t)(R0 + mr * 16 + g * 4 + i) * 256 + ct * 16 + r] =
                __float2bfloat16(acc[mr][ct][i] * rn[i]);
      }
    }
  }
}

// ---------------------------------------------------------------------------
// Generic MFMA GEMM (user tower), LDS-staged double-buffered B, 4 waves.
// MODE 0: relu->bf16; 3: l2norm->fp32; 4: plain->fp32
// ---------------------------------------------------------------------------
template<int KS, int NT, int MODE, int MR>
__global__ __launch_bounds__(256) void k_gemm(
    const bf16* __restrict__ A,
    const bf16* __restrict__ Wf,
    const float* __restrict__ bias,
    void* __restrict__ Cout,
    int Mtiles, int Astride)
{
  static_assert(NT % 4 == 0, "NT must be divisible by 4");
  constexpr int BSZ = NT * 512;
  constexpr int CH  = NT / 4;
  __shared__ bf16 bs[2][BSZ];
  const int j   = threadIdx.x;
  const int l   = j & 63;
  const int wid = j >> 6;
  int tile = blockIdx.x * 4 + wid;
  if (tile >= Mtiles) tile = Mtiles - 1;
  const int N = NT * 16;
  const int r = l & 15, g = l >> 4;

  {
    const short8* src = (const short8*)Wf;
    short8* dst = (short8*)bs[0];
    #pragma unroll
    for (int c = 0; c < CH; ++c) dst[c * 256 + j] = src[c * 256 + j];
  }

  f32x4 acc[MR][NT];
  #pragma unroll
  for (int mr = 0; mr < MR; ++mr)
    #pragma unroll
    for (int ct = 0; ct < NT; ++ct) acc[mr][ct] = (f32x4){0.f, 0.f, 0.f, 0.f};

  const bf16* arow[MR];
  #pragma unroll
  for (int mr = 0; mr < MR; ++mr)
    arow[mr] = A + (size_t)(tile * (16 * MR) + mr * 16 + r) * Astride + g * 8;

  __syncthreads();

  #pragma unroll
  for (int ks = 0; ks < KS; ++ks) {
    const int cur = ks & 1;
    short8 a[MR];
    #pragma unroll
    for (int mr = 0; mr < MR; ++mr) a[mr] = *(const short8*)(arow[mr] + ks * 32);
    short8 st[CH];
    if (ks + 1 < KS) {
      const short8* src = (const short8*)(Wf + (size_t)(ks + 1) * BSZ);
      #pragma unroll
      for (int c = 0; c < CH; ++c) st[c] = src[c * 256 + j];
    }
    const bf16* wb = bs[cur] + (size_t)l * 8;
    #pragma unroll
    for (int ct = 0; ct < NT; ++ct) {
      short8 b = *(const short8*)(wb + ct * 512);
      #pragma unroll
      for (int mr = 0; mr < MR; ++mr)
        acc[mr][ct] = __builtin_amdgcn_mfma_f32_16x16x32_bf16(a[mr], b, acc[mr][ct], 0, 0, 0);
    }
    if (ks + 1 < KS) {
      short8* dst = (short8*)bs[cur ^ 1];
      #pragma unroll
      for (int c = 0; c < CH; ++c) dst[c * 256 + j] = st[c];
    }
    __syncthreads();
  }

  #pragma unroll
  for (int mr = 0; mr < MR; ++mr) {
    #pragma unroll
    for (int ct = 0; ct < NT; ++ct) {
      const float bj = bias[ct * 16 + r];
      #pragma unroll
      for (int i = 0; i < 4; ++i) acc[mr][ct][i] += bj;
    }
  }

  if (MODE == 0 || MODE == 2 || MODE == 4) {
    #pragma unroll
    for (int mr = 0; mr < MR; ++mr)
      #pragma unroll
      for (int ct = 0; ct < NT; ++ct)
        #pragma unroll
        for (int i = 0; i < 4; ++i) {
          float v = acc[mr][ct][i];
          if (MODE == 0) v = fmaxf(v, 0.f);
          size_t off = (size_t)(tile * (16 * MR) + mr * 16 + g * 4 + i) * N + ct * 16 + r;
          if (MODE == 4) ((float*)Cout)[off] = v;
          else           ((bf16*)Cout)[off]  = __float2bfloat16(v);
        }
  } else {
    #pragma unroll
    for (int mr = 0; mr < MR; ++mr) {
      float s[4] = {0.f, 0.f, 0.f, 0.f};
      #pragma unroll
      for (int ct = 0; ct < NT; ++ct)
        #pragma unroll
        for (int i = 0; i < 4; ++i) s[i] += acc[mr][ct][i] * acc[mr][ct][i];
      #pragma unroll
      for (int off = 1; off < 16; off <<= 1) {
        #pragma unroll
        for (int i = 0; i < 4; ++i) s[i] += __shfl_xor(s[i], off);
      }
      float rn[4];
      #pragma unroll
      for (int i = 0; i < 4; ++i) rn[i] = 1.f / fmaxf(sqrtf(s[i]), 1e-12f);
      #pragma unroll
      for (int ct = 0; ct < NT; ++ct)
        #pragma unroll
        for (int i = 0; i < 4; ++i) {
          size_t off = (size_t)(tile * (16 * MR) + mr * 16 + g * 4 + i) * N + ct * 16 + r;
          float v = acc[mr][ct][i] * rn[i];
          if (MODE == 3) ((float*)Cout)[off] = v;
          else           ((bf16*)Cout)[off]  = __float2bfloat16(v);
        }
    }
  }
}

// ---------------------------------------------------------------------------
// Attention v7: 16-lane row groups, no-max softmax (scores |s|<0.1 by
// construction: |Wqk|~4e-4, ||emb||=1 — exp() safe; max-shift cancels).
// ---------------------------------------------------------------------------
__global__ __launch_bounds__(256) void k_user_attn(
    const float* __restrict__ Qt,          // [NUSERS][TOW] fp32 (Wqk-folded)
    const int*   __restrict__ hist_idx,
    const int*   __restrict__ hist_len,
    const bf16*  __restrict__ item_emb,    // [NITEMS][TOW] bf16
    bf16* __restrict__ fused)
{
  const int u = blockIdx.x;
  const int j = threadIdx.x;
  const int wid = j >> 6, lane = j & 63;
  const int g = lane >> 4, r = lane & 15;
  const int part = wid * 4 + g;
  __shared__ int   idx[HLEN];
  __shared__ float redO[16][TOW + 4];
  __shared__ float redL[16];

  const int nv = hist_len[u] + 1;

  if (j < HLEN) idx[j] = hist_idx[u * HLEN + j];
  const float* qp = Qt + (size_t)u * TOW + r * 16;
  f32x4 q0 = *(const f32x4*)(qp);
  f32x4 q1 = *(const f32x4*)(qp + 4);
  f32x4 q2 = *(const f32x4*)(qp + 8);
  f32x4 q3 = *(const f32x4*)(qp + 12);
  __syncthreads();

  float l = 0.f;
  f32x4 O0 = (f32x4){0.f,0.f,0.f,0.f}, O1 = O0, O2 = O0, O3 = O0;

  for (int h = part; h < nv; h += 16) {
    const bf16* e = item_emb + (size_t)idx[h] * TOW + r * 16;
    short8 e0 = *(const short8*)e;
    short8 e1 = *(const short8*)(e + 8);
    float ef[16];
    #pragma unroll
    for (int i = 0; i < 8; ++i) ef[i]     = bfu((unsigned short)e0[i]);
    #pragma unroll
    for (int i = 0; i < 8; ++i) ef[8 + i] = bfu((unsigned short)e1[i]);

    float sc = q0.x*ef[0] + q0.y*ef[1] + q0.z*ef[2] + q0.w*ef[3]
             + q1.x*ef[4] + q1.y*ef[5] + q1.z*ef[6] + q1.w*ef[7]
             + q2.x*ef[8] + q2.y*ef[9] + q2.z*ef[10]+ q2.w*ef[11]
             + q3.x*ef[12]+ q3.y*ef[13]+ q3.z*ef[14]+ q3.w*ef[15];
    #pragma unroll
    for (int off = 1; off < 16; off <<= 1) sc += __shfl_xor(sc, off);
    const float p = __expf(sc);
    l += p;
    O0.x += p*ef[0];  O0.y += p*ef[1];  O0.z += p*ef[2];  O0.w += p*ef[3];
    O1.x += p*ef[4];  O1.y += p*ef[5];  O1.z += p*ef[6];  O1.w += p*ef[7];
    O2.x += p*ef[8];  O2.y += p*ef[9];  O2.z += p*ef[10]; O2.w += p*ef[11];
    O3.x += p*ef[12]; O3.y += p*ef[13]; O3.z += p*ef[14]; O3.w += p*ef[15];
  }

  *(f32x4*)(&redO[part][r * 16])      = O0;
  *(f32x4*)(&redO[part][r * 16 + 4])  = O1;
  *(f32x4*)(&redO[part][r * 16 + 8])  = O2;
  *(f32x4*)(&redO[part][r * 16 + 12]) = O3;
  if (r == 0) redL[part] = l;
  __syncthreads();

  float L = 0.f, val = 0.f;
  #pragma unroll
  for (int w = 0; w < 16; ++w) {
    L   += redL[w];
    val += redO[w][j];
  }
  fused[(size_t)u * (GCN + TOW) + GCN + j] = __float2bfloat16(val / L);
}

// ---------------------------------------------------------------------------
extern "C" void kernel_launch(void* const* d_in, const int* in_sizes, int n_in,
                              void* d_out, int out_size, void* d_ws, size_t ws_size,
                              hipStream_t stream) {
  const float* item_feat = (const float*)d_in[0];
  const float* gcn_item  = (const float*)d_in[1];
  const float* gcn_user  = (const float*)d_in[2];
  const int*   hist_idx  = (const int*)d_in[3];
  const int*   hist_len  = (const int*)d_in[4];
  const float* Wi1 = (const float*)d_in[5];
  const float* bi1 = (const float*)d_in[6];
  const float* Wi2 = (const float*)d_in[7];
  const float* bi2 = (const float*)d_in[8];
  const float* Wq  = (const float*)d_in[9];
  const float* bq  = (const float*)d_in[10];
  const float* Wk  = (const float*)d_in[11];
  const float* bk  = (const float*)d_in[12];  // cancels in softmax
  const float* Wu1 = (const float*)d_in[13];
  const float* bu1 = (const float*)d_in[14];
  const float* Wu2 = (const float*)d_in[15];
  const float* bu2 = (const float*)d_in[16];
  (void)bk;

  char* ws = (char*)d_ws;
  bf16*  Wi1p  = (bf16*)(ws + 0);            // 81,920 B
  bf16*  Wi2p  = (bf16*)(ws + 81920);        // -> 212,992
  bf16*  Wu1p  = (bf16*)(ws + 212992);       // -> 409,600
  bf16*  Wu2p  = (bf16*)(ws + 409600);       // -> 540,672
  float* Wqkf  = (float*)(ws + 540672);      // -> 672,768
  bf16*  Wqkp  = (bf16*)(ws + 672768);       // -> 738,304
  // A1p padded to 100,096 rows (391 tiles x 256) for the persistent GEMM
  bf16*  A1p   = (bf16*)(ws + 738304);       // 32,000,000 + 65,536 -> 32,803,840
  float* Qt    = (float*)(ws + 738304);      // aliases A1p (dead by then)
  bf16*  h_buf    = (bf16*)(ws + 32803840);  // 51,200,000 + 65,536 -> 84,069,376
  bf16*  item_emb = (bf16*)(ws + 84069376);  // 51,200,000 + 65,536 -> 135,334,912
  bf16*  fusedA   = (bf16*)(ws + 135334912); // 12,582,912 -> 147,917,824
  bf16*  hu_buf   = (bf16*)(ws + 147917824); // 8,388,608 -> 156,306,432

  // ---- packing / folding ----
  k_prep_w<<<160, 256, 0, stream>>>(Wi1, Wi1p, 130, 5, 16, 1);   // permuted (gcn-first)
  k_prep_w<<<256, 256, 0, stream>>>(Wi2, Wi2p, 256, 8, 16, 0);
  k_prep_w<<<384, 256, 0, stream>>>(Wu1, Wu1p, 384, 12, 16, 0);
  k_prep_w<<<256, 256, 0, stream>>>(Wu2, Wu2p, 256, 8, 16, 0);
  k_fold<<<17, 256, 0, stream>>>(Wq, Wk, bq, Wqkf);
  k_prep_w<<<128, 256, 0, stream>>>(Wqkf, Wqkp, 128, 4, 16, 0);
  k_prep_a1<<<7813, 256, 0, stream>>>(item_feat, gcn_item, A1p);
  k_prep_user<<<8192, 256, 0, stream>>>(gcn_user, fusedA);

  // ---- item tower: persistent-B, barrier-free row grind ----
  const int intiles = (NITEMS + 255) / 256;  // 391 (padded rows harmless)
  k_gemm_pers<5, 0><<<256, 512, 0, stream>>>(A1p, Wi1p, bi1, h_buf, intiles, 160);
  k_gemm_pers<8, 1><<<256, 512, 0, stream>>>(h_buf, Wi2p, bi2, item_emb, intiles, 256);

  // ---- user tower ----
  const int utiles = NUSERS / 32;            // 512
  const int ublk = utiles / 4;               // 128
  k_gemm<4, 16, 4, 2><<<ublk, 256, 0, stream>>>(fusedA, Wqkp, Wqkf + 128 * 256, Qt, utiles, 384);
  k_user_attn<<<NUSERS, 256, 0, stream>>>(Qt, hist_idx, hist_len, item_emb, fusedA);
  k_gemm<12, 16, 0, 2><<<ublk, 256, 0, stream>>>(fusedA, Wu1p, bu1, hu_buf, utiles, 384);
  k_gemm<8, 16, 3, 2><<<ublk, 256, 0, stream>>>(hu_buf, Wu2p, bu2, (float*)d_out, utiles, 256);
}